// Round 1
// baseline (2046.400 us; speedup 1.0000x reference)
//
#include <hip/hip_runtime.h>
#include <math.h>

// Problem: NERRelationModel_84963043050124
// B=64 S=512 H=768 E=32 P=16 K=9 R=6 HEADS=4 C1=128 C2=64 FEAT=257
// Outputs: ner_logits [B,S,K]=294912, z [R,B,P]=6144, total [1] -> 301057 f32

#define NB 64
#define NS 512
#define NH 768
#define NE 32
#define NP 16
#define NK 9
#define NR 6
#define NHEADS 4
#define NC1 128
#define NC2 64

#define ZOFF 294912
#define TOTOFF 301056

// ---- workspace layout (float offsets) ----
#define WS_ENT   0u           // [B,E,768]
#define WS_HG1   1572864u     // [B,E,512]
#define WS_X1    2621440u     // [B,E,512]
#define WS_H2    3670016u     // [B,E,64]
#define WS_X2    3801088u     // [B,E,64]
#define WS_S1    3932160u     // [B,4,E]
#define WS_D1    3940352u
#define WS_S2    3948544u     // [B,E]
#define WS_D2    3950592u
#define WS_CTX   3952640u     // [B,64]
#define WS_PF    3956736u     // [B*P, 260] padded pitch
#define WS_FE    4222976u     // [B,P,512]
#define WS_CRF   4747264u     // [64]
#define WS_REL   4747328u     // [1]

__device__ __forceinline__ float blk_sum256(float v, float* sm) {
#pragma unroll
  for (int o = 32; o > 0; o >>= 1) v += __shfl_down(v, o);
  if ((threadIdx.x & 63) == 0) sm[threadIdx.x >> 6] = v;
  __syncthreads();
  v = sm[0] + sm[1] + sm[2] + sm[3];
  __syncthreads();
  return v;
}

__device__ __forceinline__ float logsigf(float x) {
  // stable log(sigmoid(x))
  if (x >= 0.f) return -log1pf(__expf(-x));
  return x - log1pf(__expf(x));
}

// ---------------- NER head: logits = relu(seq@W1+b1)@W2+b2 ----------------
// grid 1024 (32 tokens each), 256 threads (hidden col each)
__global__ __launch_bounds__(256) void k_ner(const float* __restrict__ seq,
    const float* __restrict__ w1, const float* __restrict__ b1,
    const float* __restrict__ w2, const float* __restrict__ b2,
    float* __restrict__ out) {
  __shared__ float hid[32 * 260];
  __shared__ float w2s[256 * NK];
  __shared__ float b2s[NK];
  const int t = threadIdx.x;
  const int tok0 = blockIdx.x * 32;
  for (int i = t; i < 256 * NK; i += 256) w2s[i] = w2[i];
  if (t < NK) b2s[t] = b2[t];
  float acc[32];
  {
    const float bv = b1[t];
#pragma unroll
    for (int r = 0; r < 32; r++) acc[r] = bv;
  }
  const float* wcol = w1 + t;
  for (int k = 0; k < NH; k += 4) {
    const float w0 = wcol[(k + 0) * 256];
    const float wA = wcol[(k + 1) * 256];
    const float wB = wcol[(k + 2) * 256];
    const float wC = wcol[(k + 3) * 256];
#pragma unroll
    for (int r = 0; r < 32; r++) {
      const float4 a4 = *reinterpret_cast<const float4*>(&seq[(size_t)(tok0 + r) * NH + k]);
      float a = acc[r];
      a = fmaf(a4.x, w0, a);
      a = fmaf(a4.y, wA, a);
      a = fmaf(a4.z, wB, a);
      a = fmaf(a4.w, wC, a);
      acc[r] = a;
    }
  }
#pragma unroll
  for (int r = 0; r < 32; r++) hid[r * 260 + t] = fmaxf(acc[r], 0.f);
  __syncthreads();
  for (int idx = t; idx < 32 * NK; idx += 256) {
    const int r = idx / NK, c = idx % NK;
    float s = b2s[c];
    const float* hrow = &hid[r * 260];
    for (int h = 0; h < 256; h++) s = fmaf(hrow[h], w2s[h * NK + c], s);
    out[(size_t)(tok0 + r) * NK + c] = s;
  }
}

// ---------------- CRF NLL per batch row ----------------
// grid 64, 64 threads. lanes 0..8: forward recursion; lane 9: numerator.
__global__ __launch_bounds__(64) void k_crf(const float* __restrict__ em,
    const int* __restrict__ tags, const int* __restrict__ mask,
    const float* __restrict__ startv, const float* __restrict__ endv,
    const float* __restrict__ trans, float* __restrict__ lossb) {
  __shared__ float ems[NS * NK];
  __shared__ float red[16];
  const int b = blockIdx.x, t = threadIdx.x;
  for (int i = t; i < NS * NK; i += 64) ems[i] = em[(size_t)b * NS * NK + i];
  __syncthreads();
  if (t < NK) {
    const int j = t;
    float tr[NK];
#pragma unroll
    for (int i = 0; i < NK; i++) tr[i] = trans[i * NK + j];
    float a = startv[j] + ems[j];
    for (int s = 1; s < NS; s++) {
      float tv[NK];
      float m = -1e30f;
#pragma unroll
      for (int i = 0; i < NK; i++) {
        const float ai = __shfl(a, i);
        tv[i] = ai + tr[i];
        m = fmaxf(m, tv[i]);
      }
      float sum = 0.f;
#pragma unroll
      for (int i = 0; i < NK; i++) sum += __expf(tv[i] - m);
      const float nxt = m + __logf(sum) + ems[s * NK + j];
      a = (mask[b * NS + s] > 0) ? nxt : a;
    }
    red[j] = a + endv[j];
  }
  if (t == 9) {
    int pt = tags[b * NS];
    float num = startv[pt] + ems[pt];
    for (int s = 1; s < NS; s++) {
      const int tg = tags[b * NS + s];
      if (mask[b * NS + s] > 0) {
        num += trans[pt * NK + tg] + ems[s * NK + tg];
        pt = tg;
      }
    }
    red[10] = num + endv[pt];
  }
  __syncthreads();
  if (t == 0) {
    float m = red[0];
    for (int j = 1; j < NK; j++) m = fmaxf(m, red[j]);
    float sum = 0.f;
    for (int j = 0; j < NK; j++) sum += __expf(red[j] - m);
    lossb[b] = m + __logf(sum) - red[10];
  }
}

// ---------------- entity span mean pool ----------------
// grid B*E, 256 threads
__global__ __launch_bounds__(256) void k_ent(const float* __restrict__ seq,
    const int* __restrict__ est, const int* __restrict__ elen, float* __restrict__ ent) {
  const int be = blockIdx.x;
  const int b = be >> 5, e = be & 31;
  const int st = est[b * NE + e];
  int en = st + elen[b * NE + e];
  en = min(max(en, 0), NS - 1);
  const float inv = 1.f / (float)(en - st + 1);
  for (int c = threadIdx.x; c < NH; c += 256) {
    float s = 0.f;
    for (int r = st; r <= en; r++) s += seq[((size_t)b * NS + r) * NH + c];
    ent[((size_t)b * NE + e) * NH + c] = s * inv;
  }
}

// ---------------- GAT1 GEMM: h = ent @ w_gat1 (768->512) ----------------
// grid B*2 (16 entities each), 256 threads (2 cols each)
__global__ __launch_bounds__(256) void k_g1(const float* __restrict__ ent,
    const float* __restrict__ w, float* __restrict__ hout) {
  const int blk = blockIdx.x;
  const int b = blk >> 1, e0 = (blk & 1) * 16;
  const int t = threadIdx.x;
  float acc0[16], acc1[16];
#pragma unroll
  for (int e = 0; e < 16; e++) { acc0[e] = 0.f; acc1[e] = 0.f; }
  for (int k = 0; k < NH; k += 4) {
    const float w00 = w[(k + 0) * 512 + t], w01 = w[(k + 1) * 512 + t];
    const float w02 = w[(k + 2) * 512 + t], w03 = w[(k + 3) * 512 + t];
    const float w10 = w[(k + 0) * 512 + t + 256], w11 = w[(k + 1) * 512 + t + 256];
    const float w12 = w[(k + 2) * 512 + t + 256], w13 = w[(k + 3) * 512 + t + 256];
#pragma unroll
    for (int e = 0; e < 16; e++) {
      const float4 a4 = *reinterpret_cast<const float4*>(&ent[((size_t)b * NE + e0 + e) * NH + k]);
      float x0 = acc0[e], x1 = acc1[e];
      x0 = fmaf(a4.x, w00, x0); x1 = fmaf(a4.x, w10, x1);
      x0 = fmaf(a4.y, w01, x0); x1 = fmaf(a4.y, w11, x1);
      x0 = fmaf(a4.z, w02, x0); x1 = fmaf(a4.z, w12, x1);
      x0 = fmaf(a4.w, w03, x0); x1 = fmaf(a4.w, w13, x1);
      acc0[e] = x0; acc1[e] = x1;
    }
  }
#pragma unroll
  for (int e = 0; e < 16; e++) {
    hout[((size_t)b * NE + e0 + e) * 512 + t] = acc0[e];
    hout[((size_t)b * NE + e0 + e) * 512 + t + 256] = acc1[e];
  }
}

// ---------------- GAT1 attention src/dst dots ----------------
// grid B*E, 128 threads
__global__ __launch_bounds__(128) void k_sd1(const float* __restrict__ h,
    const float* __restrict__ as, const float* __restrict__ ad,
    float* __restrict__ s1, float* __restrict__ d1) {
  __shared__ float sm[4];
  const int be = blockIdx.x;
  const int b = be >> 5, e = be & 31;
  const int t = threadIdx.x;
  for (int hd = 0; hd < NHEADS; hd++) {
    const float v = h[((size_t)b * NE + e) * 512 + hd * NC1 + t];
    float sv = v * as[hd * NC1 + t];
    float dv = v * ad[hd * NC1 + t];
#pragma unroll
    for (int o = 32; o > 0; o >>= 1) { sv += __shfl_xor(sv, o); dv += __shfl_xor(dv, o); }
    if ((t & 63) == 0) { sm[(t >> 6) * 2] = sv; sm[(t >> 6) * 2 + 1] = dv; }
    __syncthreads();
    if (t == 0) {
      s1[(b * NHEADS + hd) * NE + e] = sm[0] + sm[2];
      d1[(b * NHEADS + hd) * NE + e] = sm[1] + sm[3];
    }
    __syncthreads();
  }
}

// ---------------- GAT1 attention + aggregate + bias + relu ----------------
// grid B*HEADS*E, 128 threads
__global__ __launch_bounds__(128) void k_att1(const float* __restrict__ h,
    const float* __restrict__ s1, const float* __restrict__ d1,
    const unsigned char* __restrict__ adj, const float* __restrict__ bias,
    float* __restrict__ x1) {
  __shared__ float att[NE];
  const int blk = blockIdx.x;
  const int i = blk & 31, hd = (blk >> 5) & 3, b = blk >> 7;
  const int t = threadIdx.x;
  if (t < NE) {
    float lg = d1[(b * NHEADS + hd) * NE + i] + s1[(b * NHEADS + hd) * NE + t];
    lg = lg >= 0.f ? lg : 0.2f * lg;
    if (!adj[((size_t)b * NE + i) * NE + t]) lg = -1e9f;
    att[t] = lg;
  }
  __syncthreads();
  if (t == 0) {
    float m = -1e30f;
#pragma unroll
    for (int j = 0; j < NE; j++) m = fmaxf(m, att[j]);
    float ex[NE];
    float sum = 0.f;
#pragma unroll
    for (int j = 0; j < NE; j++) { ex[j] = __expf(att[j] - m); sum += ex[j]; }
    const float inv = 1.f / sum;
#pragma unroll
    for (int j = 0; j < NE; j++) att[j] = ex[j] * inv;
  }
  __syncthreads();
  float acc = bias[hd * NC1 + t];
  for (int j = 0; j < NE; j++)
    acc += att[j] * h[((size_t)b * NE + j) * 512 + hd * NC1 + t];
  x1[((size_t)b * NE + i) * 512 + hd * NC1 + t] = fmaxf(acc, 0.f);
}

// ---------------- GAT2 GEMM + src/dst dots ----------------
// grid B*2 (16 entities), 64 threads (cols)
__global__ __launch_bounds__(64) void k_g2(const float* __restrict__ x1,
    const float* __restrict__ w, const float* __restrict__ as, const float* __restrict__ ad,
    float* __restrict__ h2, float* __restrict__ s2, float* __restrict__ d2) {
  const int blk = blockIdx.x;
  const int b = blk >> 1, e0 = (blk & 1) * 16;
  const int t = threadIdx.x;
  float acc[16];
#pragma unroll
  for (int e = 0; e < 16; e++) acc[e] = 0.f;
  for (int k = 0; k < 512; k += 4) {
    const float w0 = w[(k + 0) * NC2 + t], w1 = w[(k + 1) * NC2 + t];
    const float w2 = w[(k + 2) * NC2 + t], w3 = w[(k + 3) * NC2 + t];
#pragma unroll
    for (int e = 0; e < 16; e++) {
      const float4 a4 = *reinterpret_cast<const float4*>(&x1[((size_t)b * NE + e0 + e) * 512 + k]);
      float x = acc[e];
      x = fmaf(a4.x, w0, x); x = fmaf(a4.y, w1, x);
      x = fmaf(a4.z, w2, x); x = fmaf(a4.w, w3, x);
      acc[e] = x;
    }
  }
  const float asv = as[t], adv = ad[t];
  for (int e = 0; e < 16; e++) {
    h2[((size_t)b * NE + e0 + e) * NC2 + t] = acc[e];
    float sv = acc[e] * asv, dv = acc[e] * adv;
#pragma unroll
    for (int o = 32; o > 0; o >>= 1) { sv += __shfl_xor(sv, o); dv += __shfl_xor(dv, o); }
    if (t == 0) { s2[b * NE + e0 + e] = sv; d2[b * NE + e0 + e] = dv; }
  }
}

// ---------------- GAT2 attention + aggregate + bias ----------------
// grid B*E, 64 threads
__global__ __launch_bounds__(64) void k_att2(const float* __restrict__ h2,
    const float* __restrict__ s2, const float* __restrict__ d2,
    const unsigned char* __restrict__ adj, const float* __restrict__ bias,
    float* __restrict__ x2) {
  __shared__ float att[NE];
  const int be = blockIdx.x;
  const int b = be >> 5, i = be & 31;
  const int t = threadIdx.x;
  if (t < NE) {
    float lg = d2[b * NE + i] + s2[b * NE + t];
    lg = lg >= 0.f ? lg : 0.2f * lg;
    if (!adj[((size_t)b * NE + i) * NE + t]) lg = -1e9f;
    att[t] = lg;
  }
  __syncthreads();
  if (t == 0) {
    float m = -1e30f;
#pragma unroll
    for (int j = 0; j < NE; j++) m = fmaxf(m, att[j]);
    float ex[NE];
    float sum = 0.f;
#pragma unroll
    for (int j = 0; j < NE; j++) { ex[j] = __expf(att[j] - m); sum += ex[j]; }
    const float inv = 1.f / sum;
#pragma unroll
    for (int j = 0; j < NE; j++) att[j] = ex[j] * inv;
  }
  __syncthreads();
  float acc = bias[t];
  for (int j = 0; j < NE; j++)
    acc += att[j] * h2[((size_t)b * NE + j) * NC2 + t];
  x2[((size_t)b * NE + i) * NC2 + t] = acc;
}

// ---------------- ctx = mean over entities ----------------
__global__ __launch_bounds__(64) void k_ctx(const float* __restrict__ x2, float* __restrict__ ctx) {
  const int b = blockIdx.x, t = threadIdx.x;
  float s = 0.f;
  for (int e = 0; e < NE; e++) s += x2[((size_t)b * NE + e) * NC2 + t];
  ctx[b * NC2 + t] = s * (1.f / NE);
}

// ---------------- pair feature build (pitch 260) ----------------
// grid B*P, 64 threads
__global__ __launch_bounds__(64) void k_pf(const float* __restrict__ x2,
    const float* __restrict__ ctx, const int* __restrict__ pe1, const int* __restrict__ pe2,
    float* __restrict__ pf) {
  const int bp = blockIdx.x;
  const int b = bp >> 4, p = bp & 15;
  const int t = threadIdx.x;
  const int e1 = pe1[b * NP + p], e2 = pe2[b * NP + p];
  const float v1 = x2[((size_t)b * NE + e1) * NC2 + t];
  const float v2 = x2[((size_t)b * NE + e2) * NC2 + t];
  float* row = pf + (size_t)bp * 260;
  row[t] = v1;
  row[64 + t] = v2;
  row[128 + t] = v1 * v2;
  row[192 + t] = ctx[b * NC2 + t];
  if (t == 0) row[256] = logf(fabsf((float)(e1 - e2)) + 1.f);
  if (t < 3) row[257 + t] = 0.f;
}

// ---------------- fe = leaky(LN(pf @ w_fe + b_fe)) ----------------
// grid B, 256 threads (2 cols each), 16 pairs per block
__global__ __launch_bounds__(256) void k_fe(const float* __restrict__ pf,
    const float* __restrict__ w, const float* __restrict__ bfe,
    const float* __restrict__ g, const float* __restrict__ be, float* __restrict__ fe) {
  __shared__ float sm[4];
  const int b = blockIdx.x, t = threadIdx.x;
  float a0[16], a1[16];
  {
    const float bv0 = bfe[t], bv1 = bfe[t + 256];
#pragma unroll
    for (int p = 0; p < NP; p++) { a0[p] = bv0; a1[p] = bv1; }
  }
  for (int k = 0; k < 256; k += 4) {
    const float w00 = w[(k + 0) * 512 + t], w01 = w[(k + 1) * 512 + t];
    const float w02 = w[(k + 2) * 512 + t], w03 = w[(k + 3) * 512 + t];
    const float w10 = w[(k + 0) * 512 + t + 256], w11 = w[(k + 1) * 512 + t + 256];
    const float w12 = w[(k + 2) * 512 + t + 256], w13 = w[(k + 3) * 512 + t + 256];
#pragma unroll
    for (int p = 0; p < NP; p++) {
      const float4 a4 = *reinterpret_cast<const float4*>(&pf[((size_t)b * NP + p) * 260 + k]);
      float x0 = a0[p], x1 = a1[p];
      x0 = fmaf(a4.x, w00, x0); x1 = fmaf(a4.x, w10, x1);
      x0 = fmaf(a4.y, w01, x0); x1 = fmaf(a4.y, w11, x1);
      x0 = fmaf(a4.z, w02, x0); x1 = fmaf(a4.z, w12, x1);
      x0 = fmaf(a4.w, w03, x0); x1 = fmaf(a4.w, w13, x1);
      a0[p] = x0; a1[p] = x1;
    }
  }
  { // tail k=256 (log-distance feature)
    const float w0 = w[256 * 512 + t], w1 = w[256 * 512 + t + 256];
#pragma unroll
    for (int p = 0; p < NP; p++) {
      const float av = pf[((size_t)b * NP + p) * 260 + 256];
      a0[p] = fmaf(av, w0, a0[p]);
      a1[p] = fmaf(av, w1, a1[p]);
    }
  }
  const float gv0 = g[t], gv1 = g[t + 256], bev0 = be[t], bev1 = be[t + 256];
  for (int p = 0; p < NP; p++) {
    const float s = blk_sum256(a0[p] + a1[p], sm);
    const float sq = blk_sum256(a0[p] * a0[p] + a1[p] * a1[p], sm);
    const float mean = s * (1.f / 512.f);
    const float var = sq * (1.f / 512.f) - mean * mean;
    const float rr = rsqrtf(var + 1e-5f);
    float n0 = (a0[p] - mean) * rr * gv0 + bev0;
    float n1 = (a1[p] - mean) * rr * gv1 + bev1;
    n0 = n0 >= 0.f ? n0 : 0.01f * n0;
    n1 = n1 >= 0.f ? n1 : 0.01f * n1;
    fe[((size_t)b * NP + p) * 512 + t] = n0;
    fe[((size_t)b * NP + p) * 512 + t + 256] = n1;
  }
}

// ---------------- relation heads: GEMM + LN + leaky + dot + BCE ----------------
// grid R*B, 256 threads (out col each), 16 pairs per block
__global__ __launch_bounds__(256) void k_rc(const float* __restrict__ fe,
    const float* __restrict__ w1, const float* __restrict__ b1,
    const float* __restrict__ g, const float* __restrict__ be,
    const float* __restrict__ w2, const float* __restrict__ b2,
    const int* __restrict__ ylab, float* __restrict__ zout, float* __restrict__ relacc) {
  __shared__ float sm[4];
  const int blk = blockIdx.x;
  const int r = blk >> 6, b = blk & 63;
  const int t = threadIdx.x;
  float acc[16];
  {
    const float bv = b1[r * 256 + t];
#pragma unroll
    for (int p = 0; p < NP; p++) acc[p] = bv;
  }
  const float* wr = w1 + (size_t)r * 512 * 256;
  for (int k = 0; k < 512; k += 4) {
    const float w0 = wr[(k + 0) * 256 + t], wA = wr[(k + 1) * 256 + t];
    const float wB = wr[(k + 2) * 256 + t], wC = wr[(k + 3) * 256 + t];
#pragma unroll
    for (int p = 0; p < NP; p++) {
      const float4 a4 = *reinterpret_cast<const float4*>(&fe[((size_t)b * NP + p) * 512 + k]);
      float x = acc[p];
      x = fmaf(a4.x, w0, x); x = fmaf(a4.y, wA, x);
      x = fmaf(a4.z, wB, x); x = fmaf(a4.w, wC, x);
      acc[p] = x;
    }
  }
  const float gv = g[r * 256 + t], bev = be[r * 256 + t], w2v = w2[r * 256 + t];
  const float b2v = b2[r];
  float local = 0.f;
  for (int p = 0; p < NP; p++) {
    const float s = blk_sum256(acc[p], sm);
    const float sq = blk_sum256(acc[p] * acc[p], sm);
    const float mean = s * (1.f / 256.f);
    const float var = sq * (1.f / 256.f) - mean * mean;
    const float rr = rsqrtf(var + 1e-5f);
    float n = (acc[p] - mean) * rr * gv + bev;
    n = n >= 0.f ? n : 0.01f * n;
    const float zp = blk_sum256(n * w2v, sm) + b2v;
    if (t == 0) {
      zout[((size_t)r * NB + b) * NP + p] = zp;
      const float y = (float)ylab[b * NP + p];
      local += -(2.f * y * logsigf(zp) + (1.f - y) * logsigf(-zp));
    }
  }
  if (t == 0) atomicAdd(relacc, local * (1.f / (NB * NP)));
}

// ---------------- finalize total loss ----------------
__global__ __launch_bounds__(64) void k_fin(const float* __restrict__ lossb,
    const float* __restrict__ rel, float* __restrict__ out) {
  float v = lossb[threadIdx.x];
#pragma unroll
  for (int o = 32; o > 0; o >>= 1) v += __shfl_down(v, o);
  if (threadIdx.x == 0) out[TOTOFF] = v * (1.f / NB) + rel[0];
}

extern "C" void kernel_launch(void* const* d_in, const int* in_sizes, int n_in,
                              void* d_out, int out_size, void* d_ws, size_t ws_size,
                              hipStream_t stream) {
  const float* seq = (const float*)d_in[0];
  const int* amask = (const int*)d_in[1];
  const int* nlab = (const int*)d_in[2];
  const int* est = (const int*)d_in[3];
  const int* elen = (const int*)d_in[4];
  const int* pe1 = (const int*)d_in[5];
  const int* pe2 = (const int*)d_in[6];
  const int* plab = (const int*)d_in[7];
  const unsigned char* adj = (const unsigned char*)d_in[8];  // jnp bool -> 1 byte
  const float* w_ner1 = (const float*)d_in[9];
  const float* b_ner1 = (const float*)d_in[10];
  const float* w_ner2 = (const float*)d_in[11];
  const float* b_ner2 = (const float*)d_in[12];
  const float* crf_start = (const float*)d_in[13];
  const float* crf_end = (const float*)d_in[14];
  const float* crf_trans = (const float*)d_in[15];
  const float* w_gat1 = (const float*)d_in[16];
  const float* a_src1 = (const float*)d_in[17];
  const float* a_dst1 = (const float*)d_in[18];
  const float* b_gat1 = (const float*)d_in[19];
  const float* w_gat2 = (const float*)d_in[20];
  const float* a_src2 = (const float*)d_in[21];
  const float* a_dst2 = (const float*)d_in[22];
  const float* b_gat2 = (const float*)d_in[23];
  const float* w_fe = (const float*)d_in[24];
  const float* b_fe = (const float*)d_in[25];
  const float* g_fe = (const float*)d_in[26];
  const float* be_fe = (const float*)d_in[27];
  const float* w_rc1 = (const float*)d_in[28];
  const float* b_rc1 = (const float*)d_in[29];
  const float* g_rc = (const float*)d_in[30];
  const float* be_rc = (const float*)d_in[31];
  const float* w_rc2 = (const float*)d_in[32];
  const float* b_rc2 = (const float*)d_in[33];

  float* out = (float*)d_out;
  float* ws = (float*)d_ws;
  float* ent = ws + WS_ENT;
  float* hg1 = ws + WS_HG1;
  float* x1 = ws + WS_X1;
  float* h2 = ws + WS_H2;
  float* x2 = ws + WS_X2;
  float* s1 = ws + WS_S1;
  float* d1 = ws + WS_D1;
  float* s2 = ws + WS_S2;
  float* d2 = ws + WS_D2;
  float* ctx = ws + WS_CTX;
  float* pf = ws + WS_PF;
  float* fe = ws + WS_FE;
  float* crfb = ws + WS_CRF;
  float* rel = ws + WS_REL;

  hipMemsetAsync(rel, 0, sizeof(float), stream);

  k_ner<<<1024, 256, 0, stream>>>(seq, w_ner1, b_ner1, w_ner2, b_ner2, out);
  k_crf<<<64, 64, 0, stream>>>(out, nlab, amask, crf_start, crf_end, crf_trans, crfb);
  k_ent<<<NB * NE, 256, 0, stream>>>(seq, est, elen, ent);
  k_g1<<<NB * 2, 256, 0, stream>>>(ent, w_gat1, hg1);
  k_sd1<<<NB * NE, 128, 0, stream>>>(hg1, a_src1, a_dst1, s1, d1);
  k_att1<<<NB * NHEADS * NE, 128, 0, stream>>>(hg1, s1, d1, adj, b_gat1, x1);
  k_g2<<<NB * 2, 64, 0, stream>>>(x1, w_gat2, a_src2, a_dst2, h2, s2, d2);
  k_att2<<<NB * NE, 64, 0, stream>>>(h2, s2, d2, adj, b_gat2, x2);
  k_ctx<<<NB, 64, 0, stream>>>(x2, ctx);
  k_pf<<<NB * NP, 64, 0, stream>>>(x2, ctx, pe1, pe2, pf);
  k_fe<<<NB, 256, 0, stream>>>(pf, w_fe, b_fe, g_fe, be_fe, fe);
  k_rc<<<NR * NB, 256, 0, stream>>>(fe, w_rc1, b_rc1, g_rc, be_rc, w_rc2, b_rc2,
                                    plab, out + ZOFF, rel);
  k_fin<<<1, 64, 0, stream>>>(crfb, rel, out);
}

// Round 2
// 798.281 us; speedup vs baseline: 2.5635x; 2.5635x over previous
//
#include <hip/hip_runtime.h>
#include <math.h>

// Problem: NERRelationModel_84963043050124
// B=64 S=512 H=768 E=32 P=16 K=9 R=6 HEADS=4 C1=128 C2=64 FEAT=257
// Outputs: ner_logits [B,S,K]=294912, z [R,B,P]=6144, total [1] -> 301057 f32

#define NB 64
#define NS 512
#define NH 768
#define NE 32
#define NP 16
#define NK 9
#define NR 6
#define NHEADS 4
#define NC1 128
#define NC2 64

#define ZOFF 294912
#define TOTOFF 301056

// ---- workspace layout (float offsets) ----
#define WS_ENT   0u           // [B,E,768]
#define WS_HG1   1572864u     // [B,E,512]
#define WS_X1    2621440u     // [B,E,512]
#define WS_H2    3670016u     // [B,E,64]
#define WS_X2    3801088u     // [B,E,64]
#define WS_S1    3932160u     // [B,4,E]
#define WS_D1    3940352u
#define WS_S2    3948544u     // [B,E]
#define WS_D2    3950592u
#define WS_CTX   3952640u     // [B,64]
#define WS_PF    3956736u     // [B*P, 260] padded pitch
#define WS_FE    4222976u     // [B,P,512]
#define WS_CRF   4747264u     // [64]
#define WS_REL   4747328u     // [1]

__device__ __forceinline__ float blk_sum256(float v, float* sm) {
#pragma unroll
  for (int o = 32; o > 0; o >>= 1) v += __shfl_down(v, o);
  if ((threadIdx.x & 63) == 0) sm[threadIdx.x >> 6] = v;
  __syncthreads();
  v = sm[0] + sm[1] + sm[2] + sm[3];
  __syncthreads();
  return v;
}

__device__ __forceinline__ float logsigf(float x) {
  if (x >= 0.f) return -log1pf(__expf(-x));
  return x - log1pf(__expf(x));
}

// ---------------- NER head: logits = relu(seq@W1+b1)@W2+b2 ----------------
// LDS-tiled GEMM: block = 64 tokens x 256 cols, 8x8 micro-tile, k-tile 32.
// GEMM2 (256->9) fused via per-wave shuffle reduction. grid 512, 256 thr.
__global__ __launch_bounds__(256) void k_ner(const float* __restrict__ seq,
    const float* __restrict__ w1, const float* __restrict__ b1,
    const float* __restrict__ w2, const float* __restrict__ b2,
    float* __restrict__ out) {
  __shared__ float As[64 * 36];    // [tok][k], pitch 36 (16B-aligned rows)
  __shared__ float Bs[32 * 256];   // [k][col]
  __shared__ float w2s[256 * NK];
  __shared__ float b2s[NK];
  const int t = threadIdx.x;
  const int tok0 = blockIdx.x * 64;
  const int tc = t & 31, tr = t >> 5;
  for (int i = t; i < 256 * NK; i += 256) w2s[i] = w2[i];
  if (t < NK) b2s[t] = b2[t];
  float acc[8][8];
  {
    const float4 bA = *reinterpret_cast<const float4*>(&b1[tc * 4]);
    const float4 bB = *reinterpret_cast<const float4*>(&b1[128 + tc * 4]);
#pragma unroll
    for (int i = 0; i < 8; i++) {
      acc[i][0] = bA.x; acc[i][1] = bA.y; acc[i][2] = bA.z; acc[i][3] = bA.w;
      acc[i][4] = bB.x; acc[i][5] = bB.y; acc[i][6] = bB.z; acc[i][7] = bB.w;
    }
  }
  for (int kt = 0; kt < NH; kt += 32) {
    __syncthreads();
#pragma unroll
    for (int i = 0; i < 2; i++) {       // stage A: 64x32
      const int slot = t + 256 * i;
      const int ta = slot >> 3, k4 = slot & 7;
      *reinterpret_cast<float4*>(&As[ta * 36 + k4 * 4]) =
          *reinterpret_cast<const float4*>(&seq[(size_t)(tok0 + ta) * NH + kt + k4 * 4]);
    }
#pragma unroll
    for (int i = 0; i < 8; i++) {       // stage B: 32x256
      const int slot = t + 256 * i;
      const int row = slot >> 6, cg = slot & 63;
      *reinterpret_cast<float4*>(&Bs[row * 256 + cg * 4]) =
          *reinterpret_cast<const float4*>(&w1[(size_t)(kt + row) * 256 + cg * 4]);
    }
    __syncthreads();
#pragma unroll
    for (int kg = 0; kg < 8; kg++) {
      float4 a[8];
#pragma unroll
      for (int i = 0; i < 8; i++)
        a[i] = *reinterpret_cast<const float4*>(&As[(tr * 8 + i) * 36 + kg * 4]);
#pragma unroll
      for (int k2 = 0; k2 < 4; k2++) {
        const float4 bA = *reinterpret_cast<const float4*>(&Bs[(kg * 4 + k2) * 256 + tc * 4]);
        const float4 bB = *reinterpret_cast<const float4*>(&Bs[(kg * 4 + k2) * 256 + 128 + tc * 4]);
#pragma unroll
        for (int i = 0; i < 8; i++) {
          const float av = reinterpret_cast<const float*>(&a[i])[k2];
          acc[i][0] = fmaf(av, bA.x, acc[i][0]);
          acc[i][1] = fmaf(av, bA.y, acc[i][1]);
          acc[i][2] = fmaf(av, bA.z, acc[i][2]);
          acc[i][3] = fmaf(av, bA.w, acc[i][3]);
          acc[i][4] = fmaf(av, bB.x, acc[i][4]);
          acc[i][5] = fmaf(av, bB.y, acc[i][5]);
          acc[i][6] = fmaf(av, bB.z, acc[i][6]);
          acc[i][7] = fmaf(av, bB.w, acc[i][7]);
        }
      }
    }
  }
  // epilogue: relu + 256->9 GEMM via shuffle reduce over the 32 col-threads
#pragma unroll
  for (int i = 0; i < 8; i++) {
    float r[8];
#pragma unroll
    for (int j = 0; j < 8; j++) r[j] = fmaxf(acc[i][j], 0.f);
    const int tok = tok0 + tr * 8 + i;
    float z[NK];
#pragma unroll
    for (int c = 0; c < NK; c++) {
      float p = 0.f;
#pragma unroll
      for (int j = 0; j < 4; j++) p = fmaf(r[j], w2s[(tc * 4 + j) * NK + c], p);
#pragma unroll
      for (int j = 0; j < 4; j++) p = fmaf(r[4 + j], w2s[(128 + tc * 4 + j) * NK + c], p);
#pragma unroll
      for (int o = 16; o > 0; o >>= 1) p += __shfl_xor(p, o);
      z[c] = p;
    }
    if (tc == 0) {
#pragma unroll
      for (int c = 0; c < NK; c++) out[(size_t)tok * NK + c] = z[c] + b2s[c];
    }
  }
}

// ---------------- CRF NLL per batch row ----------------
__global__ __launch_bounds__(64) void k_crf(const float* __restrict__ em,
    const int* __restrict__ tags, const int* __restrict__ mask,
    const float* __restrict__ startv, const float* __restrict__ endv,
    const float* __restrict__ trans, float* __restrict__ lossb) {
  __shared__ float ems[NS * NK];
  __shared__ float red[16];
  const int b = blockIdx.x, t = threadIdx.x;
  for (int i = t; i < NS * NK; i += 64) ems[i] = em[(size_t)b * NS * NK + i];
  __syncthreads();
  if (t < NK) {
    const int j = t;
    float tr[NK];
#pragma unroll
    for (int i = 0; i < NK; i++) tr[i] = trans[i * NK + j];
    float a = startv[j] + ems[j];
    for (int s = 1; s < NS; s++) {
      float tv[NK];
      float m = -1e30f;
#pragma unroll
      for (int i = 0; i < NK; i++) {
        const float ai = __shfl(a, i);
        tv[i] = ai + tr[i];
        m = fmaxf(m, tv[i]);
      }
      float sum = 0.f;
#pragma unroll
      for (int i = 0; i < NK; i++) sum += __expf(tv[i] - m);
      const float nxt = m + __logf(sum) + ems[s * NK + j];
      a = (mask[b * NS + s] > 0) ? nxt : a;
    }
    red[j] = a + endv[j];
  }
  if (t == 9) {
    int pt = tags[b * NS];
    float num = startv[pt] + ems[pt];
    for (int s = 1; s < NS; s++) {
      const int tg = tags[b * NS + s];
      if (mask[b * NS + s] > 0) {
        num += trans[pt * NK + tg] + ems[s * NK + tg];
        pt = tg;
      }
    }
    red[10] = num + endv[pt];
  }
  __syncthreads();
  if (t == 0) {
    float m = red[0];
    for (int j = 1; j < NK; j++) m = fmaxf(m, red[j]);
    float sum = 0.f;
    for (int j = 0; j < NK; j++) sum += __expf(red[j] - m);
    lossb[b] = m + __logf(sum) - red[10];
  }
}

// ---------------- entity span mean pool ----------------
__global__ __launch_bounds__(256) void k_ent(const float* __restrict__ seq,
    const int* __restrict__ est, const int* __restrict__ elen, float* __restrict__ ent) {
  const int be = blockIdx.x;
  const int b = be >> 5, e = be & 31;
  const int st = est[b * NE + e];
  int en = st + elen[b * NE + e];
  en = min(max(en, 0), NS - 1);
  const float inv = 1.f / (float)(en - st + 1);
  for (int c = threadIdx.x; c < NH; c += 256) {
    float s = 0.f;
    for (int r = st; r <= en; r++) s += seq[((size_t)b * NS + r) * NH + c];
    ent[((size_t)b * NE + e) * NH + c] = s * inv;
  }
}

// ---------------- GAT1 GEMM: h = ent @ w_gat1 (768->512) ----------------
// block = 32 ents x 128 cols, 4x4 micro-tile, k-tile 32. grid B*4.
__global__ __launch_bounds__(256) void k_g1(const float* __restrict__ ent,
    const float* __restrict__ w, float* __restrict__ hout) {
  __shared__ float As[32 * 36];
  __shared__ float Bs[32 * 128];
  const int b = blockIdx.x >> 2, cb = blockIdx.x & 3;
  const int t = threadIdx.x;
  const int tc = t & 31, tr = t >> 5;
  float acc[4][4];
#pragma unroll
  for (int i = 0; i < 4; i++)
#pragma unroll
    for (int j = 0; j < 4; j++) acc[i][j] = 0.f;
  for (int kt = 0; kt < NH; kt += 32) {
    __syncthreads();
    {
      const int e = t >> 3, k4 = t & 7;
      *reinterpret_cast<float4*>(&As[e * 36 + k4 * 4]) =
          *reinterpret_cast<const float4*>(&ent[((size_t)b * NE + e) * NH + kt + k4 * 4]);
    }
#pragma unroll
    for (int i = 0; i < 4; i++) {
      const int slot = t + 256 * i;
      const int row = slot >> 5, cg = slot & 31;
      *reinterpret_cast<float4*>(&Bs[row * 128 + cg * 4]) =
          *reinterpret_cast<const float4*>(&w[(size_t)(kt + row) * 512 + cb * 128 + cg * 4]);
    }
    __syncthreads();
#pragma unroll
    for (int kg = 0; kg < 8; kg++) {
      float4 a[4];
#pragma unroll
      for (int i = 0; i < 4; i++)
        a[i] = *reinterpret_cast<const float4*>(&As[(tr * 4 + i) * 36 + kg * 4]);
#pragma unroll
      for (int k2 = 0; k2 < 4; k2++) {
        const float4 bv = *reinterpret_cast<const float4*>(&Bs[(kg * 4 + k2) * 128 + tc * 4]);
#pragma unroll
        for (int i = 0; i < 4; i++) {
          const float av = reinterpret_cast<const float*>(&a[i])[k2];
          acc[i][0] = fmaf(av, bv.x, acc[i][0]);
          acc[i][1] = fmaf(av, bv.y, acc[i][1]);
          acc[i][2] = fmaf(av, bv.z, acc[i][2]);
          acc[i][3] = fmaf(av, bv.w, acc[i][3]);
        }
      }
    }
  }
#pragma unroll
  for (int i = 0; i < 4; i++) {
    float4 v;
    v.x = acc[i][0]; v.y = acc[i][1]; v.z = acc[i][2]; v.w = acc[i][3];
    *reinterpret_cast<float4*>(&hout[((size_t)b * NE + tr * 4 + i) * 512 + cb * 128 + tc * 4]) = v;
  }
}

// ---------------- GAT1 attention src/dst dots ----------------
__global__ __launch_bounds__(128) void k_sd1(const float* __restrict__ h,
    const float* __restrict__ as, const float* __restrict__ ad,
    float* __restrict__ s1, float* __restrict__ d1) {
  __shared__ float sm[4];
  const int be = blockIdx.x;
  const int b = be >> 5, e = be & 31;
  const int t = threadIdx.x;
  for (int hd = 0; hd < NHEADS; hd++) {
    const float v = h[((size_t)b * NE + e) * 512 + hd * NC1 + t];
    float sv = v * as[hd * NC1 + t];
    float dv = v * ad[hd * NC1 + t];
#pragma unroll
    for (int o = 32; o > 0; o >>= 1) { sv += __shfl_xor(sv, o); dv += __shfl_xor(dv, o); }
    if ((t & 63) == 0) { sm[(t >> 6) * 2] = sv; sm[(t >> 6) * 2 + 1] = dv; }
    __syncthreads();
    if (t == 0) {
      s1[(b * NHEADS + hd) * NE + e] = sm[0] + sm[2];
      d1[(b * NHEADS + hd) * NE + e] = sm[1] + sm[3];
    }
    __syncthreads();
  }
}

// ---------------- GAT1 attention + aggregate + bias + relu ----------------
__global__ __launch_bounds__(128) void k_att1(const float* __restrict__ h,
    const float* __restrict__ s1, const float* __restrict__ d1,
    const unsigned char* __restrict__ adj, const float* __restrict__ bias,
    float* __restrict__ x1) {
  __shared__ float att[NE];
  const int blk = blockIdx.x;
  const int i = blk & 31, hd = (blk >> 5) & 3, b = blk >> 7;
  const int t = threadIdx.x;
  if (t < NE) {
    float lg = d1[(b * NHEADS + hd) * NE + i] + s1[(b * NHEADS + hd) * NE + t];
    lg = lg >= 0.f ? lg : 0.2f * lg;
    if (!adj[((size_t)b * NE + i) * NE + t]) lg = -1e9f;
    att[t] = lg;
  }
  __syncthreads();
  if (t == 0) {
    float m = -1e30f;
#pragma unroll
    for (int j = 0; j < NE; j++) m = fmaxf(m, att[j]);
    float ex[NE];
    float sum = 0.f;
#pragma unroll
    for (int j = 0; j < NE; j++) { ex[j] = __expf(att[j] - m); sum += ex[j]; }
    const float inv = 1.f / sum;
#pragma unroll
    for (int j = 0; j < NE; j++) att[j] = ex[j] * inv;
  }
  __syncthreads();
  float acc = bias[hd * NC1 + t];
  for (int j = 0; j < NE; j++)
    acc += att[j] * h[((size_t)b * NE + j) * 512 + hd * NC1 + t];
  x1[((size_t)b * NE + i) * 512 + hd * NC1 + t] = fmaxf(acc, 0.f);
}

// ---------------- GAT2 GEMM + src/dst dots ----------------
// block = 32 ents x 64 cols, 2x4 micro-tile, k-tile 32. grid B.
__global__ __launch_bounds__(256) void k_g2(const float* __restrict__ x1,
    const float* __restrict__ w, const float* __restrict__ as, const float* __restrict__ ad,
    float* __restrict__ h2, float* __restrict__ s2, float* __restrict__ d2) {
  __shared__ float As[32 * 36];
  __shared__ float Bs[32 * 64];
  const int b = blockIdx.x;
  const int t = threadIdx.x;
  const int tc = t & 15, tr = t >> 4;
  float acc[2][4];
#pragma unroll
  for (int i = 0; i < 2; i++)
#pragma unroll
    for (int j = 0; j < 4; j++) acc[i][j] = 0.f;
  for (int kt = 0; kt < 512; kt += 32) {
    __syncthreads();
    {
      const int e = t >> 3, k4 = t & 7;
      *reinterpret_cast<float4*>(&As[e * 36 + k4 * 4]) =
          *reinterpret_cast<const float4*>(&x1[((size_t)b * NE + e) * 512 + kt + k4 * 4]);
    }
#pragma unroll
    for (int i = 0; i < 2; i++) {
      const int slot = t + 256 * i;
      const int row = slot >> 4, cg = slot & 15;
      *reinterpret_cast<float4*>(&Bs[row * 64 + cg * 4]) =
          *reinterpret_cast<const float4*>(&w[(size_t)(kt + row) * NC2 + cg * 4]);
    }
    __syncthreads();
#pragma unroll
    for (int kg = 0; kg < 8; kg++) {
      float4 a[2];
#pragma unroll
      for (int i = 0; i < 2; i++)
        a[i] = *reinterpret_cast<const float4*>(&As[(tr * 2 + i) * 36 + kg * 4]);
#pragma unroll
      for (int k2 = 0; k2 < 4; k2++) {
        const float4 bv = *reinterpret_cast<const float4*>(&Bs[(kg * 4 + k2) * 64 + tc * 4]);
#pragma unroll
        for (int i = 0; i < 2; i++) {
          const float av = reinterpret_cast<const float*>(&a[i])[k2];
          acc[i][0] = fmaf(av, bv.x, acc[i][0]);
          acc[i][1] = fmaf(av, bv.y, acc[i][1]);
          acc[i][2] = fmaf(av, bv.z, acc[i][2]);
          acc[i][3] = fmaf(av, bv.w, acc[i][3]);
        }
      }
    }
  }
  const float4 a4s = *reinterpret_cast<const float4*>(&as[tc * 4]);
  const float4 a4d = *reinterpret_cast<const float4*>(&ad[tc * 4]);
#pragma unroll
  for (int i = 0; i < 2; i++) {
    const int e = tr * 2 + i;
    float4 v;
    v.x = acc[i][0]; v.y = acc[i][1]; v.z = acc[i][2]; v.w = acc[i][3];
    *reinterpret_cast<float4*>(&h2[((size_t)b * NE + e) * NC2 + tc * 4]) = v;
    float sv = v.x * a4s.x + v.y * a4s.y + v.z * a4s.z + v.w * a4s.w;
    float dv = v.x * a4d.x + v.y * a4d.y + v.z * a4d.z + v.w * a4d.w;
#pragma unroll
    for (int o = 8; o > 0; o >>= 1) { sv += __shfl_xor(sv, o); dv += __shfl_xor(dv, o); }
    if (tc == 0) { s2[b * NE + e] = sv; d2[b * NE + e] = dv; }
  }
}

// ---------------- GAT2 attention + aggregate + bias ----------------
__global__ __launch_bounds__(64) void k_att2(const float* __restrict__ h2,
    const float* __restrict__ s2, const float* __restrict__ d2,
    const unsigned char* __restrict__ adj, const float* __restrict__ bias,
    float* __restrict__ x2) {
  __shared__ float att[NE];
  const int be = blockIdx.x;
  const int b = be >> 5, i = be & 31;
  const int t = threadIdx.x;
  if (t < NE) {
    float lg = d2[b * NE + i] + s2[b * NE + t];
    lg = lg >= 0.f ? lg : 0.2f * lg;
    if (!adj[((size_t)b * NE + i) * NE + t]) lg = -1e9f;
    att[t] = lg;
  }
  __syncthreads();
  if (t == 0) {
    float m = -1e30f;
#pragma unroll
    for (int j = 0; j < NE; j++) m = fmaxf(m, att[j]);
    float ex[NE];
    float sum = 0.f;
#pragma unroll
    for (int j = 0; j < NE; j++) { ex[j] = __expf(att[j] - m); sum += ex[j]; }
    const float inv = 1.f / sum;
#pragma unroll
    for (int j = 0; j < NE; j++) att[j] = ex[j] * inv;
  }
  __syncthreads();
  float acc = bias[t];
  for (int j = 0; j < NE; j++)
    acc += att[j] * h2[((size_t)b * NE + j) * NC2 + t];
  x2[((size_t)b * NE + i) * NC2 + t] = acc;
}

// ---------------- ctx = mean over entities ----------------
__global__ __launch_bounds__(64) void k_ctx(const float* __restrict__ x2, float* __restrict__ ctx) {
  const int b = blockIdx.x, t = threadIdx.x;
  float s = 0.f;
  for (int e = 0; e < NE; e++) s += x2[((size_t)b * NE + e) * NC2 + t];
  ctx[b * NC2 + t] = s * (1.f / NE);
}

// ---------------- pair feature build (pitch 260) ----------------
__global__ __launch_bounds__(64) void k_pf(const float* __restrict__ x2,
    const float* __restrict__ ctx, const int* __restrict__ pe1, const int* __restrict__ pe2,
    float* __restrict__ pf) {
  const int bp = blockIdx.x;
  const int b = bp >> 4, p = bp & 15;
  const int t = threadIdx.x;
  const int e1 = pe1[b * NP + p], e2 = pe2[b * NP + p];
  const float v1 = x2[((size_t)b * NE + e1) * NC2 + t];
  const float v2 = x2[((size_t)b * NE + e2) * NC2 + t];
  float* row = pf + (size_t)bp * 260;
  row[t] = v1;
  row[64 + t] = v2;
  row[128 + t] = v1 * v2;
  row[192 + t] = ctx[b * NC2 + t];
  if (t == 0) row[256] = logf(fabsf((float)(e1 - e2)) + 1.f);
  if (t < 3) row[257 + t] = 0.f;
}

// ---------------- fe = leaky(LN(pf @ w_fe + b_fe)) ----------------
__global__ __launch_bounds__(256) void k_fe(const float* __restrict__ pf,
    const float* __restrict__ w, const float* __restrict__ bfe,
    const float* __restrict__ g, const float* __restrict__ be, float* __restrict__ fe) {
  __shared__ float sm[4];
  __shared__ float pfs[NP * 260];
  const int b = blockIdx.x, t = threadIdx.x;
  for (int i = t; i < NP * 260; i += 256) pfs[i] = pf[(size_t)b * NP * 260 + i];
  __syncthreads();
  float a0[16], a1[16];
  {
    const float bv0 = bfe[t], bv1 = bfe[t + 256];
#pragma unroll
    for (int p = 0; p < NP; p++) { a0[p] = bv0; a1[p] = bv1; }
  }
  for (int k = 0; k < 256; k += 4) {
    const float w00 = w[(k + 0) * 512 + t], w01 = w[(k + 1) * 512 + t];
    const float w02 = w[(k + 2) * 512 + t], w03 = w[(k + 3) * 512 + t];
    const float w10 = w[(k + 0) * 512 + t + 256], w11 = w[(k + 1) * 512 + t + 256];
    const float w12 = w[(k + 2) * 512 + t + 256], w13 = w[(k + 3) * 512 + t + 256];
#pragma unroll
    for (int p = 0; p < NP; p++) {
      const float4 a4 = *reinterpret_cast<const float4*>(&pfs[p * 260 + k]);
      float x0 = a0[p], x1 = a1[p];
      x0 = fmaf(a4.x, w00, x0); x1 = fmaf(a4.x, w10, x1);
      x0 = fmaf(a4.y, w01, x0); x1 = fmaf(a4.y, w11, x1);
      x0 = fmaf(a4.z, w02, x0); x1 = fmaf(a4.z, w12, x1);
      x0 = fmaf(a4.w, w03, x0); x1 = fmaf(a4.w, w13, x1);
      a0[p] = x0; a1[p] = x1;
    }
  }
  {
    const float w0 = w[256 * 512 + t], w1 = w[256 * 512 + t + 256];
#pragma unroll
    for (int p = 0; p < NP; p++) {
      const float av = pfs[p * 260 + 256];
      a0[p] = fmaf(av, w0, a0[p]);
      a1[p] = fmaf(av, w1, a1[p]);
    }
  }
  const float gv0 = g[t], gv1 = g[t + 256], bev0 = be[t], bev1 = be[t + 256];
  for (int p = 0; p < NP; p++) {
    const float s = blk_sum256(a0[p] + a1[p], sm);
    const float sq = blk_sum256(a0[p] * a0[p] + a1[p] * a1[p], sm);
    const float mean = s * (1.f / 512.f);
    const float var = sq * (1.f / 512.f) - mean * mean;
    const float rr = rsqrtf(var + 1e-5f);
    float n0 = (a0[p] - mean) * rr * gv0 + bev0;
    float n1 = (a1[p] - mean) * rr * gv1 + bev1;
    n0 = n0 >= 0.f ? n0 : 0.01f * n0;
    n1 = n1 >= 0.f ? n1 : 0.01f * n1;
    fe[((size_t)b * NP + p) * 512 + t] = n0;
    fe[((size_t)b * NP + p) * 512 + t + 256] = n1;
  }
}

// ---------------- relation heads: GEMM + LN + leaky + dot + BCE ----------------
__global__ __launch_bounds__(256) void k_rc(const float* __restrict__ fe,
    const float* __restrict__ w1, const float* __restrict__ b1,
    const float* __restrict__ g, const float* __restrict__ be,
    const float* __restrict__ w2, const float* __restrict__ b2,
    const int* __restrict__ ylab, float* __restrict__ zout, float* __restrict__ relacc) {
  __shared__ float sm[4];
  __shared__ float fes[NP * 512];
  const int blk = blockIdx.x;
  const int r = blk >> 6, b = blk & 63;
  const int t = threadIdx.x;
#pragma unroll
  for (int i = 0; i < 8; i++) {
    const int slot = t + 256 * i;
    const int p = slot >> 7, k4 = slot & 127;
    *reinterpret_cast<float4*>(&fes[p * 512 + k4 * 4]) =
        *reinterpret_cast<const float4*>(&fe[((size_t)b * NP + p) * 512 + k4 * 4]);
  }
  __syncthreads();
  float acc[16];
  {
    const float bv = b1[r * 256 + t];
#pragma unroll
    for (int p = 0; p < NP; p++) acc[p] = bv;
  }
  const float* wr = w1 + (size_t)r * 512 * 256;
  for (int k = 0; k < 512; k += 4) {
    const float w0 = wr[(k + 0) * 256 + t], wA = wr[(k + 1) * 256 + t];
    const float wB = wr[(k + 2) * 256 + t], wC = wr[(k + 3) * 256 + t];
#pragma unroll
    for (int p = 0; p < NP; p++) {
      const float4 a4 = *reinterpret_cast<const float4*>(&fes[p * 512 + k]);
      float x = acc[p];
      x = fmaf(a4.x, w0, x); x = fmaf(a4.y, wA, x);
      x = fmaf(a4.z, wB, x); x = fmaf(a4.w, wC, x);
      acc[p] = x;
    }
  }
  const float gv = g[r * 256 + t], bev = be[r * 256 + t], w2v = w2[r * 256 + t];
  const float b2v = b2[r];
  float local = 0.f;
  for (int p = 0; p < NP; p++) {
    const float s = blk_sum256(acc[p], sm);
    const float sq = blk_sum256(acc[p] * acc[p], sm);
    const float mean = s * (1.f / 256.f);
    const float var = sq * (1.f / 256.f) - mean * mean;
    const float rr = rsqrtf(var + 1e-5f);
    float n = (acc[p] - mean) * rr * gv + bev;
    n = n >= 0.f ? n : 0.01f * n;
    const float zp = blk_sum256(n * w2v, sm) + b2v;
    if (t == 0) {
      zout[((size_t)r * NB + b) * NP + p] = zp;
      const float y = (float)ylab[b * NP + p];
      local += -(2.f * y * logsigf(zp) + (1.f - y) * logsigf(-zp));
    }
  }
  if (t == 0) atomicAdd(relacc, local * (1.f / (NB * NP)));
}

// ---------------- finalize total loss ----------------
__global__ __launch_bounds__(64) void k_fin(const float* __restrict__ lossb,
    const float* __restrict__ rel, float* __restrict__ out) {
  float v = lossb[threadIdx.x];
#pragma unroll
  for (int o = 32; o > 0; o >>= 1) v += __shfl_down(v, o);
  if (threadIdx.x == 0) out[TOTOFF] = v * (1.f / NB) + rel[0];
}

extern "C" void kernel_launch(void* const* d_in, const int* in_sizes, int n_in,
                              void* d_out, int out_size, void* d_ws, size_t ws_size,
                              hipStream_t stream) {
  const float* seq = (const float*)d_in[0];
  const int* amask = (const int*)d_in[1];
  const int* nlab = (const int*)d_in[2];
  const int* est = (const int*)d_in[3];
  const int* elen = (const int*)d_in[4];
  const int* pe1 = (const int*)d_in[5];
  const int* pe2 = (const int*)d_in[6];
  const int* plab = (const int*)d_in[7];
  const unsigned char* adj = (const unsigned char*)d_in[8];
  const float* w_ner1 = (const float*)d_in[9];
  const float* b_ner1 = (const float*)d_in[10];
  const float* w_ner2 = (const float*)d_in[11];
  const float* b_ner2 = (const float*)d_in[12];
  const float* crf_start = (const float*)d_in[13];
  const float* crf_end = (const float*)d_in[14];
  const float* crf_trans = (const float*)d_in[15];
  const float* w_gat1 = (const float*)d_in[16];
  const float* a_src1 = (const float*)d_in[17];
  const float* a_dst1 = (const float*)d_in[18];
  const float* b_gat1 = (const float*)d_in[19];
  const float* w_gat2 = (const float*)d_in[20];
  const float* a_src2 = (const float*)d_in[21];
  const float* a_dst2 = (const float*)d_in[22];
  const float* b_gat2 = (const float*)d_in[23];
  const float* w_fe = (const float*)d_in[24];
  const float* b_fe = (const float*)d_in[25];
  const float* g_fe = (const float*)d_in[26];
  const float* be_fe = (const float*)d_in[27];
  const float* w_rc1 = (const float*)d_in[28];
  const float* b_rc1 = (const float*)d_in[29];
  const float* g_rc = (const float*)d_in[30];
  const float* be_rc = (const float*)d_in[31];
  const float* w_rc2 = (const float*)d_in[32];
  const float* b_rc2 = (const float*)d_in[33];

  float* out = (float*)d_out;
  float* ws = (float*)d_ws;
  float* ent = ws + WS_ENT;
  float* hg1 = ws + WS_HG1;
  float* x1 = ws + WS_X1;
  float* h2 = ws + WS_H2;
  float* x2 = ws + WS_X2;
  float* s1 = ws + WS_S1;
  float* d1 = ws + WS_D1;
  float* s2 = ws + WS_S2;
  float* d2 = ws + WS_D2;
  float* ctx = ws + WS_CTX;
  float* pf = ws + WS_PF;
  float* fe = ws + WS_FE;
  float* crfb = ws + WS_CRF;
  float* rel = ws + WS_REL;

  hipMemsetAsync(rel, 0, sizeof(float), stream);

  k_ner<<<512, 256, 0, stream>>>(seq, w_ner1, b_ner1, w_ner2, b_ner2, out);
  k_crf<<<64, 64, 0, stream>>>(out, nlab, amask, crf_start, crf_end, crf_trans, crfb);
  k_ent<<<NB * NE, 256, 0, stream>>>(seq, est, elen, ent);
  k_g1<<<NB * 4, 256, 0, stream>>>(ent, w_gat1, hg1);
  k_sd1<<<NB * NE, 128, 0, stream>>>(hg1, a_src1, a_dst1, s1, d1);
  k_att1<<<NB * NHEADS * NE, 128, 0, stream>>>(hg1, s1, d1, adj, b_gat1, x1);
  k_g2<<<NB, 256, 0, stream>>>(x1, w_gat2, a_src2, a_dst2, h2, s2, d2);
  k_att2<<<NB * NE, 64, 0, stream>>>(h2, s2, d2, adj, b_gat2, x2);
  k_ctx<<<NB, 64, 0, stream>>>(x2, ctx);
  k_pf<<<NB * NP, 64, 0, stream>>>(x2, ctx, pe1, pe2, pf);
  k_fe<<<NB, 256, 0, stream>>>(pf, w_fe, b_fe, g_fe, be_fe, fe);
  k_rc<<<NR * NB, 256, 0, stream>>>(fe, w_rc1, b_rc1, g_rc, be_rc, w_rc2, b_rc2,
                                    plab, out + ZOFF, rel);
  k_fin<<<1, 64, 0, stream>>>(crfb, rel, out);
}

// Round 3
// 663.827 us; speedup vs baseline: 3.0827x; 1.2025x over previous
//
#include <hip/hip_runtime.h>
#include <math.h>

// Problem: NERRelationModel_84963043050124
// B=64 S=512 H=768 E=32 P=16 K=9 R=6 HEADS=4 C1=128 C2=64 FEAT=257
// Outputs: ner_logits [B,S,K]=294912, z [R,B,P]=6144, total [1] -> 301057 f32

#define NB 64
#define NS 512
#define NH 768
#define NE 32
#define NP 16
#define NK 9
#define NR 6
#define NHEADS 4
#define NC1 128
#define NC2 64

#define ZOFF 294912
#define TOTOFF 301056

// ---- workspace layout (float offsets) ----
#define WS_ENT   0u           // [B,E,768]
#define WS_HG1   1572864u     // [B,E,512]
#define WS_X1    2621440u     // [B,E,512]
#define WS_H2    3670016u     // [B,E,64]
#define WS_X2    3801088u     // [B,E,64]
#define WS_S1    3932160u     // [B,4,E]
#define WS_D1    3940352u
#define WS_S2    3948544u     // [B,E]
#define WS_D2    3950592u
#define WS_CTX   3952640u     // [B,64]
#define WS_PF    3956736u     // [B*P, 260] padded pitch
#define WS_FE    4222976u     // [B,P,512]
#define WS_CRF   4747264u     // [64]
#define WS_REL   4747328u     // [1]

__device__ __forceinline__ float blk_sum256(float v, float* sm) {
#pragma unroll
  for (int o = 32; o > 0; o >>= 1) v += __shfl_down(v, o);
  if ((threadIdx.x & 63) == 0) sm[threadIdx.x >> 6] = v;
  __syncthreads();
  v = sm[0] + sm[1] + sm[2] + sm[3];
  __syncthreads();
  return v;
}

__device__ __forceinline__ float logsigf(float x) {
  if (x >= 0.f) return -log1pf(__expf(-x));
  return x - log1pf(__expf(x));
}

// ---------------- NER head: logits = relu(seq@W1+b1)@W2+b2 ----------------
__global__ __launch_bounds__(256) void k_ner(const float* __restrict__ seq,
    const float* __restrict__ w1, const float* __restrict__ b1,
    const float* __restrict__ w2, const float* __restrict__ b2,
    float* __restrict__ out) {
  __shared__ float As[64 * 36];    // [tok][k], pitch 36
  __shared__ float Bs[32 * 256];   // [k][col]
  __shared__ float w2s[256 * NK];
  __shared__ float b2s[NK];
  const int t = threadIdx.x;
  const int tok0 = blockIdx.x * 64;
  const int tc = t & 31, tr = t >> 5;
  for (int i = t; i < 256 * NK; i += 256) w2s[i] = w2[i];
  if (t < NK) b2s[t] = b2[t];
  float acc[8][8];
  {
    const float4 bA = *reinterpret_cast<const float4*>(&b1[tc * 4]);
    const float4 bB = *reinterpret_cast<const float4*>(&b1[128 + tc * 4]);
#pragma unroll
    for (int i = 0; i < 8; i++) {
      acc[i][0] = bA.x; acc[i][1] = bA.y; acc[i][2] = bA.z; acc[i][3] = bA.w;
      acc[i][4] = bB.x; acc[i][5] = bB.y; acc[i][6] = bB.z; acc[i][7] = bB.w;
    }
  }
  for (int kt = 0; kt < NH; kt += 32) {
    __syncthreads();
#pragma unroll
    for (int i = 0; i < 2; i++) {
      const int slot = t + 256 * i;
      const int ta = slot >> 3, k4 = slot & 7;
      *reinterpret_cast<float4*>(&As[ta * 36 + k4 * 4]) =
          *reinterpret_cast<const float4*>(&seq[(size_t)(tok0 + ta) * NH + kt + k4 * 4]);
    }
#pragma unroll
    for (int i = 0; i < 8; i++) {
      const int slot = t + 256 * i;
      const int row = slot >> 6, cg = slot & 63;
      *reinterpret_cast<float4*>(&Bs[row * 256 + cg * 4]) =
          *reinterpret_cast<const float4*>(&w1[(size_t)(kt + row) * 256 + cg * 4]);
    }
    __syncthreads();
#pragma unroll
    for (int kg = 0; kg < 8; kg++) {
      float4 a[8];
#pragma unroll
      for (int i = 0; i < 8; i++)
        a[i] = *reinterpret_cast<const float4*>(&As[(tr * 8 + i) * 36 + kg * 4]);
#pragma unroll
      for (int k2 = 0; k2 < 4; k2++) {
        const float4 bA = *reinterpret_cast<const float4*>(&Bs[(kg * 4 + k2) * 256 + tc * 4]);
        const float4 bB = *reinterpret_cast<const float4*>(&Bs[(kg * 4 + k2) * 256 + 128 + tc * 4]);
#pragma unroll
        for (int i = 0; i < 8; i++) {
          const float av = reinterpret_cast<const float*>(&a[i])[k2];
          acc[i][0] = fmaf(av, bA.x, acc[i][0]);
          acc[i][1] = fmaf(av, bA.y, acc[i][1]);
          acc[i][2] = fmaf(av, bA.z, acc[i][2]);
          acc[i][3] = fmaf(av, bA.w, acc[i][3]);
          acc[i][4] = fmaf(av, bB.x, acc[i][4]);
          acc[i][5] = fmaf(av, bB.y, acc[i][5]);
          acc[i][6] = fmaf(av, bB.z, acc[i][6]);
          acc[i][7] = fmaf(av, bB.w, acc[i][7]);
        }
      }
    }
  }
#pragma unroll
  for (int i = 0; i < 8; i++) {
    float r[8];
#pragma unroll
    for (int j = 0; j < 8; j++) r[j] = fmaxf(acc[i][j], 0.f);
    const int tok = tok0 + tr * 8 + i;
    float z[NK];
#pragma unroll
    for (int c = 0; c < NK; c++) {
      float p = 0.f;
#pragma unroll
      for (int j = 0; j < 4; j++) p = fmaf(r[j], w2s[(tc * 4 + j) * NK + c], p);
#pragma unroll
      for (int j = 0; j < 4; j++) p = fmaf(r[4 + j], w2s[(128 + tc * 4 + j) * NK + c], p);
#pragma unroll
      for (int o = 16; o > 0; o >>= 1) p += __shfl_xor(p, o);
      z[c] = p;
    }
    if (tc == 0) {
#pragma unroll
      for (int c = 0; c < NK; c++) out[(size_t)tok * NK + c] = z[c] + b2s[c];
    }
  }
}

// ---------------- CRF NLL: log-semiring tree reduction ----------------
// Z = lse(alpha0^T . M_1 ... M_511 + end); M_s[i][j] = trans[i][j]+em[s][j]
// (identity when mask[s]==0). Tree over two halves of 256 steps each to fit
// 64KB LDS. Numerator: parallel 64-lane sum (exact for all-ones mask).
// grid 64, 256 threads.
__global__ __launch_bounds__(256) void k_crf(const float* __restrict__ em,
    const int* __restrict__ tags, const int* __restrict__ mask,
    const float* __restrict__ startv, const float* __restrict__ endv,
    const float* __restrict__ trans, float* __restrict__ lossb) {
  __shared__ float bufA[128 * 81];   // 41472 B
  __shared__ float bufB[64 * 81];    // 20736 B
  __shared__ float trs[81];
  __shared__ float halfRes[2][81];
  __shared__ float red[16];
  const int b = blockIdx.x, t = threadIdx.x;
  const float* emb = em + (size_t)b * NS * NK;
  const int* mk = mask + b * NS;
  const int* tg = tags + b * NS;
  if (t < 81) trs[t] = trans[t];
  // numerator on wave 0
  if (t < 64) {
    float num = 0.f;
    int lastS = 0;
#pragma unroll
    for (int o = 0; o < 8; o++) {
      const int s = t * 8 + o;
      if (s >= 1 && mk[s] > 0) {
        const int cur = tg[s], prv = tg[s - 1];
        num += trans[prv * NK + cur] + emb[s * NK + cur];
        lastS = s;
      }
    }
#pragma unroll
    for (int o = 32; o > 0; o >>= 1) {
      num += __shfl_xor(num, o);
      lastS = max(lastS, __shfl_xor(lastS, o));
    }
    if (t == 0) {
      const int t0 = tg[0];
      red[0] = startv[t0] + emb[t0] + num + endv[tg[lastS]];
    }
  }
  __syncthreads();

  for (int h = 0; h < 2; h++) {
    const int s0 = 1 + h * 256;
    __syncthreads();
    // leaves: pair steps (s0+2p, s0+2p+1) -> 128 matrices in bufA
    for (int idx = t; idx < 128 * 81; idx += 256) {
      const int p = idx / 81, e = idx % 81, i = e / 9, j = e % 9;
      const int sa = s0 + 2 * p, sb = sa + 1;
      const bool ma = (sa < NS) && (mk[sa] > 0);
      const bool mb = (sb < NS) && (mk[sb] > 0);
      float r;
      if (ma && mb) {
        float v[9], mx = -1e30f;
#pragma unroll
        for (int m = 0; m < 9; m++) {
          v[m] = trs[i * 9 + m] + emb[sa * 9 + m] + trs[m * 9 + j];
          mx = fmaxf(mx, v[m]);
        }
        float sum = 0.f;
#pragma unroll
        for (int m = 0; m < 9; m++) sum += __expf(v[m] - mx);
        r = mx + __logf(sum) + emb[sb * 9 + j];
      } else if (ma) {
        r = trs[e] + emb[sa * 9 + j];
      } else if (mb) {
        r = trs[e] + emb[sb * 9 + j];
      } else {
        r = (i == j) ? 0.f : -1e30f;
      }
      bufA[p * 81 + e] = r;
    }
    // tree: 128 -> 1
    float* src = bufA;
    float* dst = bufB;
    for (int n = 128; n > 1; n >>= 1) {
      __syncthreads();
      const int half = n >> 1;
      for (int idx = t; idx < half * 81; idx += 256) {
        const int q = idx / 81, e = idx % 81, i = e / 9, j = e % 9;
        const float* A = src + (size_t)(2 * q) * 81;
        const float* Bm = src + (size_t)(2 * q + 1) * 81;
        float v[9], mx = -1e30f;
#pragma unroll
        for (int m = 0; m < 9; m++) {
          v[m] = A[i * 9 + m] + Bm[m * 9 + j];
          mx = fmaxf(mx, v[m]);
        }
        float sum = 0.f;
#pragma unroll
        for (int m = 0; m < 9; m++) sum += __expf(v[m] - mx);
        dst[q * 81 + e] = mx + __logf(sum);
      }
      float* tmp = src; src = dst; dst = tmp;
    }
    __syncthreads();
    if (t < 81) halfRes[h][t] = src[t];
  }
  __syncthreads();
  // alpha0 through halfRes[0] then halfRes[1], add end, lse.
  if (t < 9) {
    float v[9], mx = -1e30f;
#pragma unroll
    for (int i2 = 0; i2 < 9; i2++) {
      v[i2] = startv[i2] + emb[i2] + halfRes[0][i2 * 9 + t];
      mx = fmaxf(mx, v[i2]);
    }
    float sum = 0.f;
#pragma unroll
    for (int i2 = 0; i2 < 9; i2++) sum += __expf(v[i2] - mx);
    red[1 + t] = mx + __logf(sum);
  }
  __syncthreads();
  if (t < 9) {
    float v[9], mx = -1e30f;
#pragma unroll
    for (int i2 = 0; i2 < 9; i2++) {
      v[i2] = red[1 + i2] + halfRes[1][i2 * 9 + t];
      mx = fmaxf(mx, v[i2]);
    }
    float sum = 0.f;
#pragma unroll
    for (int i2 = 0; i2 < 9; i2++) sum += __expf(v[i2] - mx);
    halfRes[0][t] = mx + __logf(sum) + endv[t];
  }
  __syncthreads();
  if (t == 0) {
    float mx = -1e30f;
#pragma unroll
    for (int j = 0; j < 9; j++) mx = fmaxf(mx, halfRes[0][j]);
    float sum = 0.f;
#pragma unroll
    for (int j = 0; j < 9; j++) sum += __expf(halfRes[0][j] - mx);
    lossb[b] = (mx + __logf(sum)) - red[0];
  }
}

// ---------------- entity span mean pool ----------------
__global__ __launch_bounds__(256) void k_ent(const float* __restrict__ seq,
    const int* __restrict__ est, const int* __restrict__ elen, float* __restrict__ ent) {
  const int be = blockIdx.x;
  const int b = be >> 5, e = be & 31;
  const int st = est[b * NE + e];
  int en = st + elen[b * NE + e];
  en = min(max(en, 0), NS - 1);
  const float inv = 1.f / (float)(en - st + 1);
  for (int c = threadIdx.x; c < NH; c += 256) {
    float s = 0.f;
    for (int r = st; r <= en; r++) s += seq[((size_t)b * NS + r) * NH + c];
    ent[((size_t)b * NE + e) * NH + c] = s * inv;
  }
}

// ---------------- GAT1 GEMM: h = ent @ w_gat1 (768->512) ----------------
__global__ __launch_bounds__(256) void k_g1(const float* __restrict__ ent,
    const float* __restrict__ w, float* __restrict__ hout) {
  __shared__ float As[32 * 36];
  __shared__ float Bs[32 * 128];
  const int b = blockIdx.x >> 2, cb = blockIdx.x & 3;
  const int t = threadIdx.x;
  const int tc = t & 31, tr = t >> 5;
  float acc[4][4];
#pragma unroll
  for (int i = 0; i < 4; i++)
#pragma unroll
    for (int j = 0; j < 4; j++) acc[i][j] = 0.f;
  for (int kt = 0; kt < NH; kt += 32) {
    __syncthreads();
    {
      const int e = t >> 3, k4 = t & 7;
      *reinterpret_cast<float4*>(&As[e * 36 + k4 * 4]) =
          *reinterpret_cast<const float4*>(&ent[((size_t)b * NE + e) * NH + kt + k4 * 4]);
    }
#pragma unroll
    for (int i = 0; i < 4; i++) {
      const int slot = t + 256 * i;
      const int row = slot >> 5, cg = slot & 31;
      *reinterpret_cast<float4*>(&Bs[row * 128 + cg * 4]) =
          *reinterpret_cast<const float4*>(&w[(size_t)(kt + row) * 512 + cb * 128 + cg * 4]);
    }
    __syncthreads();
#pragma unroll
    for (int kg = 0; kg < 8; kg++) {
      float4 a[4];
#pragma unroll
      for (int i = 0; i < 4; i++)
        a[i] = *reinterpret_cast<const float4*>(&As[(tr * 4 + i) * 36 + kg * 4]);
#pragma unroll
      for (int k2 = 0; k2 < 4; k2++) {
        const float4 bv = *reinterpret_cast<const float4*>(&Bs[(kg * 4 + k2) * 128 + tc * 4]);
#pragma unroll
        for (int i = 0; i < 4; i++) {
          const float av = reinterpret_cast<const float*>(&a[i])[k2];
          acc[i][0] = fmaf(av, bv.x, acc[i][0]);
          acc[i][1] = fmaf(av, bv.y, acc[i][1]);
          acc[i][2] = fmaf(av, bv.z, acc[i][2]);
          acc[i][3] = fmaf(av, bv.w, acc[i][3]);
        }
      }
    }
  }
#pragma unroll
  for (int i = 0; i < 4; i++) {
    float4 v;
    v.x = acc[i][0]; v.y = acc[i][1]; v.z = acc[i][2]; v.w = acc[i][3];
    *reinterpret_cast<float4*>(&hout[((size_t)b * NE + tr * 4 + i) * 512 + cb * 128 + tc * 4]) = v;
  }
}

// ---------------- GAT1 attention src/dst dots ----------------
__global__ __launch_bounds__(128) void k_sd1(const float* __restrict__ h,
    const float* __restrict__ as, const float* __restrict__ ad,
    float* __restrict__ s1, float* __restrict__ d1) {
  __shared__ float sm[4];
  const int be = blockIdx.x;
  const int b = be >> 5, e = be & 31;
  const int t = threadIdx.x;
  for (int hd = 0; hd < NHEADS; hd++) {
    const float v = h[((size_t)b * NE + e) * 512 + hd * NC1 + t];
    float sv = v * as[hd * NC1 + t];
    float dv = v * ad[hd * NC1 + t];
#pragma unroll
    for (int o = 32; o > 0; o >>= 1) { sv += __shfl_xor(sv, o); dv += __shfl_xor(dv, o); }
    if ((t & 63) == 0) { sm[(t >> 6) * 2] = sv; sm[(t >> 6) * 2 + 1] = dv; }
    __syncthreads();
    if (t == 0) {
      s1[(b * NHEADS + hd) * NE + e] = sm[0] + sm[2];
      d1[(b * NHEADS + hd) * NE + e] = sm[1] + sm[3];
    }
    __syncthreads();
  }
}

// ---------------- GAT1 attention + aggregate + bias + relu ----------------
__global__ __launch_bounds__(128) void k_att1(const float* __restrict__ h,
    const float* __restrict__ s1, const float* __restrict__ d1,
    const unsigned char* __restrict__ adj, const float* __restrict__ bias,
    float* __restrict__ x1) {
  __shared__ float att[NE];
  const int blk = blockIdx.x;
  const int i = blk & 31, hd = (blk >> 5) & 3, b = blk >> 7;
  const int t = threadIdx.x;
  if (t < NE) {
    float lg = d1[(b * NHEADS + hd) * NE + i] + s1[(b * NHEADS + hd) * NE + t];
    lg = lg >= 0.f ? lg : 0.2f * lg;
    if (!adj[((size_t)b * NE + i) * NE + t]) lg = -1e9f;
    att[t] = lg;
  }
  __syncthreads();
  if (t == 0) {
    float m = -1e30f;
#pragma unroll
    for (int j = 0; j < NE; j++) m = fmaxf(m, att[j]);
    float ex[NE];
    float sum = 0.f;
#pragma unroll
    for (int j = 0; j < NE; j++) { ex[j] = __expf(att[j] - m); sum += ex[j]; }
    const float inv = 1.f / sum;
#pragma unroll
    for (int j = 0; j < NE; j++) att[j] = ex[j] * inv;
  }
  __syncthreads();
  float acc = bias[hd * NC1 + t];
  for (int j = 0; j < NE; j++)
    acc += att[j] * h[((size_t)b * NE + j) * 512 + hd * NC1 + t];
  x1[((size_t)b * NE + i) * 512 + hd * NC1 + t] = fmaxf(acc, 0.f);
}

// ---------------- GAT2 GEMM + src/dst dots ----------------
__global__ __launch_bounds__(256) void k_g2(const float* __restrict__ x1,
    const float* __restrict__ w, const float* __restrict__ as, const float* __restrict__ ad,
    float* __restrict__ h2, float* __restrict__ s2, float* __restrict__ d2) {
  __shared__ float As[32 * 36];
  __shared__ float Bs[32 * 64];
  const int b = blockIdx.x;
  const int t = threadIdx.x;
  const int tc = t & 15, tr = t >> 4;
  float acc[2][4];
#pragma unroll
  for (int i = 0; i < 2; i++)
#pragma unroll
    for (int j = 0; j < 4; j++) acc[i][j] = 0.f;
  for (int kt = 0; kt < 512; kt += 32) {
    __syncthreads();
    {
      const int e = t >> 3, k4 = t & 7;
      *reinterpret_cast<float4*>(&As[e * 36 + k4 * 4]) =
          *reinterpret_cast<const float4*>(&x1[((size_t)b * NE + e) * 512 + kt + k4 * 4]);
    }
#pragma unroll
    for (int i = 0; i < 2; i++) {
      const int slot = t + 256 * i;
      const int row = slot >> 4, cg = slot & 15;
      *reinterpret_cast<float4*>(&Bs[row * 64 + cg * 4]) =
          *reinterpret_cast<const float4*>(&w[(size_t)(kt + row) * NC2 + cg * 4]);
    }
    __syncthreads();
#pragma unroll
    for (int kg = 0; kg < 8; kg++) {
      float4 a[2];
#pragma unroll
      for (int i = 0; i < 2; i++)
        a[i] = *reinterpret_cast<const float4*>(&As[(tr * 2 + i) * 36 + kg * 4]);
#pragma unroll
      for (int k2 = 0; k2 < 4; k2++) {
        const float4 bv = *reinterpret_cast<const float4*>(&Bs[(kg * 4 + k2) * 64 + tc * 4]);
#pragma unroll
        for (int i = 0; i < 2; i++) {
          const float av = reinterpret_cast<const float*>(&a[i])[k2];
          acc[i][0] = fmaf(av, bv.x, acc[i][0]);
          acc[i][1] = fmaf(av, bv.y, acc[i][1]);
          acc[i][2] = fmaf(av, bv.z, acc[i][2]);
          acc[i][3] = fmaf(av, bv.w, acc[i][3]);
        }
      }
    }
  }
  const float4 a4s = *reinterpret_cast<const float4*>(&as[tc * 4]);
  const float4 a4d = *reinterpret_cast<const float4*>(&ad[tc * 4]);
#pragma unroll
  for (int i = 0; i < 2; i++) {
    const int e = tr * 2 + i;
    float4 v;
    v.x = acc[i][0]; v.y = acc[i][1]; v.z = acc[i][2]; v.w = acc[i][3];
    *reinterpret_cast<float4*>(&h2[((size_t)b * NE + e) * NC2 + tc * 4]) = v;
    float sv = v.x * a4s.x + v.y * a4s.y + v.z * a4s.z + v.w * a4s.w;
    float dv = v.x * a4d.x + v.y * a4d.y + v.z * a4d.z + v.w * a4d.w;
#pragma unroll
    for (int o = 8; o > 0; o >>= 1) { sv += __shfl_xor(sv, o); dv += __shfl_xor(dv, o); }
    if (tc == 0) { s2[b * NE + e] = sv; d2[b * NE + e] = dv; }
  }
}

// ---------------- GAT2 attention + aggregate + bias ----------------
__global__ __launch_bounds__(64) void k_att2(const float* __restrict__ h2,
    const float* __restrict__ s2, const float* __restrict__ d2,
    const unsigned char* __restrict__ adj, const float* __restrict__ bias,
    float* __restrict__ x2) {
  __shared__ float att[NE];
  const int be = blockIdx.x;
  const int b = be >> 5, i = be & 31;
  const int t = threadIdx.x;
  if (t < NE) {
    float lg = d2[b * NE + i] + s2[b * NE + t];
    lg = lg >= 0.f ? lg : 0.2f * lg;
    if (!adj[((size_t)b * NE + i) * NE + t]) lg = -1e9f;
    att[t] = lg;
  }
  __syncthreads();
  if (t == 0) {
    float m = -1e30f;
#pragma unroll
    for (int j = 0; j < NE; j++) m = fmaxf(m, att[j]);
    float ex[NE];
    float sum = 0.f;
#pragma unroll
    for (int j = 0; j < NE; j++) { ex[j] = __expf(att[j] - m); sum += ex[j]; }
    const float inv = 1.f / sum;
#pragma unroll
    for (int j = 0; j < NE; j++) att[j] = ex[j] * inv;
  }
  __syncthreads();
  float acc = bias[t];
  for (int j = 0; j < NE; j++)
    acc += att[j] * h2[((size_t)b * NE + j) * NC2 + t];
  x2[((size_t)b * NE + i) * NC2 + t] = acc;
}

// ---------------- ctx = mean over entities ----------------
__global__ __launch_bounds__(64) void k_ctx(const float* __restrict__ x2, float* __restrict__ ctx) {
  const int b = blockIdx.x, t = threadIdx.x;
  float s = 0.f;
  for (int e = 0; e < NE; e++) s += x2[((size_t)b * NE + e) * NC2 + t];
  ctx[b * NC2 + t] = s * (1.f / NE);
}

// ---------------- pair feature build (pitch 260) ----------------
__global__ __launch_bounds__(64) void k_pf(const float* __restrict__ x2,
    const float* __restrict__ ctx, const int* __restrict__ pe1, const int* __restrict__ pe2,
    float* __restrict__ pf) {
  const int bp = blockIdx.x;
  const int b = bp >> 4, p = bp & 15;
  const int t = threadIdx.x;
  const int e1 = pe1[b * NP + p], e2 = pe2[b * NP + p];
  const float v1 = x2[((size_t)b * NE + e1) * NC2 + t];
  const float v2 = x2[((size_t)b * NE + e2) * NC2 + t];
  float* row = pf + (size_t)bp * 260;
  row[t] = v1;
  row[64 + t] = v2;
  row[128 + t] = v1 * v2;
  row[192 + t] = ctx[b * NC2 + t];
  if (t == 0) row[256] = logf(fabsf((float)(e1 - e2)) + 1.f);
  if (t < 3) row[257 + t] = 0.f;
}

// ---------------- fe = leaky(LN(pf @ w_fe + b_fe)) ----------------
__global__ __launch_bounds__(256) void k_fe(const float* __restrict__ pf,
    const float* __restrict__ w, const float* __restrict__ bfe,
    const float* __restrict__ g, const float* __restrict__ be, float* __restrict__ fe) {
  __shared__ float sm[4];
  __shared__ float pfs[NP * 260];
  const int b = blockIdx.x, t = threadIdx.x;
  for (int i = t; i < NP * 260; i += 256) pfs[i] = pf[(size_t)b * NP * 260 + i];
  __syncthreads();
  float a0[16], a1[16];
  {
    const float bv0 = bfe[t], bv1 = bfe[t + 256];
#pragma unroll
    for (int p = 0; p < NP; p++) { a0[p] = bv0; a1[p] = bv1; }
  }
  for (int k = 0; k < 256; k += 4) {
    const float w00 = w[(k + 0) * 512 + t], w01 = w[(k + 1) * 512 + t];
    const float w02 = w[(k + 2) * 512 + t], w03 = w[(k + 3) * 512 + t];
    const float w10 = w[(k + 0) * 512 + t + 256], w11 = w[(k + 1) * 512 + t + 256];
    const float w12 = w[(k + 2) * 512 + t + 256], w13 = w[(k + 3) * 512 + t + 256];
#pragma unroll
    for (int p = 0; p < NP; p++) {
      const float4 a4 = *reinterpret_cast<const float4*>(&pfs[p * 260 + k]);
      float x0 = a0[p], x1 = a1[p];
      x0 = fmaf(a4.x, w00, x0); x1 = fmaf(a4.x, w10, x1);
      x0 = fmaf(a4.y, w01, x0); x1 = fmaf(a4.y, w11, x1);
      x0 = fmaf(a4.z, w02, x0); x1 = fmaf(a4.z, w12, x1);
      x0 = fmaf(a4.w, w03, x0); x1 = fmaf(a4.w, w13, x1);
      a0[p] = x0; a1[p] = x1;
    }
  }
  {
    const float w0 = w[256 * 512 + t], w1 = w[256 * 512 + t + 256];
#pragma unroll
    for (int p = 0; p < NP; p++) {
      const float av = pfs[p * 260 + 256];
      a0[p] = fmaf(av, w0, a0[p]);
      a1[p] = fmaf(av, w1, a1[p]);
    }
  }
  const float gv0 = g[t], gv1 = g[t + 256], bev0 = be[t], bev1 = be[t + 256];
  for (int p = 0; p < NP; p++) {
    const float s = blk_sum256(a0[p] + a1[p], sm);
    const float sq = blk_sum256(a0[p] * a0[p] + a1[p] * a1[p], sm);
    const float mean = s * (1.f / 512.f);
    const float var = sq * (1.f / 512.f) - mean * mean;
    const float rr = rsqrtf(var + 1e-5f);
    float n0 = (a0[p] - mean) * rr * gv0 + bev0;
    float n1 = (a1[p] - mean) * rr * gv1 + bev1;
    n0 = n0 >= 0.f ? n0 : 0.01f * n0;
    n1 = n1 >= 0.f ? n1 : 0.01f * n1;
    fe[((size_t)b * NP + p) * 512 + t] = n0;
    fe[((size_t)b * NP + p) * 512 + t + 256] = n1;
  }
}

// ---------------- relation heads: GEMM + LN + leaky + dot + BCE ----------------
__global__ __launch_bounds__(256) void k_rc(const float* __restrict__ fe,
    const float* __restrict__ w1, const float* __restrict__ b1,
    const float* __restrict__ g, const float* __restrict__ be,
    const float* __restrict__ w2, const float* __restrict__ b2,
    const int* __restrict__ ylab, float* __restrict__ zout, float* __restrict__ relacc) {
  __shared__ float sm[4];
  __shared__ float fes[NP * 512];
  const int blk = blockIdx.x;
  const int r = blk >> 6, b = blk & 63;
  const int t = threadIdx.x;
#pragma unroll
  for (int i = 0; i < 8; i++) {
    const int slot = t + 256 * i;
    const int p = slot >> 7, k4 = slot & 127;
    *reinterpret_cast<float4*>(&fes[p * 512 + k4 * 4]) =
        *reinterpret_cast<const float4*>(&fe[((size_t)b * NP + p) * 512 + k4 * 4]);
  }
  __syncthreads();
  float acc[16];
  {
    const float bv = b1[r * 256 + t];
#pragma unroll
    for (int p = 0; p < NP; p++) acc[p] = bv;
  }
  const float* wr = w1 + (size_t)r * 512 * 256;
  for (int k = 0; k < 512; k += 4) {
    const float w0 = wr[(k + 0) * 256 + t], wA = wr[(k + 1) * 256 + t];
    const float wB = wr[(k + 2) * 256 + t], wC = wr[(k + 3) * 256 + t];
#pragma unroll
    for (int p = 0; p < NP; p++) {
      const float4 a4 = *reinterpret_cast<const float4*>(&fes[p * 512 + k]);
      float x = acc[p];
      x = fmaf(a4.x, w0, x); x = fmaf(a4.y, wA, x);
      x = fmaf(a4.z, wB, x); x = fmaf(a4.w, wC, x);
      acc[p] = x;
    }
  }
  const float gv = g[r * 256 + t], bev = be[r * 256 + t], w2v = w2[r * 256 + t];
  const float b2v = b2[r];
  float local = 0.f;
  for (int p = 0; p < NP; p++) {
    const float s = blk_sum256(acc[p], sm);
    const float sq = blk_sum256(acc[p] * acc[p], sm);
    const float mean = s * (1.f / 256.f);
    const float var = sq * (1.f / 256.f) - mean * mean;
    const float rr = rsqrtf(var + 1e-5f);
    float n = (acc[p] - mean) * rr * gv + bev;
    n = n >= 0.f ? n : 0.01f * n;
    const float zp = blk_sum256(n * w2v, sm) + b2v;
    if (t == 0) {
      zout[((size_t)r * NB + b) * NP + p] = zp;
      const float y = (float)ylab[b * NP + p];
      local += -(2.f * y * logsigf(zp) + (1.f - y) * logsigf(-zp));
    }
  }
  if (t == 0) atomicAdd(relacc, local * (1.f / (NB * NP)));
}

// ---------------- finalize total loss ----------------
__global__ __launch_bounds__(64) void k_fin(const float* __restrict__ lossb,
    const float* __restrict__ rel, float* __restrict__ out) {
  float v = lossb[threadIdx.x];
#pragma unroll
  for (int o = 32; o > 0; o >>= 1) v += __shfl_down(v, o);
  if (threadIdx.x == 0) out[TOTOFF] = v * (1.f / NB) + rel[0];
}

extern "C" void kernel_launch(void* const* d_in, const int* in_sizes, int n_in,
                              void* d_out, int out_size, void* d_ws, size_t ws_size,
                              hipStream_t stream) {
  const float* seq = (const float*)d_in[0];
  const int* amask = (const int*)d_in[1];
  const int* nlab = (const int*)d_in[2];
  const int* est = (const int*)d_in[3];
  const int* elen = (const int*)d_in[4];
  const int* pe1 = (const int*)d_in[5];
  const int* pe2 = (const int*)d_in[6];
  const int* plab = (const int*)d_in[7];
  const unsigned char* adj = (const unsigned char*)d_in[8];
  const float* w_ner1 = (const float*)d_in[9];
  const float* b_ner1 = (const float*)d_in[10];
  const float* w_ner2 = (const float*)d_in[11];
  const float* b_ner2 = (const float*)d_in[12];
  const float* crf_start = (const float*)d_in[13];
  const float* crf_end = (const float*)d_in[14];
  const float* crf_trans = (const float*)d_in[15];
  const float* w_gat1 = (const float*)d_in[16];
  const float* a_src1 = (const float*)d_in[17];
  const float* a_dst1 = (const float*)d_in[18];
  const float* b_gat1 = (const float*)d_in[19];
  const float* w_gat2 = (const float*)d_in[20];
  const float* a_src2 = (const float*)d_in[21];
  const float* a_dst2 = (const float*)d_in[22];
  const float* b_gat2 = (const float*)d_in[23];
  const float* w_fe = (const float*)d_in[24];
  const float* b_fe = (const float*)d_in[25];
  const float* g_fe = (const float*)d_in[26];
  const float* be_fe = (const float*)d_in[27];
  const float* w_rc1 = (const float*)d_in[28];
  const float* b_rc1 = (const float*)d_in[29];
  const float* g_rc = (const float*)d_in[30];
  const float* be_rc = (const float*)d_in[31];
  const float* w_rc2 = (const float*)d_in[32];
  const float* b_rc2 = (const float*)d_in[33];

  float* out = (float*)d_out;
  float* ws = (float*)d_ws;
  float* ent = ws + WS_ENT;
  float* hg1 = ws + WS_HG1;
  float* x1 = ws + WS_X1;
  float* h2 = ws + WS_H2;
  float* x2 = ws + WS_X2;
  float* s1 = ws + WS_S1;
  float* d1 = ws + WS_D1;
  float* s2 = ws + WS_S2;
  float* d2 = ws + WS_D2;
  float* ctx = ws + WS_CTX;
  float* pf = ws + WS_PF;
  float* fe = ws + WS_FE;
  float* crfb = ws + WS_CRF;
  float* rel = ws + WS_REL;

  hipMemsetAsync(rel, 0, sizeof(float), stream);

  k_ner<<<512, 256, 0, stream>>>(seq, w_ner1, b_ner1, w_ner2, b_ner2, out);
  k_crf<<<64, 256, 0, stream>>>(out, nlab, amask, crf_start, crf_end, crf_trans, crfb);
  k_ent<<<NB * NE, 256, 0, stream>>>(seq, est, elen, ent);
  k_g1<<<NB * 4, 256, 0, stream>>>(ent, w_gat1, hg1);
  k_sd1<<<NB * NE, 128, 0, stream>>>(hg1, a_src1, a_dst1, s1, d1);
  k_att1<<<NB * NHEADS * NE, 128, 0, stream>>>(hg1, s1, d1, adj, b_gat1, x1);
  k_g2<<<NB, 256, 0, stream>>>(x1, w_gat2, a_src2, a_dst2, h2, s2, d2);
  k_att2<<<NB * NE, 64, 0, stream>>>(h2, s2, d2, adj, b_gat2, x2);
  k_ctx<<<NB, 64, 0, stream>>>(x2, ctx);
  k_pf<<<NB * NP, 64, 0, stream>>>(x2, ctx, pe1, pe2, pf);
  k_fe<<<NB, 256, 0, stream>>>(pf, w_fe, b_fe, g_fe, be_fe, fe);
  k_rc<<<NR * NB, 256, 0, stream>>>(fe, w_rc1, b_rc1, g_rc, be_rc, w_rc2, b_rc2,
                                    plab, out + ZOFF, rel);
  k_fin<<<1, 64, 0, stream>>>(crfb, rel, out);
}

// Round 4
// 562.029 us; speedup vs baseline: 3.6411x; 1.1811x over previous
//
#include <hip/hip_runtime.h>
#include <math.h>

// Problem: NERRelationModel_84963043050124
// B=64 S=512 H=768 E=32 P=16 K=9 R=6 HEADS=4 C1=128 C2=64 FEAT=257
// Outputs: ner_logits [B,S,K]=294912, z [R,B,P]=6144, total [1] -> 301057 f32

#define NB 64
#define NS 512
#define NH 768
#define NE 32
#define NP 16
#define NK 9
#define NR 6
#define NHEADS 4
#define NC1 128
#define NC2 64

#define ZOFF 294912
#define TOTOFF 301056

// ---- workspace layout (float offsets) ----
#define WS_ENT   0u           // [B,E,768]
#define WS_HG1   1572864u     // [B,E,512]
#define WS_X1    2621440u     // [B,E,512]
#define WS_H2    3670016u     // [B,E,64]
#define WS_X2    3801088u     // [B,E,64]
#define WS_S1    3932160u     // [B,4,E]
#define WS_D1    3940352u
#define WS_S2    3948544u     // [B,E]
#define WS_D2    3950592u
#define WS_CTX   3952640u     // [B,64]
#define WS_PF    3956736u     // [B*P, 260] padded pitch
#define WS_FE    4222976u     // [B,P,512]
#define WS_CRF   4747264u     // [64]
#define WS_REL   4747328u     // [1]
#define WS_W1T   4747392u     // bf16 [256][768] = 98304 floats

typedef __attribute__((ext_vector_type(8))) short bf16x8;
typedef __attribute__((ext_vector_type(4))) float f32x4;

__device__ __forceinline__ unsigned short f2bf(float x) {
  union { float f; unsigned u; } v; v.f = x;
  unsigned r = v.u + 0x7FFFu + ((v.u >> 16) & 1u);
  return (unsigned short)(r >> 16);
}

__device__ __forceinline__ float blk_sum256(float v, float* sm) {
#pragma unroll
  for (int o = 32; o > 0; o >>= 1) v += __shfl_down(v, o);
  if ((threadIdx.x & 63) == 0) sm[threadIdx.x >> 6] = v;
  __syncthreads();
  v = sm[0] + sm[1] + sm[2] + sm[3];
  __syncthreads();
  return v;
}

__device__ __forceinline__ float logsigf(float x) {
  if (x >= 0.f) return -log1pf(__expf(-x));
  return x - log1pf(__expf(x));
}

// ---------------- w1 -> bf16 transposed [col][k] ----------------
__global__ __launch_bounds__(256) void k_w1t(const float* __restrict__ w1,
    unsigned short* __restrict__ w1t) {
  const int k = blockIdx.x, t = threadIdx.x;
  w1t[t * NH + k] = f2bf(w1[k * 256 + t]);
}

// ---------------- NER head: MFMA bf16 ----------------
// block = 64 tok x 256 cols; 4 waves, wave tile 64x64 (4x4 16x16 tiles), KT=32.
// GEMM2 (256->9) fused: per-lane w2 slice + quad shuffle reduce + LDS sum.
__global__ __launch_bounds__(256) void k_ner(const float* __restrict__ seq,
    const unsigned short* __restrict__ w1t, const float* __restrict__ b1,
    const float* __restrict__ w2, const float* __restrict__ b2,
    float* __restrict__ out) {
  __shared__ unsigned short AsS[64 * 40];   // [tok][k] pitch 40
  __shared__ unsigned short BsS[256 * 40];  // [col][k] pitch 40
  __shared__ float zs[64 * 4 * 12];         // [tokr][wave][cc]
  const int t = threadIdx.x;
  const int tok0 = blockIdx.x * 64;
  const int w = t >> 6, lane = t & 63, quad = lane >> 4, l15 = lane & 15;

  f32x4 acc[4][4];
#pragma unroll
  for (int r = 0; r < 4; r++)
#pragma unroll
    for (int c = 0; c < 4; c++) acc[r][c] = (f32x4){0.f, 0.f, 0.f, 0.f};

  const int tokA = t >> 2, koffA = (t & 3) * 8;
  const float* aptr = seq + (size_t)(tok0 + tokA) * NH + koffA;

  for (int kt = 0; kt < NH; kt += 32) {
    __syncthreads();
    {  // stage A: 64x32 fp32 -> bf16
      const float4 f0 = *reinterpret_cast<const float4*>(aptr + kt);
      const float4 f1 = *reinterpret_cast<const float4*>(aptr + kt + 4);
      bf16x8 av;
      av[0] = (short)f2bf(f0.x); av[1] = (short)f2bf(f0.y);
      av[2] = (short)f2bf(f0.z); av[3] = (short)f2bf(f0.w);
      av[4] = (short)f2bf(f1.x); av[5] = (short)f2bf(f1.y);
      av[6] = (short)f2bf(f1.z); av[7] = (short)f2bf(f1.w);
      *reinterpret_cast<bf16x8*>(&AsS[tokA * 40 + koffA]) = av;
    }
#pragma unroll
    for (int i = 0; i < 4; i++) {  // stage B: 256 cols x 32 k bf16
      const int q = t + 256 * i;
      const int col = q >> 2, koff = (q & 3) * 8;
      *reinterpret_cast<uint4*>(&BsS[col * 40 + koff]) =
          *reinterpret_cast<const uint4*>(&w1t[(size_t)col * NH + kt + koff]);
    }
    __syncthreads();
    bf16x8 a[4], b[4];
#pragma unroll
    for (int r = 0; r < 4; r++)
      a[r] = *reinterpret_cast<const bf16x8*>(&AsS[(r * 16 + l15) * 40 + quad * 8]);
#pragma unroll
    for (int c = 0; c < 4; c++)
      b[c] = *reinterpret_cast<const bf16x8*>(&BsS[(w * 64 + c * 16 + l15) * 40 + quad * 8]);
#pragma unroll
    for (int r = 0; r < 4; r++)
#pragma unroll
      for (int c = 0; c < 4; c++)
        acc[r][c] = __builtin_amdgcn_mfma_f32_16x16x32_bf16(a[r], b[c], acc[r][c], 0, 0, 0);
  }

  // epilogue: +b1, relu, 256->9 via per-lane w2 slice + quad reduce
  float b1v[4], w2v[4][NK];
#pragma unroll
  for (int c = 0; c < 4; c++) {
    const int col = w * 64 + c * 16 + l15;
    b1v[c] = b1[col];
#pragma unroll
    for (int cc = 0; cc < NK; cc++) w2v[c][cc] = w2[col * NK + cc];
  }
#pragma unroll
  for (int r = 0; r < 4; r++) {
#pragma unroll
    for (int reg = 0; reg < 4; reg++) {
      float p[NK];
#pragma unroll
      for (int cc = 0; cc < NK; cc++) p[cc] = 0.f;
#pragma unroll
      for (int c = 0; c < 4; c++) {
        const float h = fmaxf(acc[r][c][reg] + b1v[c], 0.f);
#pragma unroll
        for (int cc = 0; cc < NK; cc++) p[cc] = fmaf(h, w2v[c][cc], p[cc]);
      }
#pragma unroll
      for (int o = 1; o < 16; o <<= 1)
#pragma unroll
        for (int cc = 0; cc < NK; cc++) p[cc] += __shfl_xor(p[cc], o);
      if (l15 == 0) {
        const int tokr = r * 16 + quad * 4 + reg;
#pragma unroll
        for (int cc = 0; cc < NK; cc++) zs[(tokr * 4 + w) * 12 + cc] = p[cc];
      }
    }
  }
  __syncthreads();
  if (t < 64) {
#pragma unroll
    for (int cc = 0; cc < NK; cc++) {
      const float z = zs[(t * 4 + 0) * 12 + cc] + zs[(t * 4 + 1) * 12 + cc] +
                      zs[(t * 4 + 2) * 12 + cc] + zs[(t * 4 + 3) * 12 + cc] + b2[cc];
      out[(size_t)(tok0 + t) * NK + cc] = z;
    }
  }
}

// ---------------- CRF NLL: log-semiring tree, 4 quarters, LDS-staged ----------------
__global__ __launch_bounds__(256) void k_crf(const float* __restrict__ em,
    const int* __restrict__ tags, const int* __restrict__ mask,
    const float* __restrict__ startv, const float* __restrict__ endv,
    const float* __restrict__ trans, float* __restrict__ lossb) {
  __shared__ float bufA[64 * 81];   // 20736 B
  __shared__ float bufB[32 * 81];   // 10368 B
  __shared__ float ems[128 * 9];    // 4608 B
  __shared__ int mks[128];
  __shared__ float trs[81];
  __shared__ float qres[4][81];
  __shared__ float av[9];
  __shared__ float red[4];
  const int b = blockIdx.x, t = threadIdx.x;
  const float* emb = em + (size_t)b * NS * NK;
  const int* mk = mask + b * NS;
  const int* tg = tags + b * NS;
  if (t < 81) trs[t] = trans[t];
  // numerator on wave 0 (exact for contiguous mask)
  if (t < 64) {
    float num = 0.f;
    int lastS = 0;
#pragma unroll
    for (int o = 0; o < 8; o++) {
      const int s = t * 8 + o;
      if (s >= 1 && mk[s] > 0) {
        const int cur = tg[s], prv = tg[s - 1];
        num += trans[prv * NK + cur] + emb[s * NK + cur];
        lastS = s;
      }
    }
#pragma unroll
    for (int o = 32; o > 0; o >>= 1) {
      num += __shfl_xor(num, o);
      lastS = max(lastS, __shfl_xor(lastS, o));
    }
    if (t == 0) {
      const int t0 = tg[0];
      red[0] = startv[t0] + emb[t0] + num + endv[tg[lastS]];
    }
  }

  for (int h = 0; h < 4; h++) {
    const int s0 = 1 + h * 128;
    __syncthreads();
    for (int i = t; i < 128 * 9; i += 256) {
      const int g = s0 * 9 + i;
      ems[i] = (g < NS * 9) ? emb[g] : 0.f;
    }
    if (t < 128) {
      const int s = s0 + t;
      mks[t] = (s < NS) ? mk[s] : 0;
    }
    __syncthreads();
    // leaves: 64 pair-matrices
    for (int idx = t; idx < 64 * 81; idx += 256) {
      const int p = idx / 81, e = idx % 81, i = e / 9, j = e % 9;
      const int la = 2 * p, lb = la + 1;
      const bool ma = mks[la] > 0, mb = mks[lb] > 0;
      float r;
      if (ma && mb) {
        float v[9], mx = -1e30f;
#pragma unroll
        for (int m = 0; m < 9; m++) {
          v[m] = trs[i * 9 + m] + ems[la * 9 + m] + trs[m * 9 + j];
          mx = fmaxf(mx, v[m]);
        }
        float sum = 0.f;
#pragma unroll
        for (int m = 0; m < 9; m++) sum += __expf(v[m] - mx);
        r = mx + __logf(sum) + ems[lb * 9 + j];
      } else if (ma) {
        r = trs[e] + ems[la * 9 + j];
      } else if (mb) {
        r = trs[e] + ems[lb * 9 + j];
      } else {
        r = (i == j) ? 0.f : -1e30f;
      }
      bufA[p * 81 + e] = r;
    }
    float* src = bufA;
    float* dst = bufB;
    for (int n = 64; n > 1; n >>= 1) {
      __syncthreads();
      const int half = n >> 1;
      for (int idx = t; idx < half * 81; idx += 256) {
        const int q = idx / 81, e = idx % 81, i = e / 9, j = e % 9;
        const float* A = src + (size_t)(2 * q) * 81;
        const float* Bm = src + (size_t)(2 * q + 1) * 81;
        float v[9], mx = -1e30f;
#pragma unroll
        for (int m = 0; m < 9; m++) {
          v[m] = A[i * 9 + m] + Bm[m * 9 + j];
          mx = fmaxf(mx, v[m]);
        }
        float sum = 0.f;
#pragma unroll
        for (int m = 0; m < 9; m++) sum += __expf(v[m] - mx);
        dst[q * 81 + e] = mx + __logf(sum);
      }
      float* tmp = src; src = dst; dst = tmp;
    }
    __syncthreads();
    if (t < 81) qres[h][t] = src[t];
  }
  __syncthreads();
  if (t < 9) av[t] = startv[t] + emb[t];
  __syncthreads();
  for (int h = 0; h < 4; h++) {
    float nv = 0.f;
    if (t < 9) {
      float v[9], mx = -1e30f;
#pragma unroll
      for (int i2 = 0; i2 < 9; i2++) {
        v[i2] = av[i2] + qres[h][i2 * 9 + t];
        mx = fmaxf(mx, v[i2]);
      }
      float sum = 0.f;
#pragma unroll
      for (int i2 = 0; i2 < 9; i2++) sum += __expf(v[i2] - mx);
      nv = mx + __logf(sum);
    }
    __syncthreads();
    if (t < 9) av[t] = nv;
    __syncthreads();
  }
  if (t == 0) {
    float mx = -1e30f;
#pragma unroll
    for (int j = 0; j < 9; j++) mx = fmaxf(mx, av[j] + endv[j]);
    float sum = 0.f;
#pragma unroll
    for (int j = 0; j < 9; j++) sum += __expf(av[j] + endv[j] - mx);
    lossb[b] = (mx + __logf(sum)) - red[0];
  }
}

// ---------------- entity span mean pool ----------------
__global__ __launch_bounds__(256) void k_ent(const float* __restrict__ seq,
    const int* __restrict__ est, const int* __restrict__ elen, float* __restrict__ ent) {
  const int be = blockIdx.x;
  const int b = be >> 5, e = be & 31;
  const int st = est[b * NE + e];
  int en = st + elen[b * NE + e];
  en = min(max(en, 0), NS - 1);
  const float inv = 1.f / (float)(en - st + 1);
  for (int c = threadIdx.x; c < NH; c += 256) {
    float s = 0.f;
    for (int r = st; r <= en; r++) s += seq[((size_t)b * NS + r) * NH + c];
    ent[((size_t)b * NE + e) * NH + c] = s * inv;
  }
}

// ---------------- GAT1 GEMM: h = ent @ w_gat1 (768->512) ----------------
__global__ __launch_bounds__(256) void k_g1(const float* __restrict__ ent,
    const float* __restrict__ w, float* __restrict__ hout) {
  __shared__ float As[32 * 36];
  __shared__ float Bs[32 * 128];
  const int b = blockIdx.x >> 2, cb = blockIdx.x & 3;
  const int t = threadIdx.x;
  const int tc = t & 31, tr = t >> 5;
  float acc[4][4];
#pragma unroll
  for (int i = 0; i < 4; i++)
#pragma unroll
    for (int j = 0; j < 4; j++) acc[i][j] = 0.f;
  for (int kt = 0; kt < NH; kt += 32) {
    __syncthreads();
    {
      const int e = t >> 3, k4 = t & 7;
      *reinterpret_cast<float4*>(&As[e * 36 + k4 * 4]) =
          *reinterpret_cast<const float4*>(&ent[((size_t)b * NE + e) * NH + kt + k4 * 4]);
    }
#pragma unroll
    for (int i = 0; i < 4; i++) {
      const int slot = t + 256 * i;
      const int row = slot >> 5, cg = slot & 31;
      *reinterpret_cast<float4*>(&Bs[row * 128 + cg * 4]) =
          *reinterpret_cast<const float4*>(&w[(size_t)(kt + row) * 512 + cb * 128 + cg * 4]);
    }
    __syncthreads();
#pragma unroll
    for (int kg = 0; kg < 8; kg++) {
      float4 a[4];
#pragma unroll
      for (int i = 0; i < 4; i++)
        a[i] = *reinterpret_cast<const float4*>(&As[(tr * 4 + i) * 36 + kg * 4]);
#pragma unroll
      for (int k2 = 0; k2 < 4; k2++) {
        const float4 bv = *reinterpret_cast<const float4*>(&Bs[(kg * 4 + k2) * 128 + tc * 4]);
#pragma unroll
        for (int i = 0; i < 4; i++) {
          const float av = reinterpret_cast<const float*>(&a[i])[k2];
          acc[i][0] = fmaf(av, bv.x, acc[i][0]);
          acc[i][1] = fmaf(av, bv.y, acc[i][1]);
          acc[i][2] = fmaf(av, bv.z, acc[i][2]);
          acc[i][3] = fmaf(av, bv.w, acc[i][3]);
        }
      }
    }
  }
#pragma unroll
  for (int i = 0; i < 4; i++) {
    float4 v;
    v.x = acc[i][0]; v.y = acc[i][1]; v.z = acc[i][2]; v.w = acc[i][3];
    *reinterpret_cast<float4*>(&hout[((size_t)b * NE + tr * 4 + i) * 512 + cb * 128 + tc * 4]) = v;
  }
}

// ---------------- GAT1 attention src/dst dots ----------------
__global__ __launch_bounds__(128) void k_sd1(const float* __restrict__ h,
    const float* __restrict__ as, const float* __restrict__ ad,
    float* __restrict__ s1, float* __restrict__ d1) {
  __shared__ float sm[4];
  const int be = blockIdx.x;
  const int b = be >> 5, e = be & 31;
  const int t = threadIdx.x;
  for (int hd = 0; hd < NHEADS; hd++) {
    const float v = h[((size_t)b * NE + e) * 512 + hd * NC1 + t];
    float sv = v * as[hd * NC1 + t];
    float dv = v * ad[hd * NC1 + t];
#pragma unroll
    for (int o = 32; o > 0; o >>= 1) { sv += __shfl_xor(sv, o); dv += __shfl_xor(dv, o); }
    if ((t & 63) == 0) { sm[(t >> 6) * 2] = sv; sm[(t >> 6) * 2 + 1] = dv; }
    __syncthreads();
    if (t == 0) {
      s1[(b * NHEADS + hd) * NE + e] = sm[0] + sm[2];
      d1[(b * NHEADS + hd) * NE + e] = sm[1] + sm[3];
    }
    __syncthreads();
  }
}

// ---------------- GAT1 attention + aggregate + bias + relu ----------------
__global__ __launch_bounds__(128) void k_att1(const float* __restrict__ h,
    const float* __restrict__ s1, const float* __restrict__ d1,
    const unsigned char* __restrict__ adj, const float* __restrict__ bias,
    float* __restrict__ x1) {
  __shared__ float att[NE];
  const int blk = blockIdx.x;
  const int i = blk & 31, hd = (blk >> 5) & 3, b = blk >> 7;
  const int t = threadIdx.x;
  if (t < NE) {
    float lg = d1[(b * NHEADS + hd) * NE + i] + s1[(b * NHEADS + hd) * NE + t];
    lg = lg >= 0.f ? lg : 0.2f * lg;
    if (!adj[((size_t)b * NE + i) * NE + t]) lg = -1e9f;
    att[t] = lg;
  }
  __syncthreads();
  if (t == 0) {
    float m = -1e30f;
#pragma unroll
    for (int j = 0; j < NE; j++) m = fmaxf(m, att[j]);
    float ex[NE];
    float sum = 0.f;
#pragma unroll
    for (int j = 0; j < NE; j++) { ex[j] = __expf(att[j] - m); sum += ex[j]; }
    const float inv = 1.f / sum;
#pragma unroll
    for (int j = 0; j < NE; j++) att[j] = ex[j] * inv;
  }
  __syncthreads();
  float acc = bias[hd * NC1 + t];
  for (int j = 0; j < NE; j++)
    acc += att[j] * h[((size_t)b * NE + j) * 512 + hd * NC1 + t];
  x1[((size_t)b * NE + i) * 512 + hd * NC1 + t] = fmaxf(acc, 0.f);
}

// ---------------- GAT2 GEMM + src/dst dots ----------------
__global__ __launch_bounds__(256) void k_g2(const float* __restrict__ x1,
    const float* __restrict__ w, const float* __restrict__ as, const float* __restrict__ ad,
    float* __restrict__ h2, float* __restrict__ s2, float* __restrict__ d2) {
  __shared__ float As[32 * 36];
  __shared__ float Bs[32 * 64];
  const int b = blockIdx.x;
  const int t = threadIdx.x;
  const int tc = t & 15, tr = t >> 4;
  float acc[2][4];
#pragma unroll
  for (int i = 0; i < 2; i++)
#pragma unroll
    for (int j = 0; j < 4; j++) acc[i][j] = 0.f;
  for (int kt = 0; kt < 512; kt += 32) {
    __syncthreads();
    {
      const int e = t >> 3, k4 = t & 7;
      *reinterpret_cast<float4*>(&As[e * 36 + k4 * 4]) =
          *reinterpret_cast<const float4*>(&x1[((size_t)b * NE + e) * 512 + kt + k4 * 4]);
    }
#pragma unroll
    for (int i = 0; i < 2; i++) {
      const int slot = t + 256 * i;
      const int row = slot >> 4, cg = slot & 15;
      *reinterpret_cast<float4*>(&Bs[row * 64 + cg * 4]) =
          *reinterpret_cast<const float4*>(&w[(size_t)(kt + row) * NC2 + cg * 4]);
    }
    __syncthreads();
#pragma unroll
    for (int kg = 0; kg < 8; kg++) {
      float4 a[2];
#pragma unroll
      for (int i = 0; i < 2; i++)
        a[i] = *reinterpret_cast<const float4*>(&As[(tr * 2 + i) * 36 + kg * 4]);
#pragma unroll
      for (int k2 = 0; k2 < 4; k2++) {
        const float4 bv = *reinterpret_cast<const float4*>(&Bs[(kg * 4 + k2) * 64 + tc * 4]);
#pragma unroll
        for (int i = 0; i < 2; i++) {
          const float av = reinterpret_cast<const float*>(&a[i])[k2];
          acc[i][0] = fmaf(av, bv.x, acc[i][0]);
          acc[i][1] = fmaf(av, bv.y, acc[i][1]);
          acc[i][2] = fmaf(av, bv.z, acc[i][2]);
          acc[i][3] = fmaf(av, bv.w, acc[i][3]);
        }
      }
    }
  }
  const float4 a4s = *reinterpret_cast<const float4*>(&as[tc * 4]);
  const float4 a4d = *reinterpret_cast<const float4*>(&ad[tc * 4]);
#pragma unroll
  for (int i = 0; i < 2; i++) {
    const int e = tr * 2 + i;
    float4 v;
    v.x = acc[i][0]; v.y = acc[i][1]; v.z = acc[i][2]; v.w = acc[i][3];
    *reinterpret_cast<float4*>(&h2[((size_t)b * NE + e) * NC2 + tc * 4]) = v;
    float sv = v.x * a4s.x + v.y * a4s.y + v.z * a4s.z + v.w * a4s.w;
    float dv = v.x * a4d.x + v.y * a4d.y + v.z * a4d.z + v.w * a4d.w;
#pragma unroll
    for (int o = 8; o > 0; o >>= 1) { sv += __shfl_xor(sv, o); dv += __shfl_xor(dv, o); }
    if (tc == 0) { s2[b * NE + e] = sv; d2[b * NE + e] = dv; }
  }
}

// ---------------- GAT2 attention + aggregate + bias ----------------
__global__ __launch_bounds__(64) void k_att2(const float* __restrict__ h2,
    const float* __restrict__ s2, const float* __restrict__ d2,
    const unsigned char* __restrict__ adj, const float* __restrict__ bias,
    float* __restrict__ x2) {
  __shared__ float att[NE];
  const int be = blockIdx.x;
  const int b = be >> 5, i = be & 31;
  const int t = threadIdx.x;
  if (t < NE) {
    float lg = d2[b * NE + i] + s2[b * NE + t];
    lg = lg >= 0.f ? lg : 0.2f * lg;
    if (!adj[((size_t)b * NE + i) * NE + t]) lg = -1e9f;
    att[t] = lg;
  }
  __syncthreads();
  if (t == 0) {
    float m = -1e30f;
#pragma unroll
    for (int j = 0; j < NE; j++) m = fmaxf(m, att[j]);
    float ex[NE];
    float sum = 0.f;
#pragma unroll
    for (int j = 0; j < NE; j++) { ex[j] = __expf(att[j] - m); sum += ex[j]; }
    const float inv = 1.f / sum;
#pragma unroll
    for (int j = 0; j < NE; j++) att[j] = ex[j] * inv;
  }
  __syncthreads();
  float acc = bias[t];
  for (int j = 0; j < NE; j++)
    acc += att[j] * h2[((size_t)b * NE + j) * NC2 + t];
  x2[((size_t)b * NE + i) * NC2 + t] = acc;
}

// ---------------- ctx = mean over entities ----------------
__global__ __launch_bounds__(64) void k_ctx(const float* __restrict__ x2, float* __restrict__ ctx) {
  const int b = blockIdx.x, t = threadIdx.x;
  float s = 0.f;
  for (int e = 0; e < NE; e++) s += x2[((size_t)b * NE + e) * NC2 + t];
  ctx[b * NC2 + t] = s * (1.f / NE);
}

// ---------------- pair feature build (pitch 260) ----------------
__global__ __launch_bounds__(64) void k_pf(const float* __restrict__ x2,
    const float* __restrict__ ctx, const int* __restrict__ pe1, const int* __restrict__ pe2,
    float* __restrict__ pf) {
  const int bp = blockIdx.x;
  const int b = bp >> 4, p = bp & 15;
  const int t = threadIdx.x;
  const int e1 = pe1[b * NP + p], e2 = pe2[b * NP + p];
  const float v1 = x2[((size_t)b * NE + e1) * NC2 + t];
  const float v2 = x2[((size_t)b * NE + e2) * NC2 + t];
  float* row = pf + (size_t)bp * 260;
  row[t] = v1;
  row[64 + t] = v2;
  row[128 + t] = v1 * v2;
  row[192 + t] = ctx[b * NC2 + t];
  if (t == 0) row[256] = logf(fabsf((float)(e1 - e2)) + 1.f);
  if (t < 3) row[257 + t] = 0.f;
}

// ---------------- fe = leaky(LN(pf @ w_fe + b_fe)) ----------------
__global__ __launch_bounds__(256) void k_fe(const float* __restrict__ pf,
    const float* __restrict__ w, const float* __restrict__ bfe,
    const float* __restrict__ g, const float* __restrict__ be, float* __restrict__ fe) {
  __shared__ float sm[4];
  __shared__ float pfs[NP * 260];
  const int b = blockIdx.x, t = threadIdx.x;
  for (int i = t; i < NP * 260; i += 256) pfs[i] = pf[(size_t)b * NP * 260 + i];
  __syncthreads();
  float a0[16], a1[16];
  {
    const float bv0 = bfe[t], bv1 = bfe[t + 256];
#pragma unroll
    for (int p = 0; p < NP; p++) { a0[p] = bv0; a1[p] = bv1; }
  }
  for (int k = 0; k < 256; k += 4) {
    const float w00 = w[(k + 0) * 512 + t], w01 = w[(k + 1) * 512 + t];
    const float w02 = w[(k + 2) * 512 + t], w03 = w[(k + 3) * 512 + t];
    const float w10 = w[(k + 0) * 512 + t + 256], w11 = w[(k + 1) * 512 + t + 256];
    const float w12 = w[(k + 2) * 512 + t + 256], w13 = w[(k + 3) * 512 + t + 256];
#pragma unroll
    for (int p = 0; p < NP; p++) {
      const float4 a4 = *reinterpret_cast<const float4*>(&pfs[p * 260 + k]);
      float x0 = a0[p], x1 = a1[p];
      x0 = fmaf(a4.x, w00, x0); x1 = fmaf(a4.x, w10, x1);
      x0 = fmaf(a4.y, w01, x0); x1 = fmaf(a4.y, w11, x1);
      x0 = fmaf(a4.z, w02, x0); x1 = fmaf(a4.z, w12, x1);
      x0 = fmaf(a4.w, w03, x0); x1 = fmaf(a4.w, w13, x1);
      a0[p] = x0; a1[p] = x1;
    }
  }
  {
    const float w0 = w[256 * 512 + t], w1 = w[256 * 512 + t + 256];
#pragma unroll
    for (int p = 0; p < NP; p++) {
      const float av = pfs[p * 260 + 256];
      a0[p] = fmaf(av, w0, a0[p]);
      a1[p] = fmaf(av, w1, a1[p]);
    }
  }
  const float gv0 = g[t], gv1 = g[t + 256], bev0 = be[t], bev1 = be[t + 256];
  for (int p = 0; p < NP; p++) {
    const float s = blk_sum256(a0[p] + a1[p], sm);
    const float sq = blk_sum256(a0[p] * a0[p] + a1[p] * a1[p], sm);
    const float mean = s * (1.f / 512.f);
    const float var = sq * (1.f / 512.f) - mean * mean;
    const float rr = rsqrtf(var + 1e-5f);
    float n0 = (a0[p] - mean) * rr * gv0 + bev0;
    float n1 = (a1[p] - mean) * rr * gv1 + bev1;
    n0 = n0 >= 0.f ? n0 : 0.01f * n0;
    n1 = n1 >= 0.f ? n1 : 0.01f * n1;
    fe[((size_t)b * NP + p) * 512 + t] = n0;
    fe[((size_t)b * NP + p) * 512 + t + 256] = n1;
  }
}

// ---------------- relation heads: GEMM + LN + leaky + dot + BCE ----------------
__global__ __launch_bounds__(256) void k_rc(const float* __restrict__ fe,
    const float* __restrict__ w1, const float* __restrict__ b1,
    const float* __restrict__ g, const float* __restrict__ be,
    const float* __restrict__ w2, const float* __restrict__ b2,
    const int* __restrict__ ylab, float* __restrict__ zout, float* __restrict__ relacc) {
  __shared__ float sm[4];
  __shared__ float fes[NP * 512];
  const int blk = blockIdx.x;
  const int r = blk >> 6, b = blk & 63;
  const int t = threadIdx.x;
#pragma unroll
  for (int i = 0; i < 8; i++) {
    const int slot = t + 256 * i;
    const int p = slot >> 7, k4 = slot & 127;
    *reinterpret_cast<float4*>(&fes[p * 512 + k4 * 4]) =
        *reinterpret_cast<const float4*>(&fe[((size_t)b * NP + p) * 512 + k4 * 4]);
  }
  __syncthreads();
  float acc[16];
  {
    const float bv = b1[r * 256 + t];
#pragma unroll
    for (int p = 0; p < NP; p++) acc[p] = bv;
  }
  const float* wr = w1 + (size_t)r * 512 * 256;
  for (int k = 0; k < 512; k += 4) {
    const float w0 = wr[(k + 0) * 256 + t], wA = wr[(k + 1) * 256 + t];
    const float wB = wr[(k + 2) * 256 + t], wC = wr[(k + 3) * 256 + t];
#pragma unroll
    for (int p = 0; p < NP; p++) {
      const float4 a4 = *reinterpret_cast<const float4*>(&fes[p * 512 + k]);
      float x = acc[p];
      x = fmaf(a4.x, w0, x); x = fmaf(a4.y, wA, x);
      x = fmaf(a4.z, wB, x); x = fmaf(a4.w, wC, x);
      acc[p] = x;
    }
  }
  const float gv = g[r * 256 + t], bev = be[r * 256 + t], w2v = w2[r * 256 + t];
  const float b2v = b2[r];
  float local = 0.f;
  for (int p = 0; p < NP; p++) {
    const float s = blk_sum256(acc[p], sm);
    const float sq = blk_sum256(acc[p] * acc[p], sm);
    const float mean = s * (1.f / 256.f);
    const float var = sq * (1.f / 256.f) - mean * mean;
    const float rr = rsqrtf(var + 1e-5f);
    float n = (acc[p] - mean) * rr * gv + bev;
    n = n >= 0.f ? n : 0.01f * n;
    const float zp = blk_sum256(n * w2v, sm) + b2v;
    if (t == 0) {
      zout[((size_t)r * NB + b) * NP + p] = zp;
      const float y = (float)ylab[b * NP + p];
      local += -(2.f * y * logsigf(zp) + (1.f - y) * logsigf(-zp));
    }
  }
  if (t == 0) atomicAdd(relacc, local * (1.f / (NB * NP)));
}

// ---------------- finalize total loss ----------------
__global__ __launch_bounds__(64) void k_fin(const float* __restrict__ lossb,
    const float* __restrict__ rel, float* __restrict__ out) {
  float v = lossb[threadIdx.x];
#pragma unroll
  for (int o = 32; o > 0; o >>= 1) v += __shfl_down(v, o);
  if (threadIdx.x == 0) out[TOTOFF] = v * (1.f / NB) + rel[0];
}

extern "C" void kernel_launch(void* const* d_in, const int* in_sizes, int n_in,
                              void* d_out, int out_size, void* d_ws, size_t ws_size,
                              hipStream_t stream) {
  const float* seq = (const float*)d_in[0];
  const int* amask = (const int*)d_in[1];
  const int* nlab = (const int*)d_in[2];
  const int* est = (const int*)d_in[3];
  const int* elen = (const int*)d_in[4];
  const int* pe1 = (const int*)d_in[5];
  const int* pe2 = (const int*)d_in[6];
  const int* plab = (const int*)d_in[7];
  const unsigned char* adj = (const unsigned char*)d_in[8];
  const float* w_ner1 = (const float*)d_in[9];
  const float* b_ner1 = (const float*)d_in[10];
  const float* w_ner2 = (const float*)d_in[11];
  const float* b_ner2 = (const float*)d_in[12];
  const float* crf_start = (const float*)d_in[13];
  const float* crf_end = (const float*)d_in[14];
  const float* crf_trans = (const float*)d_in[15];
  const float* w_gat1 = (const float*)d_in[16];
  const float* a_src1 = (const float*)d_in[17];
  const float* a_dst1 = (const float*)d_in[18];
  const float* b_gat1 = (const float*)d_in[19];
  const float* w_gat2 = (const float*)d_in[20];
  const float* a_src2 = (const float*)d_in[21];
  const float* a_dst2 = (const float*)d_in[22];
  const float* b_gat2 = (const float*)d_in[23];
  const float* w_fe = (const float*)d_in[24];
  const float* b_fe = (const float*)d_in[25];
  const float* g_fe = (const float*)d_in[26];
  const float* be_fe = (const float*)d_in[27];
  const float* w_rc1 = (const float*)d_in[28];
  const float* b_rc1 = (const float*)d_in[29];
  const float* g_rc = (const float*)d_in[30];
  const float* be_rc = (const float*)d_in[31];
  const float* w_rc2 = (const float*)d_in[32];
  const float* b_rc2 = (const float*)d_in[33];

  float* out = (float*)d_out;
  float* ws = (float*)d_ws;
  float* ent = ws + WS_ENT;
  float* hg1 = ws + WS_HG1;
  float* x1 = ws + WS_X1;
  float* h2 = ws + WS_H2;
  float* x2 = ws + WS_X2;
  float* s1 = ws + WS_S1;
  float* d1 = ws + WS_D1;
  float* s2 = ws + WS_S2;
  float* d2 = ws + WS_D2;
  float* ctx = ws + WS_CTX;
  float* pf = ws + WS_PF;
  float* fe = ws + WS_FE;
  float* crfb = ws + WS_CRF;
  float* rel = ws + WS_REL;
  unsigned short* w1t = (unsigned short*)(ws + WS_W1T);

  hipMemsetAsync(rel, 0, sizeof(float), stream);

  k_w1t<<<NH, 256, 0, stream>>>(w_ner1, w1t);
  k_ner<<<512, 256, 0, stream>>>(seq, w1t, b_ner1, w_ner2, b_ner2, out);
  k_crf<<<64, 256, 0, stream>>>(out, nlab, amask, crf_start, crf_end, crf_trans, crfb);
  k_ent<<<NB * NE, 256, 0, stream>>>(seq, est, elen, ent);
  k_g1<<<NB * 4, 256, 0, stream>>>(ent, w_gat1, hg1);
  k_sd1<<<NB * NE, 128, 0, stream>>>(hg1, a_src1, a_dst1, s1, d1);
  k_att1<<<NB * NHEADS * NE, 128, 0, stream>>>(hg1, s1, d1, adj, b_gat1, x1);
  k_g2<<<NB, 256, 0, stream>>>(x1, w_gat2, a_src2, a_dst2, h2, s2, d2);
  k_att2<<<NB * NE, 64, 0, stream>>>(h2, s2, d2, adj, b_gat2, x2);
  k_ctx<<<NB, 64, 0, stream>>>(x2, ctx);
  k_pf<<<NB * NP, 64, 0, stream>>>(x2, ctx, pe1, pe2, pf);
  k_fe<<<NB, 256, 0, stream>>>(pf, w_fe, b_fe, g_fe, be_fe, fe);
  k_rc<<<NR * NB, 256, 0, stream>>>(fe, w_rc1, b_rc1, g_rc, be_rc, w_rc2, b_rc2,
                                    plab, out + ZOFF, rel);
  k_fin<<<1, 64, 0, stream>>>(crfb, rel, out);
}

// Round 5
// 489.999 us; speedup vs baseline: 4.1763x; 1.1470x over previous
//
#include <hip/hip_runtime.h>
#include <math.h>

// Problem: NERRelationModel_84963043050124
// B=64 S=512 H=768 E=32 P=16 K=9 R=6 HEADS=4 C1=128 C2=64 FEAT=257
// Outputs: ner_logits [B,S,K]=294912, z [R,B,P]=6144, total [1] -> 301057 f32

#define NB 64
#define NS 512
#define NH 768
#define NE 32
#define NP 16
#define NK 9
#define NR 6
#define NHEADS 4
#define NC1 128
#define NC2 64

#define ZOFF 294912
#define TOTOFF 301056

// ---- workspace layout (float offsets) ----
#define WS_ENT   0u           // [B,E,768]  (reused: WRT/WFET after k_g1)
#define WS_HG1   1572864u     // [B,E,512]
#define WS_X1    2621440u     // [B,E,512]
#define WS_H2    3670016u     // [B,E,64]
#define WS_X2    3801088u     // [B,E,64]
#define WS_S1    3932160u     // [B,4,E]
#define WS_D1    3940352u
#define WS_S2    3948544u     // [B,E]
#define WS_D2    3950592u
#define WS_CTX   3952640u     // [B,64]
#define WS_PF    3956736u     // [B*P, 260] padded pitch
#define WS_FE    4222976u     // bf16 [B,P,512] (262144 floats used)
#define WS_CRF   4747264u     // [64]
#define WS_REL   4747328u     // [1]
#define WS_W1T   4747392u     // bf16 [256][768] = 98304 floats
// overlapped into dead ENT region (valid after k_g1 consumed ent):
#define WS_WRT   0u           // bf16 [R*256][512] = 393216 floats
#define WS_WFET  393216u      // bf16 [512][320]   = 81920 floats

typedef __attribute__((ext_vector_type(8))) short bf16x8;
typedef __attribute__((ext_vector_type(4))) float f32x4;

__device__ __forceinline__ unsigned short f2bf(float x) {
  union { float f; unsigned u; } v; v.f = x;
  unsigned r = v.u + 0x7FFFu + ((v.u >> 16) & 1u);
  return (unsigned short)(r >> 16);
}

__device__ __forceinline__ float logsigf(float x) {
  if (x >= 0.f) return -log1pf(__expf(-x));
  return x - log1pf(__expf(x));
}

// ---------------- w1 -> bf16 transposed [col][k] ----------------
__global__ __launch_bounds__(256) void k_w1t(const float* __restrict__ w1,
    unsigned short* __restrict__ w1t) {
  const int k = blockIdx.x, t = threadIdx.x;
  w1t[t * NH + k] = f2bf(w1[k * 256 + t]);
}

// ---------------- w_rc1 [r][k(512)][col(256)] -> bf16 [r*256+col][512] ----------------
// tiled transpose, grid R*8 (k-tiles of 64), 256 threads
__global__ __launch_bounds__(256) void k_wrt(const float* __restrict__ w1,
    unsigned short* __restrict__ wrt) {
  __shared__ unsigned short tr[256 * 72];
  const int r = blockIdx.x >> 3, kt = blockIdx.x & 7;
  const int k0 = kt * 64, t = threadIdx.x;
#pragma unroll
  for (int i = 0; i < 16; i++) {
    const int slot = t + 256 * i;
    const int row = slot >> 6, c4 = slot & 63;
    const float4 f = *reinterpret_cast<const float4*>(
        &w1[((size_t)(r * 512) + k0 + row) * 256 + c4 * 4]);
    tr[(c4 * 4 + 0) * 72 + row] = f2bf(f.x);
    tr[(c4 * 4 + 1) * 72 + row] = f2bf(f.y);
    tr[(c4 * 4 + 2) * 72 + row] = f2bf(f.z);
    tr[(c4 * 4 + 3) * 72 + row] = f2bf(f.w);
  }
  __syncthreads();
#pragma unroll
  for (int i = 0; i < 8; i++) {
    const int slot = t + 256 * i;
    const int col = slot >> 3, q = slot & 7;
    *reinterpret_cast<uint4*>(&wrt[((size_t)(r * 256 + col)) * 512 + k0 + q * 8]) =
        *reinterpret_cast<const uint4*>(&tr[col * 72 + q * 8]);
  }
}

// ---------------- w_fe [k(257)][col(512)] -> bf16 [col][320] (zero-pad k) ----------------
// grid 10 = 5 k-tiles(64) x 2 col-tiles(256), 256 threads
__global__ __launch_bounds__(256) void k_wfet(const float* __restrict__ w,
    unsigned short* __restrict__ wt) {
  __shared__ unsigned short tr[256 * 72];
  const int kt = blockIdx.x % 5, cb = blockIdx.x / 5;
  const int k0 = kt * 64, c0 = cb * 256, t = threadIdx.x;
#pragma unroll
  for (int i = 0; i < 16; i++) {
    const int slot = t + 256 * i;
    const int row = slot >> 6, c4 = slot & 63;
    const int k = k0 + row;
    float4 f = {0.f, 0.f, 0.f, 0.f};
    if (k < 257)
      f = *reinterpret_cast<const float4*>(&w[(size_t)k * 512 + c0 + c4 * 4]);
    tr[(c4 * 4 + 0) * 72 + row] = f2bf(f.x);
    tr[(c4 * 4 + 1) * 72 + row] = f2bf(f.y);
    tr[(c4 * 4 + 2) * 72 + row] = f2bf(f.z);
    tr[(c4 * 4 + 3) * 72 + row] = f2bf(f.w);
  }
  __syncthreads();
#pragma unroll
  for (int i = 0; i < 8; i++) {
    const int slot = t + 256 * i;
    const int col = slot >> 3, q = slot & 7;
    *reinterpret_cast<uint4*>(&wt[((size_t)(c0 + col)) * 320 + k0 + q * 8]) =
        *reinterpret_cast<const uint4*>(&tr[col * 72 + q * 8]);
  }
}

// ---------------- NER head: MFMA bf16 ----------------
__global__ __launch_bounds__(256) void k_ner(const float* __restrict__ seq,
    const unsigned short* __restrict__ w1t, const float* __restrict__ b1,
    const float* __restrict__ w2, const float* __restrict__ b2,
    float* __restrict__ out) {
  __shared__ unsigned short AsS[64 * 40];   // [tok][k] pitch 40
  __shared__ unsigned short BsS[256 * 40];  // [col][k] pitch 40
  __shared__ float zs[64 * 4 * 12];         // [tokr][wave][cc]
  const int t = threadIdx.x;
  const int tok0 = blockIdx.x * 64;
  const int w = t >> 6, lane = t & 63, quad = lane >> 4, l15 = lane & 15;

  f32x4 acc[4][4];
#pragma unroll
  for (int r = 0; r < 4; r++)
#pragma unroll
    for (int c = 0; c < 4; c++) acc[r][c] = (f32x4){0.f, 0.f, 0.f, 0.f};

  const int tokA = t >> 2, koffA = (t & 3) * 8;
  const float* aptr = seq + (size_t)(tok0 + tokA) * NH + koffA;

  for (int kt = 0; kt < NH; kt += 32) {
    __syncthreads();
    {
      const float4 f0 = *reinterpret_cast<const float4*>(aptr + kt);
      const float4 f1 = *reinterpret_cast<const float4*>(aptr + kt + 4);
      bf16x8 av;
      av[0] = (short)f2bf(f0.x); av[1] = (short)f2bf(f0.y);
      av[2] = (short)f2bf(f0.z); av[3] = (short)f2bf(f0.w);
      av[4] = (short)f2bf(f1.x); av[5] = (short)f2bf(f1.y);
      av[6] = (short)f2bf(f1.z); av[7] = (short)f2bf(f1.w);
      *reinterpret_cast<bf16x8*>(&AsS[tokA * 40 + koffA]) = av;
    }
#pragma unroll
    for (int i = 0; i < 4; i++) {
      const int q = t + 256 * i;
      const int col = q >> 2, koff = (q & 3) * 8;
      *reinterpret_cast<uint4*>(&BsS[col * 40 + koff]) =
          *reinterpret_cast<const uint4*>(&w1t[(size_t)col * NH + kt + koff]);
    }
    __syncthreads();
    bf16x8 a[4], b[4];
#pragma unroll
    for (int r = 0; r < 4; r++)
      a[r] = *reinterpret_cast<const bf16x8*>(&AsS[(r * 16 + l15) * 40 + quad * 8]);
#pragma unroll
    for (int c = 0; c < 4; c++)
      b[c] = *reinterpret_cast<const bf16x8*>(&BsS[(w * 64 + c * 16 + l15) * 40 + quad * 8]);
#pragma unroll
    for (int r = 0; r < 4; r++)
#pragma unroll
      for (int c = 0; c < 4; c++)
        acc[r][c] = __builtin_amdgcn_mfma_f32_16x16x32_bf16(a[r], b[c], acc[r][c], 0, 0, 0);
  }

  float b1v[4], w2v[4][NK];
#pragma unroll
  for (int c = 0; c < 4; c++) {
    const int col = w * 64 + c * 16 + l15;
    b1v[c] = b1[col];
#pragma unroll
    for (int cc = 0; cc < NK; cc++) w2v[c][cc] = w2[col * NK + cc];
  }
#pragma unroll
  for (int r = 0; r < 4; r++) {
#pragma unroll
    for (int reg = 0; reg < 4; reg++) {
      float p[NK];
#pragma unroll
      for (int cc = 0; cc < NK; cc++) p[cc] = 0.f;
#pragma unroll
      for (int c = 0; c < 4; c++) {
        const float h = fmaxf(acc[r][c][reg] + b1v[c], 0.f);
#pragma unroll
        for (int cc = 0; cc < NK; cc++) p[cc] = fmaf(h, w2v[c][cc], p[cc]);
      }
#pragma unroll
      for (int o = 1; o < 16; o <<= 1)
#pragma unroll
        for (int cc = 0; cc < NK; cc++) p[cc] += __shfl_xor(p[cc], o);
      if (l15 == 0) {
        const int tokr = r * 16 + quad * 4 + reg;
#pragma unroll
        for (int cc = 0; cc < NK; cc++) zs[(tokr * 4 + w) * 12 + cc] = p[cc];
      }
    }
  }
  __syncthreads();
  if (t < 64) {
#pragma unroll
    for (int cc = 0; cc < NK; cc++) {
      const float z = zs[(t * 4 + 0) * 12 + cc] + zs[(t * 4 + 1) * 12 + cc] +
                      zs[(t * 4 + 2) * 12 + cc] + zs[(t * 4 + 3) * 12 + cc] + b2[cc];
      out[(size_t)(tok0 + t) * NK + cc] = z;
    }
  }
}

// ---------------- CRF NLL: log-semiring tree, 4 quarters, LDS-staged ----------------
__global__ __launch_bounds__(256) void k_crf(const float* __restrict__ em,
    const int* __restrict__ tags, const int* __restrict__ mask,
    const float* __restrict__ startv, const float* __restrict__ endv,
    const float* __restrict__ trans, float* __restrict__ lossb) {
  __shared__ float bufA[64 * 81];
  __shared__ float bufB[32 * 81];
  __shared__ float ems[128 * 9];
  __shared__ int mks[128];
  __shared__ float trs[81];
  __shared__ float qres[4][81];
  __shared__ float av[9];
  __shared__ float red[4];
  const int b = blockIdx.x, t = threadIdx.x;
  const float* emb = em + (size_t)b * NS * NK;
  const int* mk = mask + b * NS;
  const int* tg = tags + b * NS;
  if (t < 81) trs[t] = trans[t];
  if (t < 64) {
    float num = 0.f;
    int lastS = 0;
#pragma unroll
    for (int o = 0; o < 8; o++) {
      const int s = t * 8 + o;
      if (s >= 1 && mk[s] > 0) {
        const int cur = tg[s], prv = tg[s - 1];
        num += trans[prv * NK + cur] + emb[s * NK + cur];
        lastS = s;
      }
    }
#pragma unroll
    for (int o = 32; o > 0; o >>= 1) {
      num += __shfl_xor(num, o);
      lastS = max(lastS, __shfl_xor(lastS, o));
    }
    if (t == 0) {
      const int t0 = tg[0];
      red[0] = startv[t0] + emb[t0] + num + endv[tg[lastS]];
    }
  }

  for (int h = 0; h < 4; h++) {
    const int s0 = 1 + h * 128;
    __syncthreads();
    for (int i = t; i < 128 * 9; i += 256) {
      const int g = s0 * 9 + i;
      ems[i] = (g < NS * 9) ? emb[g] : 0.f;
    }
    if (t < 128) {
      const int s = s0 + t;
      mks[t] = (s < NS) ? mk[s] : 0;
    }
    __syncthreads();
    for (int idx = t; idx < 64 * 81; idx += 256) {
      const int p = idx / 81, e = idx % 81, i = e / 9, j = e % 9;
      const int la = 2 * p, lb = la + 1;
      const bool ma = mks[la] > 0, mb = mks[lb] > 0;
      float r;
      if (ma && mb) {
        float v[9], mx = -1e30f;
#pragma unroll
        for (int m = 0; m < 9; m++) {
          v[m] = trs[i * 9 + m] + ems[la * 9 + m] + trs[m * 9 + j];
          mx = fmaxf(mx, v[m]);
        }
        float sum = 0.f;
#pragma unroll
        for (int m = 0; m < 9; m++) sum += __expf(v[m] - mx);
        r = mx + __logf(sum) + ems[lb * 9 + j];
      } else if (ma) {
        r = trs[e] + ems[la * 9 + j];
      } else if (mb) {
        r = trs[e] + ems[lb * 9 + j];
      } else {
        r = (i == j) ? 0.f : -1e30f;
      }
      bufA[p * 81 + e] = r;
    }
    float* src = bufA;
    float* dst = bufB;
    for (int n = 64; n > 1; n >>= 1) {
      __syncthreads();
      const int half = n >> 1;
      for (int idx = t; idx < half * 81; idx += 256) {
        const int q = idx / 81, e = idx % 81, i = e / 9, j = e % 9;
        const float* A = src + (size_t)(2 * q) * 81;
        const float* Bm = src + (size_t)(2 * q + 1) * 81;
        float v[9], mx = -1e30f;
#pragma unroll
        for (int m = 0; m < 9; m++) {
          v[m] = A[i * 9 + m] + Bm[m * 9 + j];
          mx = fmaxf(mx, v[m]);
        }
        float sum = 0.f;
#pragma unroll
        for (int m = 0; m < 9; m++) sum += __expf(v[m] - mx);
        dst[q * 81 + e] = mx + __logf(sum);
      }
      float* tmp = src; src = dst; dst = tmp;
    }
    __syncthreads();
    if (t < 81) qres[h][t] = src[t];
  }
  __syncthreads();
  if (t < 9) av[t] = startv[t] + emb[t];
  __syncthreads();
  for (int h = 0; h < 4; h++) {
    float nv = 0.f;
    if (t < 9) {
      float v[9], mx = -1e30f;
#pragma unroll
      for (int i2 = 0; i2 < 9; i2++) {
        v[i2] = av[i2] + qres[h][i2 * 9 + t];
        mx = fmaxf(mx, v[i2]);
      }
      float sum = 0.f;
#pragma unroll
      for (int i2 = 0; i2 < 9; i2++) sum += __expf(v[i2] - mx);
      nv = mx + __logf(sum);
    }
    __syncthreads();
    if (t < 9) av[t] = nv;
    __syncthreads();
  }
  if (t == 0) {
    float mx = -1e30f;
#pragma unroll
    for (int j = 0; j < 9; j++) mx = fmaxf(mx, av[j] + endv[j]);
    float sum = 0.f;
#pragma unroll
    for (int j = 0; j < 9; j++) sum += __expf(av[j] + endv[j] - mx);
    lossb[b] = (mx + __logf(sum)) - red[0];
  }
}

// ---------------- entity span mean pool ----------------
__global__ __launch_bounds__(256) void k_ent(const float* __restrict__ seq,
    const int* __restrict__ est, const int* __restrict__ elen, float* __restrict__ ent) {
  const int be = blockIdx.x;
  const int b = be >> 5, e = be & 31;
  const int st = est[b * NE + e];
  int en = st + elen[b * NE + e];
  en = min(max(en, 0), NS - 1);
  const float inv = 1.f / (float)(en - st + 1);
  for (int c = threadIdx.x; c < NH; c += 256) {
    float s = 0.f;
    for (int r = st; r <= en; r++) s += seq[((size_t)b * NS + r) * NH + c];
    ent[((size_t)b * NE + e) * NH + c] = s * inv;
  }
}

// ---------------- GAT1 GEMM: h = ent @ w_gat1 (768->512) ----------------
__global__ __launch_bounds__(256) void k_g1(const float* __restrict__ ent,
    const float* __restrict__ w, float* __restrict__ hout) {
  __shared__ float As[32 * 36];
  __shared__ float Bs[32 * 128];
  const int b = blockIdx.x >> 2, cb = blockIdx.x & 3;
  const int t = threadIdx.x;
  const int tc = t & 31, tr = t >> 5;
  float acc[4][4];
#pragma unroll
  for (int i = 0; i < 4; i++)
#pragma unroll
    for (int j = 0; j < 4; j++) acc[i][j] = 0.f;
  for (int kt = 0; kt < NH; kt += 32) {
    __syncthreads();
    {
      const int e = t >> 3, k4 = t & 7;
      *reinterpret_cast<float4*>(&As[e * 36 + k4 * 4]) =
          *reinterpret_cast<const float4*>(&ent[((size_t)b * NE + e) * NH + kt + k4 * 4]);
    }
#pragma unroll
    for (int i = 0; i < 4; i++) {
      const int slot = t + 256 * i;
      const int row = slot >> 5, cg = slot & 31;
      *reinterpret_cast<float4*>(&Bs[row * 128 + cg * 4]) =
          *reinterpret_cast<const float4*>(&w[(size_t)(kt + row) * 512 + cb * 128 + cg * 4]);
    }
    __syncthreads();
#pragma unroll
    for (int kg = 0; kg < 8; kg++) {
      float4 a[4];
#pragma unroll
      for (int i = 0; i < 4; i++)
        a[i] = *reinterpret_cast<const float4*>(&As[(tr * 4 + i) * 36 + kg * 4]);
#pragma unroll
      for (int k2 = 0; k2 < 4; k2++) {
        const float4 bv = *reinterpret_cast<const float4*>(&Bs[(kg * 4 + k2) * 128 + tc * 4]);
#pragma unroll
        for (int i = 0; i < 4; i++) {
          const float av = reinterpret_cast<const float*>(&a[i])[k2];
          acc[i][0] = fmaf(av, bv.x, acc[i][0]);
          acc[i][1] = fmaf(av, bv.y, acc[i][1]);
          acc[i][2] = fmaf(av, bv.z, acc[i][2]);
          acc[i][3] = fmaf(av, bv.w, acc[i][3]);
        }
      }
    }
  }
#pragma unroll
  for (int i = 0; i < 4; i++) {
    float4 v;
    v.x = acc[i][0]; v.y = acc[i][1]; v.z = acc[i][2]; v.w = acc[i][3];
    *reinterpret_cast<float4*>(&hout[((size_t)b * NE + tr * 4 + i) * 512 + cb * 128 + tc * 4]) = v;
  }
}

// ---------------- GAT1 attention src/dst dots ----------------
__global__ __launch_bounds__(128) void k_sd1(const float* __restrict__ h,
    const float* __restrict__ as, const float* __restrict__ ad,
    float* __restrict__ s1, float* __restrict__ d1) {
  __shared__ float sm[4];
  const int be = blockIdx.x;
  const int b = be >> 5, e = be & 31;
  const int t = threadIdx.x;
  for (int hd = 0; hd < NHEADS; hd++) {
    const float v = h[((size_t)b * NE + e) * 512 + hd * NC1 + t];
    float sv = v * as[hd * NC1 + t];
    float dv = v * ad[hd * NC1 + t];
#pragma unroll
    for (int o = 32; o > 0; o >>= 1) { sv += __shfl_xor(sv, o); dv += __shfl_xor(dv, o); }
    if ((t & 63) == 0) { sm[(t >> 6) * 2] = sv; sm[(t >> 6) * 2 + 1] = dv; }
    __syncthreads();
    if (t == 0) {
      s1[(b * NHEADS + hd) * NE + e] = sm[0] + sm[2];
      d1[(b * NHEADS + hd) * NE + e] = sm[1] + sm[3];
    }
    __syncthreads();
  }
}

// ---------------- GAT1 attention + aggregate + bias + relu ----------------
__global__ __launch_bounds__(128) void k_att1(const float* __restrict__ h,
    const float* __restrict__ s1, const float* __restrict__ d1,
    const unsigned char* __restrict__ adj, const float* __restrict__ bias,
    float* __restrict__ x1) {
  __shared__ float att[NE];
  const int blk = blockIdx.x;
  const int i = blk & 31, hd = (blk >> 5) & 3, b = blk >> 7;
  const int t = threadIdx.x;
  if (t < NE) {
    float lg = d1[(b * NHEADS + hd) * NE + i] + s1[(b * NHEADS + hd) * NE + t];
    lg = lg >= 0.f ? lg : 0.2f * lg;
    if (!adj[((size_t)b * NE + i) * NE + t]) lg = -1e9f;
    att[t] = lg;
  }
  __syncthreads();
  if (t == 0) {
    float m = -1e30f;
#pragma unroll
    for (int j = 0; j < NE; j++) m = fmaxf(m, att[j]);
    float ex[NE];
    float sum = 0.f;
#pragma unroll
    for (int j = 0; j < NE; j++) { ex[j] = __expf(att[j] - m); sum += ex[j]; }
    const float inv = 1.f / sum;
#pragma unroll
    for (int j = 0; j < NE; j++) att[j] = ex[j] * inv;
  }
  __syncthreads();
  float acc = bias[hd * NC1 + t];
  for (int j = 0; j < NE; j++)
    acc += att[j] * h[((size_t)b * NE + j) * 512 + hd * NC1 + t];
  x1[((size_t)b * NE + i) * 512 + hd * NC1 + t] = fmaxf(acc, 0.f);
}

// ---------------- GAT2 GEMM + src/dst dots ----------------
__global__ __launch_bounds__(256) void k_g2(const float* __restrict__ x1,
    const float* __restrict__ w, const float* __restrict__ as, const float* __restrict__ ad,
    float* __restrict__ h2, float* __restrict__ s2, float* __restrict__ d2) {
  __shared__ float As[32 * 36];
  __shared__ float Bs[32 * 64];
  const int b = blockIdx.x;
  const int t = threadIdx.x;
  const int tc = t & 15, tr = t >> 4;
  float acc[2][4];
#pragma unroll
  for (int i = 0; i < 2; i++)
#pragma unroll
    for (int j = 0; j < 4; j++) acc[i][j] = 0.f;
  for (int kt = 0; kt < 512; kt += 32) {
    __syncthreads();
    {
      const int e = t >> 3, k4 = t & 7;
      *reinterpret_cast<float4*>(&As[e * 36 + k4 * 4]) =
          *reinterpret_cast<const float4*>(&x1[((size_t)b * NE + e) * 512 + kt + k4 * 4]);
    }
#pragma unroll
    for (int i = 0; i < 2; i++) {
      const int slot = t + 256 * i;
      const int row = slot >> 4, cg = slot & 15;
      *reinterpret_cast<float4*>(&Bs[row * 64 + cg * 4]) =
          *reinterpret_cast<const float4*>(&w[(size_t)(kt + row) * NC2 + cg * 4]);
    }
    __syncthreads();
#pragma unroll
    for (int kg = 0; kg < 8; kg++) {
      float4 a[2];
#pragma unroll
      for (int i = 0; i < 2; i++)
        a[i] = *reinterpret_cast<const float4*>(&As[(tr * 2 + i) * 36 + kg * 4]);
#pragma unroll
      for (int k2 = 0; k2 < 4; k2++) {
        const float4 bv = *reinterpret_cast<const float4*>(&Bs[(kg * 4 + k2) * 64 + tc * 4]);
#pragma unroll
        for (int i = 0; i < 2; i++) {
          const float av = reinterpret_cast<const float*>(&a[i])[k2];
          acc[i][0] = fmaf(av, bv.x, acc[i][0]);
          acc[i][1] = fmaf(av, bv.y, acc[i][1]);
          acc[i][2] = fmaf(av, bv.z, acc[i][2]);
          acc[i][3] = fmaf(av, bv.w, acc[i][3]);
        }
      }
    }
  }
  const float4 a4s = *reinterpret_cast<const float4*>(&as[tc * 4]);
  const float4 a4d = *reinterpret_cast<const float4*>(&ad[tc * 4]);
#pragma unroll
  for (int i = 0; i < 2; i++) {
    const int e = tr * 2 + i;
    float4 v;
    v.x = acc[i][0]; v.y = acc[i][1]; v.z = acc[i][2]; v.w = acc[i][3];
    *reinterpret_cast<float4*>(&h2[((size_t)b * NE + e) * NC2 + tc * 4]) = v;
    float sv = v.x * a4s.x + v.y * a4s.y + v.z * a4s.z + v.w * a4s.w;
    float dv = v.x * a4d.x + v.y * a4d.y + v.z * a4d.z + v.w * a4d.w;
#pragma unroll
    for (int o = 8; o > 0; o >>= 1) { sv += __shfl_xor(sv, o); dv += __shfl_xor(dv, o); }
    if (tc == 0) { s2[b * NE + e] = sv; d2[b * NE + e] = dv; }
  }
}

// ---------------- GAT2 attention + aggregate + bias ----------------
__global__ __launch_bounds__(64) void k_att2(const float* __restrict__ h2,
    const float* __restrict__ s2, const float* __restrict__ d2,
    const unsigned char* __restrict__ adj, const float* __restrict__ bias,
    float* __restrict__ x2) {
  __shared__ float att[NE];
  const int be = blockIdx.x;
  const int b = be >> 5, i = be & 31;
  const int t = threadIdx.x;
  if (t < NE) {
    float lg = d2[b * NE + i] + s2[b * NE + t];
    lg = lg >= 0.f ? lg : 0.2f * lg;
    if (!adj[((size_t)b * NE + i) * NE + t]) lg = -1e9f;
    att[t] = lg;
  }
  __syncthreads();
  if (t == 0) {
    float m = -1e30f;
#pragma unroll
    for (int j = 0; j < NE; j++) m = fmaxf(m, att[j]);
    float ex[NE];
    float sum = 0.f;
#pragma unroll
    for (int j = 0; j < NE; j++) { ex[j] = __expf(att[j] - m); sum += ex[j]; }
    const float inv = 1.f / sum;
#pragma unroll
    for (int j = 0; j < NE; j++) att[j] = ex[j] * inv;
  }
  __syncthreads();
  float acc = bias[t];
  for (int j = 0; j < NE; j++)
    acc += att[j] * h2[((size_t)b * NE + j) * NC2 + t];
  x2[((size_t)b * NE + i) * NC2 + t] = acc;
}

// ---------------- ctx = mean over entities ----------------
__global__ __launch_bounds__(64) void k_ctx(const float* __restrict__ x2, float* __restrict__ ctx) {
  const int b = blockIdx.x, t = threadIdx.x;
  float s = 0.f;
  for (int e = 0; e < NE; e++) s += x2[((size_t)b * NE + e) * NC2 + t];
  ctx[b * NC2 + t] = s * (1.f / NE);
}

// ---------------- pair feature build (pitch 260) ----------------
__global__ __launch_bounds__(64) void k_pf(const float* __restrict__ x2,
    const float* __restrict__ ctx, const int* __restrict__ pe1, const int* __restrict__ pe2,
    float* __restrict__ pf) {
  const int bp = blockIdx.x;
  const int b = bp >> 4, p = bp & 15;
  const int t = threadIdx.x;
  const int e1 = pe1[b * NP + p], e2 = pe2[b * NP + p];
  const float v1 = x2[((size_t)b * NE + e1) * NC2 + t];
  const float v2 = x2[((size_t)b * NE + e2) * NC2 + t];
  float* row = pf + (size_t)bp * 260;
  row[t] = v1;
  row[64 + t] = v2;
  row[128 + t] = v1 * v2;
  row[192 + t] = ctx[b * NC2 + t];
  if (t == 0) row[256] = logf(fabsf((float)(e1 - e2)) + 1.f);
  if (t < 3) row[257 + t] = 0.f;
}

// ---------------- fe = leaky(LN(pf @ w_fe + b_fe)) -- MFMA bf16, bf16 out ----------------
// grid B, 256 threads. M=16 pairs, N=512, K=320 (zero-padded).
__global__ __launch_bounds__(256) void k_fe(const float* __restrict__ pf,
    const unsigned short* __restrict__ wt, const float* __restrict__ bfe,
    const float* __restrict__ g, const float* __restrict__ be,
    unsigned short* __restrict__ feb) {
  __shared__ unsigned short Af[16 * 320];
  __shared__ float Cs[16 * 520];
  const int b = blockIdx.x, t = threadIdx.x;
  const int w = t >> 6, lane = t & 63, quad = lane >> 4, l15 = lane & 15;
  for (int i = t; i < 16 * 320; i += 256) {
    const int p = i / 320, k = i - p * 320;
    Af[i] = (k < 260) ? f2bf(pf[(size_t)(b * NP + p) * 260 + k]) : (unsigned short)0;
  }
  __syncthreads();
  f32x4 acc[8];
#pragma unroll
  for (int c = 0; c < 8; c++) acc[c] = (f32x4){0.f, 0.f, 0.f, 0.f};
#pragma unroll
  for (int kt = 0; kt < 10; kt++) {
    const bf16x8 a = *reinterpret_cast<const bf16x8*>(&Af[l15 * 320 + kt * 32 + quad * 8]);
#pragma unroll
    for (int c = 0; c < 8; c++) {
      const int col = w * 128 + c * 16 + l15;
      const bf16x8 bv = *reinterpret_cast<const bf16x8*>(&wt[(size_t)col * 320 + kt * 32 + quad * 8]);
      acc[c] = __builtin_amdgcn_mfma_f32_16x16x32_bf16(a, bv, acc[c], 0, 0, 0);
    }
  }
#pragma unroll
  for (int c = 0; c < 8; c++)
#pragma unroll
    for (int reg = 0; reg < 4; reg++)
      Cs[(quad * 4 + reg) * 520 + w * 128 + c * 16 + l15] = acc[c][reg];
  __syncthreads();
  float bfev[8], gv[8], bev[8];
#pragma unroll
  for (int ch = 0; ch < 8; ch++) {
    const int col = ch * 64 + lane;
    bfev[ch] = bfe[col]; gv[ch] = g[col]; bev[ch] = be[col];
  }
#pragma unroll
  for (int pp = 0; pp < 4; pp++) {
    const int p = w * 4 + pp;
    float v[8], s = 0.f, sq = 0.f;
#pragma unroll
    for (int ch = 0; ch < 8; ch++) {
      v[ch] = Cs[p * 520 + ch * 64 + lane] + bfev[ch];
      s += v[ch]; sq += v[ch] * v[ch];
    }
#pragma unroll
    for (int o = 32; o > 0; o >>= 1) { s += __shfl_xor(s, o); sq += __shfl_xor(sq, o); }
    const float mean = s * (1.f / 512.f);
    const float var = sq * (1.f / 512.f) - mean * mean;
    const float rr = rsqrtf(var + 1e-5f);
#pragma unroll
    for (int ch = 0; ch < 8; ch++) {
      float n = (v[ch] - mean) * rr * gv[ch] + bev[ch];
      n = n >= 0.f ? n : 0.01f * n;
      feb[(size_t)(b * NP + p) * 512 + ch * 64 + lane] = f2bf(n);
    }
  }
}

// ---------------- relation heads: MFMA bf16 GEMM + LN + leaky + dot + BCE ----------------
// grid R*B, 256 threads. M=16 pairs, N=256, K=512.
__global__ __launch_bounds__(256) void k_rc(const unsigned short* __restrict__ feb,
    const unsigned short* __restrict__ wrt, const float* __restrict__ b1,
    const float* __restrict__ g, const float* __restrict__ be,
    const float* __restrict__ w2, const float* __restrict__ b2,
    const int* __restrict__ ylab, float* __restrict__ zout, float* __restrict__ relacc) {
  __shared__ unsigned short Af[16 * 520];
  __shared__ float Cs[16 * 264];
  const int blk = blockIdx.x;
  const int r = blk >> 6, b = blk & 63;
  const int t = threadIdx.x;
  const int w = t >> 6, lane = t & 63, quad = lane >> 4, l15 = lane & 15;
#pragma unroll
  for (int i = 0; i < 4; i++) {
    const int slot = t + 256 * i;
    const int p = slot >> 6, q = slot & 63;
    *reinterpret_cast<uint4*>(&Af[p * 520 + q * 8]) =
        *reinterpret_cast<const uint4*>(&feb[(size_t)(b * NP + p) * 512 + q * 8]);
  }
  __syncthreads();
  f32x4 acc[4];
#pragma unroll
  for (int c = 0; c < 4; c++) acc[c] = (f32x4){0.f, 0.f, 0.f, 0.f};
#pragma unroll
  for (int kt = 0; kt < 16; kt++) {
    const bf16x8 a = *reinterpret_cast<const bf16x8*>(&Af[l15 * 520 + kt * 32 + quad * 8]);
#pragma unroll
    for (int c = 0; c < 4; c++) {
      const int col = w * 64 + c * 16 + l15;
      const bf16x8 bv = *reinterpret_cast<const bf16x8*>(
          &wrt[(size_t)(r * 256 + col) * 512 + kt * 32 + quad * 8]);
      acc[c] = __builtin_amdgcn_mfma_f32_16x16x32_bf16(a, bv, acc[c], 0, 0, 0);
    }
  }
#pragma unroll
  for (int c = 0; c < 4; c++)
#pragma unroll
    for (int reg = 0; reg < 4; reg++)
      Cs[(quad * 4 + reg) * 264 + w * 64 + c * 16 + l15] = acc[c][reg];
  __syncthreads();
  float b1v[4], gv[4], bev[4], w2v[4];
#pragma unroll
  for (int ch = 0; ch < 4; ch++) {
    const int col = r * 256 + ch * 64 + lane;
    b1v[ch] = b1[col]; gv[ch] = g[col]; bev[ch] = be[col]; w2v[ch] = w2[col];
  }
  const float b2v = b2[r];
  float local = 0.f;
#pragma unroll
  for (int pp = 0; pp < 4; pp++) {
    const int p = w * 4 + pp;
    float v[4], s = 0.f, sq = 0.f;
#pragma unroll
    for (int ch = 0; ch < 4; ch++) {
      v[ch] = Cs[p * 264 + ch * 64 + lane] + b1v[ch];
      s += v[ch]; sq += v[ch] * v[ch];
    }
#pragma unroll
    for (int o = 32; o > 0; o >>= 1) { s += __shfl_xor(s, o); sq += __shfl_xor(sq, o); }
    const float mean = s * (1.f / 256.f);
    const float var = sq * (1.f / 256.f) - mean * mean;
    const float rr = rsqrtf(var + 1e-5f);
    float zdot = 0.f;
#pragma unroll
    for (int ch = 0; ch < 4; ch++) {
      float n = (v[ch] - mean) * rr * gv[ch] + bev[ch];
      n = n >= 0.f ? n : 0.01f * n;
      zdot = fmaf(n, w2v[ch], zdot);
    }
#pragma unroll
    for (int o = 32; o > 0; o >>= 1) zdot += __shfl_xor(zdot, o);
    if (lane == 0) {
      const float zp = zdot + b2v;
      zout[(size_t)(r * NB + b) * NP + p] = zp;
      const float y = (float)ylab[b * NP + p];
      local += -(2.f * y * logsigf(zp) + (1.f - y) * logsigf(-zp));
    }
  }
  if (lane == 0) atomicAdd(relacc, local * (1.f / (NB * NP)));
}

// ---------------- finalize total loss ----------------
__global__ __launch_bounds__(64) void k_fin(const float* __restrict__ lossb,
    const float* __restrict__ rel, float* __restrict__ out) {
  float v = lossb[threadIdx.x];
#pragma unroll
  for (int o = 32; o > 0; o >>= 1) v += __shfl_down(v, o);
  if (threadIdx.x == 0) out[TOTOFF] = v * (1.f / NB) + rel[0];
}

extern "C" void kernel_launch(void* const* d_in, const int* in_sizes, int n_in,
                              void* d_out, int out_size, void* d_ws, size_t ws_size,
                              hipStream_t stream) {
  const float* seq = (const float*)d_in[0];
  const int* amask = (const int*)d_in[1];
  const int* nlab = (const int*)d_in[2];
  const int* est = (const int*)d_in[3];
  const int* elen = (const int*)d_in[4];
  const int* pe1 = (const int*)d_in[5];
  const int* pe2 = (const int*)d_in[6];
  const int* plab = (const int*)d_in[7];
  const unsigned char* adj = (const unsigned char*)d_in[8];
  const float* w_ner1 = (const float*)d_in[9];
  const float* b_ner1 = (const float*)d_in[10];
  const float* w_ner2 = (const float*)d_in[11];
  const float* b_ner2 = (const float*)d_in[12];
  const float* crf_start = (const float*)d_in[13];
  const float* crf_end = (const float*)d_in[14];
  const float* crf_trans = (const float*)d_in[15];
  const float* w_gat1 = (const float*)d_in[16];
  const float* a_src1 = (const float*)d_in[17];
  const float* a_dst1 = (const float*)d_in[18];
  const float* b_gat1 = (const float*)d_in[19];
  const float* w_gat2 = (const float*)d_in[20];
  const float* a_src2 = (const float*)d_in[21];
  const float* a_dst2 = (const float*)d_in[22];
  const float* b_gat2 = (const float*)d_in[23];
  const float* w_fe = (const float*)d_in[24];
  const float* b_fe = (const float*)d_in[25];
  const float* g_fe = (const float*)d_in[26];
  const float* be_fe = (const float*)d_in[27];
  const float* w_rc1 = (const float*)d_in[28];
  const float* b_rc1 = (const float*)d_in[29];
  const float* g_rc = (const float*)d_in[30];
  const float* be_rc = (const float*)d_in[31];
  const float* w_rc2 = (const float*)d_in[32];
  const float* b_rc2 = (const float*)d_in[33];

  float* out = (float*)d_out;
  float* ws = (float*)d_ws;
  float* ent = ws + WS_ENT;
  float* hg1 = ws + WS_HG1;
  float* x1 = ws + WS_X1;
  float* h2 = ws + WS_H2;
  float* x2 = ws + WS_X2;
  float* s1 = ws + WS_S1;
  float* d1 = ws + WS_D1;
  float* s2 = ws + WS_S2;
  float* d2 = ws + WS_D2;
  float* ctx = ws + WS_CTX;
  float* pf = ws + WS_PF;
  float* crfb = ws + WS_CRF;
  float* rel = ws + WS_REL;
  unsigned short* w1t = (unsigned short*)(ws + WS_W1T);
  unsigned short* feb = (unsigned short*)(ws + WS_FE);
  unsigned short* wrt = (unsigned short*)(ws + WS_WRT);    // overlaps dead ENT region
  unsigned short* wfet = (unsigned short*)(ws + WS_WFET);  // overlaps dead ENT region

  hipMemsetAsync(rel, 0, sizeof(float), stream);

  k_w1t<<<NH, 256, 0, stream>>>(w_ner1, w1t);
  k_ner<<<512, 256, 0, stream>>>(seq, w1t, b_ner1, w_ner2, b_ner2, out);
  k_crf<<<64, 256, 0, stream>>>(out, nlab, amask, crf_start, crf_end, crf_trans, crfb);
  k_ent<<<NB * NE, 256, 0, stream>>>(seq, est, elen, ent);
  k_g1<<<NB * 4, 256, 0, stream>>>(ent, w_gat1, hg1);
  // ent is dead after k_g1 -> its region now hosts wrt/wfet
  k_wrt<<<NR * 8, 256, 0, stream>>>(w_rc1, wrt);
  k_wfet<<<10, 256, 0, stream>>>(w_fe, wfet);
  k_sd1<<<NB * NE, 128, 0, stream>>>(hg1, a_src1, a_dst1, s1, d1);
  k_att1<<<NB * NHEADS * NE, 128, 0, stream>>>(hg1, s1, d1, adj, b_gat1, x1);
  k_g2<<<NB, 256, 0, stream>>>(x1, w_gat2, a_src2, a_dst2, h2, s2, d2);
  k_att2<<<NB * NE, 64, 0, stream>>>(h2, s2, d2, adj, b_gat2, x2);
  k_ctx<<<NB, 64, 0, stream>>>(x2, ctx);
  k_pf<<<NB * NP, 64, 0, stream>>>(x2, ctx, pe1, pe2, pf);
  k_fe<<<NB, 256, 0, stream>>>(pf, wfet, b_fe, g_fe, be_fe, feb);
  k_rc<<<NR * NB, 256, 0, stream>>>(feb, wrt, b_rc1, g_rc, be_rc, w_rc2, b_rc2,
                                    plab, out + ZOFF, rel);
  k_fin<<<1, 64, 0, stream>>>(crfb, rel, out);
}

// Round 6
// 449.190 us; speedup vs baseline: 4.5558x; 1.0909x over previous
//
#include <hip/hip_runtime.h>
#include <math.h>

// Problem: NERRelationModel_84963043050124
// B=64 S=512 H=768 E=32 P=16 K=9 R=6 HEADS=4 C1=128 C2=64 FEAT=257
// Outputs: ner_logits [B,S,K]=294912, z [R,B,P]=6144, total [1] -> 301057 f32

#define NB 64
#define NS 512
#define NH 768
#define NE 32
#define NP 16
#define NK 9
#define NR 6
#define NHEADS 4
#define NC1 128
#define NC2 64
#define SEGS 16
#define SEGLEN 32

#define ZOFF 294912
#define TOTOFF 301056

// ---- workspace layout (float offsets) ----
#define WS_ENT   0u           // [B,E,768]  (reused: WRT/WFET/SEG after k_g1)
#define WS_HG1   1572864u     // [B,E,512]
#define WS_X1    2621440u     // [B,E,512]
#define WS_H2    3670016u     // [B,E,64]
#define WS_X2    3801088u     // [B,E,64]
#define WS_S1    3932160u     // [B,4,E]
#define WS_D1    3940352u
#define WS_S2    3948544u     // [B,E]
#define WS_D2    3950592u
#define WS_CTX   3952640u     // [B,64]
#define WS_PF    3956736u     // [B*P, 260] padded pitch
#define WS_FE    4222976u     // bf16 [B,P,512]
#define WS_CRF   4747264u     // [64]
#define WS_REL   4747328u     // [1]
#define WS_W1T   4747392u     // bf16 [256][768] = 98304 floats
// overlapped into dead ENT region (valid after k_g1 consumed ent):
#define WS_WRT   0u           // bf16 [R*256][512] = 393216 floats
#define WS_WFET  393216u      // bf16 [512][320]   = 81920 floats
#define WS_SEG   475136u      // f32 [B][SEGS][81] = 82944 floats

typedef __attribute__((ext_vector_type(8))) short bf16x8;
typedef __attribute__((ext_vector_type(4))) float f32x4;

__device__ __forceinline__ unsigned short f2bf(float x) {
  union { float f; unsigned u; } v; v.f = x;
  unsigned r = v.u + 0x7FFFu + ((v.u >> 16) & 1u);
  return (unsigned short)(r >> 16);
}

__device__ __forceinline__ float logsigf(float x) {
  if (x >= 0.f) return -log1pf(__expf(-x));
  return x - log1pf(__expf(x));
}

// ---------------- w1 -> bf16 transposed [col][k] ----------------
__global__ __launch_bounds__(256) void k_w1t(const float* __restrict__ w1,
    unsigned short* __restrict__ w1t) {
  const int k = blockIdx.x, t = threadIdx.x;
  w1t[t * NH + k] = f2bf(w1[k * 256 + t]);
}

// ---------------- w_rc1 [r][k(512)][col(256)] -> bf16 [r*256+col][512] ----------------
__global__ __launch_bounds__(256) void k_wrt(const float* __restrict__ w1,
    unsigned short* __restrict__ wrt) {
  __shared__ unsigned short tr[256 * 72];
  const int r = blockIdx.x >> 3, kt = blockIdx.x & 7;
  const int k0 = kt * 64, t = threadIdx.x;
#pragma unroll
  for (int i = 0; i < 16; i++) {
    const int slot = t + 256 * i;
    const int row = slot >> 6, c4 = slot & 63;
    const float4 f = *reinterpret_cast<const float4*>(
        &w1[((size_t)(r * 512) + k0 + row) * 256 + c4 * 4]);
    tr[(c4 * 4 + 0) * 72 + row] = f2bf(f.x);
    tr[(c4 * 4 + 1) * 72 + row] = f2bf(f.y);
    tr[(c4 * 4 + 2) * 72 + row] = f2bf(f.z);
    tr[(c4 * 4 + 3) * 72 + row] = f2bf(f.w);
  }
  __syncthreads();
#pragma unroll
  for (int i = 0; i < 8; i++) {
    const int slot = t + 256 * i;
    const int col = slot >> 3, q = slot & 7;
    *reinterpret_cast<uint4*>(&wrt[((size_t)(r * 256 + col)) * 512 + k0 + q * 8]) =
        *reinterpret_cast<const uint4*>(&tr[col * 72 + q * 8]);
  }
}

// ---------------- w_fe [k(257)][col(512)] -> bf16 [col][320] ----------------
__global__ __launch_bounds__(256) void k_wfet(const float* __restrict__ w,
    unsigned short* __restrict__ wt) {
  __shared__ unsigned short tr[256 * 72];
  const int kt = blockIdx.x % 5, cb = blockIdx.x / 5;
  const int k0 = kt * 64, c0 = cb * 256, t = threadIdx.x;
#pragma unroll
  for (int i = 0; i < 16; i++) {
    const int slot = t + 256 * i;
    const int row = slot >> 6, c4 = slot & 63;
    const int k = k0 + row;
    float4 f = {0.f, 0.f, 0.f, 0.f};
    if (k < 257)
      f = *reinterpret_cast<const float4*>(&w[(size_t)k * 512 + c0 + c4 * 4]);
    tr[(c4 * 4 + 0) * 72 + row] = f2bf(f.x);
    tr[(c4 * 4 + 1) * 72 + row] = f2bf(f.y);
    tr[(c4 * 4 + 2) * 72 + row] = f2bf(f.z);
    tr[(c4 * 4 + 3) * 72 + row] = f2bf(f.w);
  }
  __syncthreads();
#pragma unroll
  for (int i = 0; i < 8; i++) {
    const int slot = t + 256 * i;
    const int col = slot >> 3, q = slot & 7;
    *reinterpret_cast<uint4*>(&wt[((size_t)(c0 + col)) * 320 + k0 + q * 8]) =
        *reinterpret_cast<const uint4*>(&tr[col * 72 + q * 8]);
  }
}

// ---------------- NER head: MFMA bf16 ----------------
__global__ __launch_bounds__(256) void k_ner(const float* __restrict__ seq,
    const unsigned short* __restrict__ w1t, const float* __restrict__ b1,
    const float* __restrict__ w2, const float* __restrict__ b2,
    float* __restrict__ out) {
  __shared__ unsigned short AsS[64 * 40];
  __shared__ unsigned short BsS[256 * 40];
  __shared__ float zs[64 * 4 * 12];
  const int t = threadIdx.x;
  const int tok0 = blockIdx.x * 64;
  const int w = t >> 6, lane = t & 63, quad = lane >> 4, l15 = lane & 15;

  f32x4 acc[4][4];
#pragma unroll
  for (int r = 0; r < 4; r++)
#pragma unroll
    for (int c = 0; c < 4; c++) acc[r][c] = (f32x4){0.f, 0.f, 0.f, 0.f};

  const int tokA = t >> 2, koffA = (t & 3) * 8;
  const float* aptr = seq + (size_t)(tok0 + tokA) * NH + koffA;

  for (int kt = 0; kt < NH; kt += 32) {
    __syncthreads();
    {
      const float4 f0 = *reinterpret_cast<const float4*>(aptr + kt);
      const float4 f1 = *reinterpret_cast<const float4*>(aptr + kt + 4);
      bf16x8 av;
      av[0] = (short)f2bf(f0.x); av[1] = (short)f2bf(f0.y);
      av[2] = (short)f2bf(f0.z); av[3] = (short)f2bf(f0.w);
      av[4] = (short)f2bf(f1.x); av[5] = (short)f2bf(f1.y);
      av[6] = (short)f2bf(f1.z); av[7] = (short)f2bf(f1.w);
      *reinterpret_cast<bf16x8*>(&AsS[tokA * 40 + koffA]) = av;
    }
#pragma unroll
    for (int i = 0; i < 4; i++) {
      const int q = t + 256 * i;
      const int col = q >> 2, koff = (q & 3) * 8;
      *reinterpret_cast<uint4*>(&BsS[col * 40 + koff]) =
          *reinterpret_cast<const uint4*>(&w1t[(size_t)col * NH + kt + koff]);
    }
    __syncthreads();
    bf16x8 a[4], b[4];
#pragma unroll
    for (int r = 0; r < 4; r++)
      a[r] = *reinterpret_cast<const bf16x8*>(&AsS[(r * 16 + l15) * 40 + quad * 8]);
#pragma unroll
    for (int c = 0; c < 4; c++)
      b[c] = *reinterpret_cast<const bf16x8*>(&BsS[(w * 64 + c * 16 + l15) * 40 + quad * 8]);
#pragma unroll
    for (int r = 0; r < 4; r++)
#pragma unroll
      for (int c = 0; c < 4; c++)
        acc[r][c] = __builtin_amdgcn_mfma_f32_16x16x32_bf16(a[r], b[c], acc[r][c], 0, 0, 0);
  }

  float b1v[4], w2v[4][NK];
#pragma unroll
  for (int c = 0; c < 4; c++) {
    const int col = w * 64 + c * 16 + l15;
    b1v[c] = b1[col];
#pragma unroll
    for (int cc = 0; cc < NK; cc++) w2v[c][cc] = w2[col * NK + cc];
  }
#pragma unroll
  for (int r = 0; r < 4; r++) {
#pragma unroll
    for (int reg = 0; reg < 4; reg++) {
      float p[NK];
#pragma unroll
      for (int cc = 0; cc < NK; cc++) p[cc] = 0.f;
#pragma unroll
      for (int c = 0; c < 4; c++) {
        const float h = fmaxf(acc[r][c][reg] + b1v[c], 0.f);
#pragma unroll
        for (int cc = 0; cc < NK; cc++) p[cc] = fmaf(h, w2v[c][cc], p[cc]);
      }
#pragma unroll
      for (int o = 1; o < 16; o <<= 1)
#pragma unroll
        for (int cc = 0; cc < NK; cc++) p[cc] += __shfl_xor(p[cc], o);
      if (l15 == 0) {
        const int tokr = r * 16 + quad * 4 + reg;
#pragma unroll
        for (int cc = 0; cc < NK; cc++) zs[(tokr * 4 + w) * 12 + cc] = p[cc];
      }
    }
  }
  __syncthreads();
  if (t < 64) {
#pragma unroll
    for (int cc = 0; cc < NK; cc++) {
      const float z = zs[(t * 4 + 0) * 12 + cc] + zs[(t * 4 + 1) * 12 + cc] +
                      zs[(t * 4 + 2) * 12 + cc] + zs[(t * 4 + 3) * 12 + cc] + b2[cc];
      out[(size_t)(tok0 + t) * NK + cc] = z;
    }
  }
}

// ---------------- CRF segment reduce: 32 steps -> one 9x9 log-semiring matrix ----------------
// grid NB*SEGS (1024), 128 threads.
__global__ __launch_bounds__(128) void k_crf_seg(const float* __restrict__ em,
    const int* __restrict__ mask, const float* __restrict__ trans,
    float* __restrict__ segm) {
  __shared__ float bufA[16 * 81];
  __shared__ float bufB[8 * 81];
  __shared__ float ems[SEGLEN * 9];
  __shared__ int mks[SEGLEN];
  __shared__ float trs[81];
  const int blk = blockIdx.x;
  const int b = blk >> 4, seg = blk & 15;
  const int t = threadIdx.x;
  const int s0 = 1 + seg * SEGLEN;
  const float* emb = em + (size_t)b * NS * NK;
  const int* mk = mask + b * NS;
  if (t < 81) trs[t] = trans[t];
  for (int i = t; i < SEGLEN * 9; i += 128) {
    const int g = s0 * 9 + i;
    ems[i] = (g < NS * 9) ? emb[g] : 0.f;
  }
  if (t < SEGLEN) {
    const int s = s0 + t;
    mks[t] = (s < NS) ? mk[s] : 0;
  }
  __syncthreads();
  // leaves: 16 pair matrices
  for (int idx = t; idx < 16 * 81; idx += 128) {
    const int p = idx / 81, e = idx % 81, i = e / 9, j = e % 9;
    const int la = 2 * p, lb = la + 1;
    const bool ma = mks[la] > 0, mb = mks[lb] > 0;
    float r;
    if (ma && mb) {
      float v[9], mx = -1e30f;
#pragma unroll
      for (int m = 0; m < 9; m++) {
        v[m] = trs[i * 9 + m] + ems[la * 9 + m] + trs[m * 9 + j];
        mx = fmaxf(mx, v[m]);
      }
      float sum = 0.f;
#pragma unroll
      for (int m = 0; m < 9; m++) sum += __expf(v[m] - mx);
      r = mx + __logf(sum) + ems[lb * 9 + j];
    } else if (ma) {
      r = trs[e] + ems[la * 9 + j];
    } else if (mb) {
      r = trs[e] + ems[lb * 9 + j];
    } else {
      r = (i == j) ? 0.f : -1e30f;
    }
    bufA[p * 81 + e] = r;
  }
  float* src = bufA;
  float* dst = bufB;
  for (int n = 16; n > 1; n >>= 1) {
    __syncthreads();
    const int half = n >> 1;
    for (int idx = t; idx < half * 81; idx += 128) {
      const int q = idx / 81, e = idx % 81, i = e / 9, j = e % 9;
      const float* A = src + (size_t)(2 * q) * 81;
      const float* Bm = src + (size_t)(2 * q + 1) * 81;
      float v[9], mx = -1e30f;
#pragma unroll
      for (int m = 0; m < 9; m++) {
        v[m] = A[i * 9 + m] + Bm[m * 9 + j];
        mx = fmaxf(mx, v[m]);
      }
      float sum = 0.f;
#pragma unroll
      for (int m = 0; m < 9; m++) sum += __expf(v[m] - mx);
      dst[q * 81 + e] = mx + __logf(sum);
    }
    float* tmp = src; src = dst; dst = tmp;
  }
  __syncthreads();
  if (t < 81) segm[((size_t)b * SEGS + seg) * 81 + t] = src[t];
}

// ---------------- CRF finalize: numerator + alpha chain through SEGS matrices ----------------
// grid NB, 64 threads (single wave).
__global__ __launch_bounds__(64) void k_crf_fin(const float* __restrict__ em,
    const int* __restrict__ tags, const int* __restrict__ mask,
    const float* __restrict__ startv, const float* __restrict__ endv,
    const float* __restrict__ trans, const float* __restrict__ segm,
    float* __restrict__ lossb) {
  __shared__ float sm[SEGS * 81];
  __shared__ float av[16];
  __shared__ float red[2];
  const int b = blockIdx.x, t = threadIdx.x;
  const float* emb = em + (size_t)b * NS * NK;
  const int* mk = mask + b * NS;
  const int* tg = tags + b * NS;
  for (int i = t; i < SEGS * 81; i += 64) sm[i] = segm[(size_t)b * SEGS * 81 + i];
  {
    float num = 0.f;
    int lastS = 0;
#pragma unroll
    for (int o = 0; o < 8; o++) {
      const int s = t * 8 + o;
      if (s >= 1 && mk[s] > 0) {
        const int cur = tg[s], prv = tg[s - 1];
        num += trans[prv * NK + cur] + emb[s * NK + cur];
        lastS = s;
      }
    }
#pragma unroll
    for (int o = 32; o > 0; o >>= 1) {
      num += __shfl_xor(num, o);
      lastS = max(lastS, __shfl_xor(lastS, o));
    }
    if (t == 0) {
      const int t0 = tg[0];
      red[0] = startv[t0] + emb[t0] + num + endv[tg[lastS]];
    }
  }
  __syncthreads();
  if (t < 9) av[t] = startv[t] + emb[t];
  __syncthreads();
  for (int h = 0; h < SEGS; h++) {
    float nv = 0.f;
    if (t < 9) {
      float v[9], mx = -1e30f;
#pragma unroll
      for (int i2 = 0; i2 < 9; i2++) {
        v[i2] = av[i2] + sm[h * 81 + i2 * 9 + t];
        mx = fmaxf(mx, v[i2]);
      }
      float sum = 0.f;
#pragma unroll
      for (int i2 = 0; i2 < 9; i2++) sum += __expf(v[i2] - mx);
      nv = mx + __logf(sum);
    }
    __syncthreads();
    if (t < 9) av[t] = nv;
    __syncthreads();
  }
  if (t == 0) {
    float mx = -1e30f;
#pragma unroll
    for (int j = 0; j < 9; j++) mx = fmaxf(mx, av[j] + endv[j]);
    float sum = 0.f;
#pragma unroll
    for (int j = 0; j < 9; j++) sum += __expf(av[j] + endv[j] - mx);
    lossb[b] = (mx + __logf(sum)) - red[0];
  }
}

// ---------------- entity span mean pool ----------------
__global__ __launch_bounds__(256) void k_ent(const float* __restrict__ seq,
    const int* __restrict__ est, const int* __restrict__ elen, float* __restrict__ ent) {
  const int be = blockIdx.x;
  const int b = be >> 5, e = be & 31;
  const int st = est[b * NE + e];
  int en = st + elen[b * NE + e];
  en = min(max(en, 0), NS - 1);
  const float inv = 1.f / (float)(en - st + 1);
  for (int c = threadIdx.x; c < NH; c += 256) {
    float s = 0.f;
    for (int r = st; r <= en; r++) s += seq[((size_t)b * NS + r) * NH + c];
    ent[((size_t)b * NE + e) * NH + c] = s * inv;
  }
}

// ---------------- GAT1 GEMM: h = ent @ w_gat1 (768->512) ----------------
__global__ __launch_bounds__(256) void k_g1(const float* __restrict__ ent,
    const float* __restrict__ w, float* __restrict__ hout) {
  __shared__ float As[32 * 36];
  __shared__ float Bs[32 * 128];
  const int b = blockIdx.x >> 2, cb = blockIdx.x & 3;
  const int t = threadIdx.x;
  const int tc = t & 31, tr = t >> 5;
  float acc[4][4];
#pragma unroll
  for (int i = 0; i < 4; i++)
#pragma unroll
    for (int j = 0; j < 4; j++) acc[i][j] = 0.f;
  for (int kt = 0; kt < NH; kt += 32) {
    __syncthreads();
    {
      const int e = t >> 3, k4 = t & 7;
      *reinterpret_cast<float4*>(&As[e * 36 + k4 * 4]) =
          *reinterpret_cast<const float4*>(&ent[((size_t)b * NE + e) * NH + kt + k4 * 4]);
    }
#pragma unroll
    for (int i = 0; i < 4; i++) {
      const int slot = t + 256 * i;
      const int row = slot >> 5, cg = slot & 31;
      *reinterpret_cast<float4*>(&Bs[row * 128 + cg * 4]) =
          *reinterpret_cast<const float4*>(&w[(size_t)(kt + row) * 512 + cb * 128 + cg * 4]);
    }
    __syncthreads();
#pragma unroll
    for (int kg = 0; kg < 8; kg++) {
      float4 a[4];
#pragma unroll
      for (int i = 0; i < 4; i++)
        a[i] = *reinterpret_cast<const float4*>(&As[(tr * 4 + i) * 36 + kg * 4]);
#pragma unroll
      for (int k2 = 0; k2 < 4; k2++) {
        const float4 bv = *reinterpret_cast<const float4*>(&Bs[(kg * 4 + k2) * 128 + tc * 4]);
#pragma unroll
        for (int i = 0; i < 4; i++) {
          const float av = reinterpret_cast<const float*>(&a[i])[k2];
          acc[i][0] = fmaf(av, bv.x, acc[i][0]);
          acc[i][1] = fmaf(av, bv.y, acc[i][1]);
          acc[i][2] = fmaf(av, bv.z, acc[i][2]);
          acc[i][3] = fmaf(av, bv.w, acc[i][3]);
        }
      }
    }
  }
#pragma unroll
  for (int i = 0; i < 4; i++) {
    float4 v;
    v.x = acc[i][0]; v.y = acc[i][1]; v.z = acc[i][2]; v.w = acc[i][3];
    *reinterpret_cast<float4*>(&hout[((size_t)b * NE + tr * 4 + i) * 512 + cb * 128 + tc * 4]) = v;
  }
}

// ---------------- GAT1 attention src/dst dots ----------------
__global__ __launch_bounds__(128) void k_sd1(const float* __restrict__ h,
    const float* __restrict__ as, const float* __restrict__ ad,
    float* __restrict__ s1, float* __restrict__ d1) {
  __shared__ float sm[4];
  const int be = blockIdx.x;
  const int b = be >> 5, e = be & 31;
  const int t = threadIdx.x;
  for (int hd = 0; hd < NHEADS; hd++) {
    const float v = h[((size_t)b * NE + e) * 512 + hd * NC1 + t];
    float sv = v * as[hd * NC1 + t];
    float dv = v * ad[hd * NC1 + t];
#pragma unroll
    for (int o = 32; o > 0; o >>= 1) { sv += __shfl_xor(sv, o); dv += __shfl_xor(dv, o); }
    if ((t & 63) == 0) { sm[(t >> 6) * 2] = sv; sm[(t >> 6) * 2 + 1] = dv; }
    __syncthreads();
    if (t == 0) {
      s1[(b * NHEADS + hd) * NE + e] = sm[0] + sm[2];
      d1[(b * NHEADS + hd) * NE + e] = sm[1] + sm[3];
    }
    __syncthreads();
  }
}

// ---------------- GAT1 attention + aggregate + bias + relu ----------------
__global__ __launch_bounds__(128) void k_att1(const float* __restrict__ h,
    const float* __restrict__ s1, const float* __restrict__ d1,
    const unsigned char* __restrict__ adj, const float* __restrict__ bias,
    float* __restrict__ x1) {
  __shared__ float att[NE];
  const int blk = blockIdx.x;
  const int i = blk & 31, hd = (blk >> 5) & 3, b = blk >> 7;
  const int t = threadIdx.x;
  if (t < NE) {
    float lg = d1[(b * NHEADS + hd) * NE + i] + s1[(b * NHEADS + hd) * NE + t];
    lg = lg >= 0.f ? lg : 0.2f * lg;
    if (!adj[((size_t)b * NE + i) * NE + t]) lg = -1e9f;
    att[t] = lg;
  }
  __syncthreads();
  if (t == 0) {
    float m = -1e30f;
#pragma unroll
    for (int j = 0; j < NE; j++) m = fmaxf(m, att[j]);
    float ex[NE];
    float sum = 0.f;
#pragma unroll
    for (int j = 0; j < NE; j++) { ex[j] = __expf(att[j] - m); sum += ex[j]; }
    const float inv = 1.f / sum;
#pragma unroll
    for (int j = 0; j < NE; j++) att[j] = ex[j] * inv;
  }
  __syncthreads();
  float acc = bias[hd * NC1 + t];
  for (int j = 0; j < NE; j++)
    acc += att[j] * h[((size_t)b * NE + j) * 512 + hd * NC1 + t];
  x1[((size_t)b * NE + i) * 512 + hd * NC1 + t] = fmaxf(acc, 0.f);
}

// ---------------- GAT2 GEMM + src/dst dots ----------------
__global__ __launch_bounds__(256) void k_g2(const float* __restrict__ x1,
    const float* __restrict__ w, const float* __restrict__ as, const float* __restrict__ ad,
    float* __restrict__ h2, float* __restrict__ s2, float* __restrict__ d2) {
  __shared__ float As[32 * 36];
  __shared__ float Bs[32 * 64];
  const int b = blockIdx.x;
  const int t = threadIdx.x;
  const int tc = t & 15, tr = t >> 4;
  float acc[2][4];
#pragma unroll
  for (int i = 0; i < 2; i++)
#pragma unroll
    for (int j = 0; j < 4; j++) acc[i][j] = 0.f;
  for (int kt = 0; kt < 512; kt += 32) {
    __syncthreads();
    {
      const int e = t >> 3, k4 = t & 7;
      *reinterpret_cast<float4*>(&As[e * 36 + k4 * 4]) =
          *reinterpret_cast<const float4*>(&x1[((size_t)b * NE + e) * 512 + kt + k4 * 4]);
    }
#pragma unroll
    for (int i = 0; i < 2; i++) {
      const int slot = t + 256 * i;
      const int row = slot >> 4, cg = slot & 15;
      *reinterpret_cast<float4*>(&Bs[row * 64 + cg * 4]) =
          *reinterpret_cast<const float4*>(&w[(size_t)(kt + row) * NC2 + cg * 4]);
    }
    __syncthreads();
#pragma unroll
    for (int kg = 0; kg < 8; kg++) {
      float4 a[2];
#pragma unroll
      for (int i = 0; i < 2; i++)
        a[i] = *reinterpret_cast<const float4*>(&As[(tr * 2 + i) * 36 + kg * 4]);
#pragma unroll
      for (int k2 = 0; k2 < 4; k2++) {
        const float4 bv = *reinterpret_cast<const float4*>(&Bs[(kg * 4 + k2) * 64 + tc * 4]);
#pragma unroll
        for (int i = 0; i < 2; i++) {
          const float av = reinterpret_cast<const float*>(&a[i])[k2];
          acc[i][0] = fmaf(av, bv.x, acc[i][0]);
          acc[i][1] = fmaf(av, bv.y, acc[i][1]);
          acc[i][2] = fmaf(av, bv.z, acc[i][2]);
          acc[i][3] = fmaf(av, bv.w, acc[i][3]);
        }
      }
    }
  }
  const float4 a4s = *reinterpret_cast<const float4*>(&as[tc * 4]);
  const float4 a4d = *reinterpret_cast<const float4*>(&ad[tc * 4]);
#pragma unroll
  for (int i = 0; i < 2; i++) {
    const int e = tr * 2 + i;
    float4 v;
    v.x = acc[i][0]; v.y = acc[i][1]; v.z = acc[i][2]; v.w = acc[i][3];
    *reinterpret_cast<float4*>(&h2[((size_t)b * NE + e) * NC2 + tc * 4]) = v;
    float sv = v.x * a4s.x + v.y * a4s.y + v.z * a4s.z + v.w * a4s.w;
    float dv = v.x * a4d.x + v.y * a4d.y + v.z * a4d.z + v.w * a4d.w;
#pragma unroll
    for (int o = 8; o > 0; o >>= 1) { sv += __shfl_xor(sv, o); dv += __shfl_xor(dv, o); }
    if (tc == 0) { s2[b * NE + e] = sv; d2[b * NE + e] = dv; }
  }
}

// ---------------- GAT2 attention + aggregate + bias ----------------
__global__ __launch_bounds__(64) void k_att2(const float* __restrict__ h2,
    const float* __restrict__ s2, const float* __restrict__ d2,
    const unsigned char* __restrict__ adj, const float* __restrict__ bias,
    float* __restrict__ x2) {
  __shared__ float att[NE];
  const int be = blockIdx.x;
  const int b = be >> 5, i = be & 31;
  const int t = threadIdx.x;
  if (t < NE) {
    float lg = d2[b * NE + i] + s2[b * NE + t];
    lg = lg >= 0.f ? lg : 0.2f * lg;
    if (!adj[((size_t)b * NE + i) * NE + t]) lg = -1e9f;
    att[t] = lg;
  }
  __syncthreads();
  if (t == 0) {
    float m = -1e30f;
#pragma unroll
    for (int j = 0; j < NE; j++) m = fmaxf(m, att[j]);
    float ex[NE];
    float sum = 0.f;
#pragma unroll
    for (int j = 0; j < NE; j++) { ex[j] = __expf(att[j] - m); sum += ex[j]; }
    const float inv = 1.f / sum;
#pragma unroll
    for (int j = 0; j < NE; j++) att[j] = ex[j] * inv;
  }
  __syncthreads();
  float acc = bias[t];
  for (int j = 0; j < NE; j++)
    acc += att[j] * h2[((size_t)b * NE + j) * NC2 + t];
  x2[((size_t)b * NE + i) * NC2 + t] = acc;
}

// ---------------- ctx = mean over entities ----------------
__global__ __launch_bounds__(64) void k_ctx(const float* __restrict__ x2, float* __restrict__ ctx) {
  const int b = blockIdx.x, t = threadIdx.x;
  float s = 0.f;
  for (int e = 0; e < NE; e++) s += x2[((size_t)b * NE + e) * NC2 + t];
  ctx[b * NC2 + t] = s * (1.f / NE);
}

// ---------------- pair feature build (pitch 260) ----------------
__global__ __launch_bounds__(64) void k_pf(const float* __restrict__ x2,
    const float* __restrict__ ctx, const int* __restrict__ pe1, const int* __restrict__ pe2,
    float* __restrict__ pf) {
  const int bp = blockIdx.x;
  const int b = bp >> 4, p = bp & 15;
  const int t = threadIdx.x;
  const int e1 = pe1[b * NP + p], e2 = pe2[b * NP + p];
  const float v1 = x2[((size_t)b * NE + e1) * NC2 + t];
  const float v2 = x2[((size_t)b * NE + e2) * NC2 + t];
  float* row = pf + (size_t)bp * 260;
  row[t] = v1;
  row[64 + t] = v2;
  row[128 + t] = v1 * v2;
  row[192 + t] = ctx[b * NC2 + t];
  if (t == 0) row[256] = logf(fabsf((float)(e1 - e2)) + 1.f);
  if (t < 3) row[257 + t] = 0.f;
}

// ---------------- fe = leaky(LN(pf @ w_fe + b_fe)) -- MFMA bf16, bf16 out ----------------
__global__ __launch_bounds__(256) void k_fe(const float* __restrict__ pf,
    const unsigned short* __restrict__ wt, const float* __restrict__ bfe,
    const float* __restrict__ g, const float* __restrict__ be,
    unsigned short* __restrict__ feb) {
  __shared__ unsigned short Af[16 * 320];
  __shared__ float Cs[16 * 520];
  const int b = blockIdx.x, t = threadIdx.x;
  const int w = t >> 6, lane = t & 63, quad = lane >> 4, l15 = lane & 15;
  for (int i = t; i < 16 * 320; i += 256) {
    const int p = i / 320, k = i - p * 320;
    Af[i] = (k < 260) ? f2bf(pf[(size_t)(b * NP + p) * 260 + k]) : (unsigned short)0;
  }
  __syncthreads();
  f32x4 acc[8];
#pragma unroll
  for (int c = 0; c < 8; c++) acc[c] = (f32x4){0.f, 0.f, 0.f, 0.f};
#pragma unroll
  for (int kt = 0; kt < 10; kt++) {
    const bf16x8 a = *reinterpret_cast<const bf16x8*>(&Af[l15 * 320 + kt * 32 + quad * 8]);
#pragma unroll
    for (int c = 0; c < 8; c++) {
      const int col = w * 128 + c * 16 + l15;
      const bf16x8 bv = *reinterpret_cast<const bf16x8*>(&wt[(size_t)col * 320 + kt * 32 + quad * 8]);
      acc[c] = __builtin_amdgcn_mfma_f32_16x16x32_bf16(a, bv, acc[c], 0, 0, 0);
    }
  }
#pragma unroll
  for (int c = 0; c < 8; c++)
#pragma unroll
    for (int reg = 0; reg < 4; reg++)
      Cs[(quad * 4 + reg) * 520 + w * 128 + c * 16 + l15] = acc[c][reg];
  __syncthreads();
  float bfev[8], gv[8], bev[8];
#pragma unroll
  for (int ch = 0; ch < 8; ch++) {
    const int col = ch * 64 + lane;
    bfev[ch] = bfe[col]; gv[ch] = g[col]; bev[ch] = be[col];
  }
#pragma unroll
  for (int pp = 0; pp < 4; pp++) {
    const int p = w * 4 + pp;
    float v[8], s = 0.f, sq = 0.f;
#pragma unroll
    for (int ch = 0; ch < 8; ch++) {
      v[ch] = Cs[p * 520 + ch * 64 + lane] + bfev[ch];
      s += v[ch]; sq += v[ch] * v[ch];
    }
#pragma unroll
    for (int o = 32; o > 0; o >>= 1) { s += __shfl_xor(s, o); sq += __shfl_xor(sq, o); }
    const float mean = s * (1.f / 512.f);
    const float var = sq * (1.f / 512.f) - mean * mean;
    const float rr = rsqrtf(var + 1e-5f);
#pragma unroll
    for (int ch = 0; ch < 8; ch++) {
      float n = (v[ch] - mean) * rr * gv[ch] + bev[ch];
      n = n >= 0.f ? n : 0.01f * n;
      feb[(size_t)(b * NP + p) * 512 + ch * 64 + lane] = f2bf(n);
    }
  }
}

// ---------------- relation heads: MFMA bf16 GEMM + LN + leaky + dot + BCE ----------------
__global__ __launch_bounds__(256) void k_rc(const unsigned short* __restrict__ feb,
    const unsigned short* __restrict__ wrt, const float* __restrict__ b1,
    const float* __restrict__ g, const float* __restrict__ be,
    const float* __restrict__ w2, const float* __restrict__ b2,
    const int* __restrict__ ylab, float* __restrict__ zout, float* __restrict__ relacc) {
  __shared__ unsigned short Af[16 * 520];
  __shared__ float Cs[16 * 264];
  const int blk = blockIdx.x;
  const int r = blk >> 6, b = blk & 63;
  const int t = threadIdx.x;
  const int w = t >> 6, lane = t & 63, quad = lane >> 4, l15 = lane & 15;
#pragma unroll
  for (int i = 0; i < 4; i++) {
    const int slot = t + 256 * i;
    const int p = slot >> 6, q = slot & 63;
    *reinterpret_cast<uint4*>(&Af[p * 520 + q * 8]) =
        *reinterpret_cast<const uint4*>(&feb[(size_t)(b * NP + p) * 512 + q * 8]);
  }
  __syncthreads();
  f32x4 acc[4];
#pragma unroll
  for (int c = 0; c < 4; c++) acc[c] = (f32x4){0.f, 0.f, 0.f, 0.f};
#pragma unroll
  for (int kt = 0; kt < 16; kt++) {
    const bf16x8 a = *reinterpret_cast<const bf16x8*>(&Af[l15 * 520 + kt * 32 + quad * 8]);
#pragma unroll
    for (int c = 0; c < 4; c++) {
      const int col = w * 64 + c * 16 + l15;
      const bf16x8 bv = *reinterpret_cast<const bf16x8*>(
          &wrt[(size_t)(r * 256 + col) * 512 + kt * 32 + quad * 8]);
      acc[c] = __builtin_amdgcn_mfma_f32_16x16x32_bf16(a, bv, acc[c], 0, 0, 0);
    }
  }
#pragma unroll
  for (int c = 0; c < 4; c++)
#pragma unroll
    for (int reg = 0; reg < 4; reg++)
      Cs[(quad * 4 + reg) * 264 + w * 64 + c * 16 + l15] = acc[c][reg];
  __syncthreads();
  float b1v[4], gv[4], bev[4], w2v[4];
#pragma unroll
  for (int ch = 0; ch < 4; ch++) {
    const int col = r * 256 + ch * 64 + lane;
    b1v[ch] = b1[col]; gv[ch] = g[col]; bev[ch] = be[col]; w2v[ch] = w2[col];
  }
  const float b2v = b2[r];
  float local = 0.f;
#pragma unroll
  for (int pp = 0; pp < 4; pp++) {
    const int p = w * 4 + pp;
    float v[4], s = 0.f, sq = 0.f;
#pragma unroll
    for (int ch = 0; ch < 4; ch++) {
      v[ch] = Cs[p * 264 + ch * 64 + lane] + b1v[ch];
      s += v[ch]; sq += v[ch] * v[ch];
    }
#pragma unroll
    for (int o = 32; o > 0; o >>= 1) { s += __shfl_xor(s, o); sq += __shfl_xor(sq, o); }
    const float mean = s * (1.f / 256.f);
    const float var = sq * (1.f / 256.f) - mean * mean;
    const float rr = rsqrtf(var + 1e-5f);
    float zdot = 0.f;
#pragma unroll
    for (int ch = 0; ch < 4; ch++) {
      float n = (v[ch] - mean) * rr * gv[ch] + bev[ch];
      n = n >= 0.f ? n : 0.01f * n;
      zdot = fmaf(n, w2v[ch], zdot);
    }
#pragma unroll
    for (int o = 32; o > 0; o >>= 1) zdot += __shfl_xor(zdot, o);
    if (lane == 0) {
      const float zp = zdot + b2v;
      zout[(size_t)(r * NB + b) * NP + p] = zp;
      const float y = (float)ylab[b * NP + p];
      local += -(2.f * y * logsigf(zp) + (1.f - y) * logsigf(-zp));
    }
  }
  if (lane == 0) atomicAdd(relacc, local * (1.f / (NB * NP)));
}

// ---------------- finalize total loss ----------------
__global__ __launch_bounds__(64) void k_fin(const float* __restrict__ lossb,
    const float* __restrict__ rel, float* __restrict__ out) {
  float v = lossb[threadIdx.x];
#pragma unroll
  for (int o = 32; o > 0; o >>= 1) v += __shfl_down(v, o);
  if (threadIdx.x == 0) out[TOTOFF] = v * (1.f / NB) + rel[0];
}

extern "C" void kernel_launch(void* const* d_in, const int* in_sizes, int n_in,
                              void* d_out, int out_size, void* d_ws, size_t ws_size,
                              hipStream_t stream) {
  const float* seq = (const float*)d_in[0];
  const int* amask = (const int*)d_in[1];
  const int* nlab = (const int*)d_in[2];
  const int* est = (const int*)d_in[3];
  const int* elen = (const int*)d_in[4];
  const int* pe1 = (const int*)d_in[5];
  const int* pe2 = (const int*)d_in[6];
  const int* plab = (const int*)d_in[7];
  const unsigned char* adj = (const unsigned char*)d_in[8];
  const float* w_ner1 = (const float*)d_in[9];
  const float* b_ner1 = (const float*)d_in[10];
  const float* w_ner2 = (const float*)d_in[11];
  const float* b_ner2 = (const float*)d_in[12];
  const float* crf_start = (const float*)d_in[13];
  const float* crf_end = (const float*)d_in[14];
  const float* crf_trans = (const float*)d_in[15];
  const float* w_gat1 = (const float*)d_in[16];
  const float* a_src1 = (const float*)d_in[17];
  const float* a_dst1 = (const float*)d_in[18];
  const float* b_gat1 = (const float*)d_in[19];
  const float* w_gat2 = (const float*)d_in[20];
  const float* a_src2 = (const float*)d_in[21];
  const float* a_dst2 = (const float*)d_in[22];
  const float* b_gat2 = (const float*)d_in[23];
  const float* w_fe = (const float*)d_in[24];
  const float* b_fe = (const float*)d_in[25];
  const float* g_fe = (const float*)d_in[26];
  const float* be_fe = (const float*)d_in[27];
  const float* w_rc1 = (const float*)d_in[28];
  const float* b_rc1 = (const float*)d_in[29];
  const float* g_rc = (const float*)d_in[30];
  const float* be_rc = (const float*)d_in[31];
  const float* w_rc2 = (const float*)d_in[32];
  const float* b_rc2 = (const float*)d_in[33];

  float* out = (float*)d_out;
  float* ws = (float*)d_ws;
  float* ent = ws + WS_ENT;
  float* hg1 = ws + WS_HG1;
  float* x1 = ws + WS_X1;
  float* h2 = ws + WS_H2;
  float* x2 = ws + WS_X2;
  float* s1 = ws + WS_S1;
  float* d1 = ws + WS_D1;
  float* s2 = ws + WS_S2;
  float* d2 = ws + WS_D2;
  float* ctx = ws + WS_CTX;
  float* pf = ws + WS_PF;
  float* crfb = ws + WS_CRF;
  float* rel = ws + WS_REL;
  unsigned short* w1t = (unsigned short*)(ws + WS_W1T);
  unsigned short* feb = (unsigned short*)(ws + WS_FE);
  unsigned short* wrt = (unsigned short*)(ws + WS_WRT);    // dead ENT region
  unsigned short* wfet = (unsigned short*)(ws + WS_WFET);  // dead ENT region
  float* segm = ws + WS_SEG;                               // dead ENT region

  hipMemsetAsync(rel, 0, sizeof(float), stream);

  k_w1t<<<NH, 256, 0, stream>>>(w_ner1, w1t);
  k_ner<<<512, 256, 0, stream>>>(seq, w1t, b_ner1, w_ner2, b_ner2, out);
  k_ent<<<NB * NE, 256, 0, stream>>>(seq, est, elen, ent);
  k_g1<<<NB * 4, 256, 0, stream>>>(ent, w_gat1, hg1);
  // ent is dead after k_g1 -> its region now hosts wrt/wfet/segm
  k_wrt<<<NR * 8, 256, 0, stream>>>(w_rc1, wrt);
  k_wfet<<<10, 256, 0, stream>>>(w_fe, wfet);
  k_crf_seg<<<NB * SEGS, 128, 0, stream>>>(out, amask, crf_trans, segm);
  k_crf_fin<<<NB, 64, 0, stream>>>(out, nlab, amask, crf_start, crf_end, crf_trans,
                                   segm, crfb);
  k_sd1<<<NB * NE, 128, 0, stream>>>(hg1, a_src1, a_dst1, s1, d1);
  k_att1<<<NB * NHEADS * NE, 128, 0, stream>>>(hg1, s1, d1, adj, b_gat1, x1);
  k_g2<<<NB, 256, 0, stream>>>(x1, w_gat2, a_src2, a_dst2, h2, s2, d2);
  k_att2<<<NB * NE, 64, 0, stream>>>(h2, s2, d2, adj, b_gat2, x2);
  k_ctx<<<NB, 64, 0, stream>>>(x2, ctx);
  k_pf<<<NB * NP, 64, 0, stream>>>(x2, ctx, pe1, pe2, pf);
  k_fe<<<NB, 256, 0, stream>>>(pf, wfet, b_fe, g_fe, be_fe, feb);
  k_rc<<<NR * NB, 256, 0, stream>>>(feb, wrt, b_rc1, g_rc, be_rc, w_rc2, b_rc2,
                                    plab, out + ZOFF, rel);
  k_fin<<<1, 64, 0, stream>>>(crfb, rel, out);
}